// Round 4
// baseline (392.253 us; speedup 1.0000x reference)
//
#include <hip/hip_runtime.h>
#include <hip/hip_bf16.h>
#include <math.h>

#define N_PTS 16384
#define KNN 8

#define DT_BF16 1
#define DT_FP32 2

// Workspace layout:
//   flag : int          @ 0
//   idx  : int  [N*9]   @ 64        -> 589,824 B
//   x1   : f32  [N*64]  @ 589,888   -> 4,194,304 B
// Grid-KNN scratch lives INSIDE the x1 region (dead before conv1 writes x1):
//   sat    : int [110592]  @ x1+0        (cell counts, transformed in place to 3D SAT)
//   start  : int [110593]  @ x1+442368   (exclusive prefix + 1 sentinel)
//   cursor : int [110592]  @ x1+884800
//   pid    : int [16384]   @ x1+1327168
//   pts4   : f4  [16384]   @ x1+1392704  (end 1,654,848 <= 4,194,304)
#define WS_FLAG_OFF 0
#define WS_IDX_OFF  64
#define WS_X1_OFF   589888
#define WS_NEEDED   4784192

#define WS_SAT_OFF    (WS_X1_OFF)
#define WS_START_OFF  (WS_X1_OFF + 442368)
#define WS_CURSOR_OFF (WS_X1_OFF + 884800)
#define WS_PID_OFF    (WS_X1_OFF + 1327168)
#define WS_PTS_OFF    (WS_X1_OFF + 1392704)

// 48^3 grid: cell edge 0.1875 (was 0.281 at 32^3) -> ~3x fewer candidates in
// the r=1 window at the dense center, where most targets live.
#define GRID_R   48
#define NROWS2D  (GRID_R * GRID_R)          // 2304 (y,z) rows
#define NCELLS   (GRID_R * GRID_R * GRID_R) // 110592
#define GLO      -4.5f
#define CELL_E   0.1875f
#define CELL_INV 5.3333335f
#define NBR_MIN  26   // SAT window population target (incl. self)
#define MAXR     8    // window cap; beyond -> generic ring fallback
#define MAXROWS  289  // (2*MAXR+1)^2

__device__ __forceinline__ float bf2f(__hip_bfloat16 v) { return __bfloat162float(v); }

__device__ __forceinline__ float ldf(const float* p, int i) { return p[i]; }
__device__ __forceinline__ float ldf(const __hip_bfloat16* p, int i) { return bf2f(p[i]); }
__device__ __forceinline__ void stf(float* p, int i, float v) { p[i] = v; }
__device__ __forceinline__ void stf(__hip_bfloat16* p, int i, float v) { p[i] = __float2bfloat16(v); }

__device__ __forceinline__ int clamp_idx(int j) {
    return ((unsigned)j < (unsigned)N_PTS) ? j : 0;
}

__device__ __forceinline__ int cell_of(float v) {
    int c = (int)((v - GLO) * CELL_INV);
    return min(max(c, 0), GRID_R - 1);
}

// flag[0] holds the sniffer's bad-count; >16 => fp32 input.
__device__ __forceinline__ int get_dt(const int* flag) {
    return (flag[0] > 16) ? DT_FP32 : DT_BF16;
}

// ---------------------------------------------------------------------------
// zero: cnt[] and flag.
// ---------------------------------------------------------------------------
__global__ __launch_bounds__(256) void zero_kernel(int* __restrict__ cnt, int* __restrict__ flag) {
    const int e = blockIdx.x * 256 + threadIdx.x;
    cnt[e] = 0;
    if (e == 0) flag[0] = 0;
}

// ---------------------------------------------------------------------------
// sniff (multi-block).
// ---------------------------------------------------------------------------
__global__ __launch_bounds__(256) void sniff_kernel(const unsigned short* __restrict__ posu,
                                                    int* __restrict__ flag) {
    __shared__ int red[256];
    int local = 0;
    for (int e = blockIdx.x * 256 + threadIdx.x; e < 3 * N_PTS; e += 64 * 256) {
        const float v = __uint_as_float(((unsigned)posu[e]) << 16);
        if (!(fabsf(v) <= 64.0f)) local++;
    }
    red[threadIdx.x] = local;
    __syncthreads();
    for (int s = 128; s > 0; s >>= 1) {
        if (threadIdx.x < s) red[threadIdx.x] += red[threadIdx.x + s];
        __syncthreads();
    }
    if (threadIdx.x == 0 && red[0] > 0) atomicAdd(flag, red[0]);
}

// ---------------------------------------------------------------------------
// Grid build: count -> scan(+sat x-pass) -> sat y/z passes -> scatter.
// ---------------------------------------------------------------------------
template <typename T>
__device__ __forceinline__ void count_body(const T* __restrict__ pos, int* __restrict__ cnt) {
    const int i = blockIdx.x * 256 + threadIdx.x;
    const float x = ldf(pos, 3 * i + 0);
    const float y = ldf(pos, 3 * i + 1);
    const float z = ldf(pos, 3 * i + 2);
    const int c = (cell_of(z) * GRID_R + cell_of(y)) * GRID_R + cell_of(x);
    atomicAdd(&cnt[c], 1);
}

__global__ __launch_bounds__(256) void grid_count_kernel(const void* __restrict__ pos,
                                                         const int* __restrict__ flag,
                                                         int* __restrict__ cnt) {
    if (get_dt(flag) == DT_BF16) count_body<__hip_bfloat16>((const __hip_bfloat16*)pos, cnt);
    else                         count_body<float>((const float*)pos, cnt);
}

// exclusive prefix over 110592 cells (start/cursor, + sentinel), then
// in-place x-prefix of cnt (SAT pass 1). Single block of 1024.
__global__ __launch_bounds__(1024) void grid_scan_kernel(int* __restrict__ cnt,
                                                         int* __restrict__ start,
                                                         int* __restrict__ cursor) {
    __shared__ int part[1024];
    const int t = threadIdx.x;
    const int base = t * 108;                 // 1024 * 108 = 110592
    int s = 0;
    for (int k = 0; k < 108; ++k) s += cnt[base + k];
    part[t] = s;
    __syncthreads();
    for (int off = 1; off < 1024; off <<= 1) {
        int v = (t >= off) ? part[t - off] : 0;
        __syncthreads();
        part[t] += v;
        __syncthreads();
    }
    int run = (t == 0) ? 0 : part[t - 1];
    for (int k = 0; k < 108; ++k) {
        start[base + k] = run;
        cursor[base + k] = run;
        run += cnt[base + k];
    }
    if (t == 1023) start[NCELLS] = run;       // sentinel: cell end = start[c+1]
    __syncthreads();
    // SAT pass 1: inclusive prefix along x, in place over cnt (rows of 48)
    for (int row = t; row < NROWS2D; row += 1024) {
        const int rb = row * GRID_R;
        int acc = 0;
        for (int x = 0; x < GRID_R; ++x) { acc += cnt[rb + x]; cnt[rb + x] = acc; }
    }
}

// SAT pass 2: prefix along y. 2304 threads, one (z,x) column each.
__global__ __launch_bounds__(256) void saty_kernel(int* __restrict__ sat) {
    const int t = blockIdx.x * 256 + threadIdx.x;   // < 2304
    const int z = t / GRID_R, x = t - z * GRID_R;
    const int base = z * NROWS2D + x;
    int v[GRID_R];
#pragma unroll
    for (int y = 0; y < GRID_R; ++y) v[y] = sat[base + y * GRID_R];
    int run = 0;
#pragma unroll
    for (int y = 0; y < GRID_R; ++y) { run += v[y]; sat[base + y * GRID_R] = run; }
}

// SAT pass 3: prefix along z. 2304 threads, one (y,x) column each.
__global__ __launch_bounds__(256) void satz_kernel(int* __restrict__ sat) {
    const int t = blockIdx.x * 256 + threadIdx.x;   // < 2304
    const int base = t;                              // y*48 + x
    int v[GRID_R];
#pragma unroll
    for (int z = 0; z < GRID_R; ++z) v[z] = sat[base + z * NROWS2D];
    int run = 0;
#pragma unroll
    for (int z = 0; z < GRID_R; ++z) { run += v[z]; sat[base + z * NROWS2D] = run; }
}

template <typename T>
__device__ __forceinline__ void scatter_body(const T* __restrict__ pos, int* __restrict__ cursor,
                                             float4* __restrict__ pts4, int* __restrict__ pid) {
    const int i = blockIdx.x * 256 + threadIdx.x;
    const float x = ldf(pos, 3 * i + 0);
    const float y = ldf(pos, 3 * i + 1);
    const float z = ldf(pos, 3 * i + 2);
    const int c = (cell_of(z) * GRID_R + cell_of(y)) * GRID_R + cell_of(x);
    const int slot = atomicAdd(&cursor[c], 1);
    const float sq = fmaf(x, x, fmaf(y, y, z * z));
    pts4[slot] = make_float4(-2.0f * x, -2.0f * y, -2.0f * z, sq);
    pid[slot] = i;
}

__global__ __launch_bounds__(256) void grid_scatter_kernel(const void* __restrict__ pos,
                                                           const int* __restrict__ flag,
                                                           int* __restrict__ cursor,
                                                           float4* __restrict__ pts4,
                                                           int* __restrict__ pid) {
    if (get_dt(flag) == DT_BF16) scatter_body<__hip_bfloat16>((const __hip_bfloat16*)pos, cursor, pts4, pid);
    else                         scatter_body<float>((const float*)pos, cursor, pts4, pid);
}

// ---------------------------------------------------------------------------
// KNN v5: one wave per target.
//  1) SAT query finds smallest window radius r with >= NBR_MIN points
//     (uniform broadcast loads; r capped at MAXR).
//  2) Window rows (x-runs) are CONTIGUOUS spans in pts4 (cells consecutive in
//     x are adjacent in memory). Stage row (start, prefix) in LDS via
//     shfl-prefix, then lanes take candidates t = lane, lane+64, ... ->
//     wave time = M/64, not max-cell-count (r3's per-cell imbalance).
//  3) One termination check; rare failures fall back to the exact generic
//     per-cell ring loop (never overlaps the window; tau-gated so cheap).
// Lex (d, idx) order everywhere -> invariant to scatter order; matches
// stable top_k ties. Margin gets a -1e-5 conservative epsilon.
// ---------------------------------------------------------------------------
__device__ __forceinline__ int sat_at(const int* __restrict__ sat, int x, int y, int z) {
    if (x < 0 || y < 0 || z < 0) return 0;
    return sat[(z * GRID_R + y) * GRID_R + x];
}

__device__ __forceinline__ int boxcount(const int* __restrict__ sat,
                                        int x0, int x1, int y0, int y1, int z0, int z1) {
    return sat_at(sat, x1, y1, z1) - sat_at(sat, x0 - 1, y1, z1)
         - sat_at(sat, x1, y0 - 1, z1) - sat_at(sat, x1, y1, z0 - 1)
         + sat_at(sat, x0 - 1, y0 - 1, z1) + sat_at(sat, x0 - 1, y1, z0 - 1)
         + sat_at(sat, x1, y0 - 1, z0 - 1) - sat_at(sat, x0 - 1, y0 - 1, z0 - 1);
}

template <typename T>
__device__ void knn_body(const T* __restrict__ pos,
                         const int* __restrict__ cstart, const int* __restrict__ sat,
                         const float4* __restrict__ pts4, const int* __restrict__ pid,
                         int* __restrict__ idx_out,
                         int* __restrict__ rs, int* __restrict__ pf) {
    const int tid  = threadIdx.x;
    const int lane = tid & 63;
    const int i    = blockIdx.x * 4 + (tid >> 6);

    const float pix = ldf(pos, 3 * i + 0);
    const float piy = ldf(pos, 3 * i + 1);
    const float piz = ldf(pos, 3 * i + 2);
    const float sqi = fmaf(pix, pix, fmaf(piy, piy, piz * piz));
    const int cx = cell_of(pix), cy = cell_of(piy), cz = cell_of(piz);

    float bd[KNN];
    int   bi[KNN];
#pragma unroll
    for (int q = 0; q < KNN; ++q) { bd[q] = INFINITY; bi[q] = 0x7fffffff; }
    float tau = INFINITY;

    auto do_insert = [&](float d, int pj) {
        float cd = d; int ci = pj;
#pragma unroll
        for (int q = 0; q < KNN; ++q) {
            const bool ins = (cd < bd[q]) || (cd == bd[q] && ci < bi[q]);
            const float nd = ins ? cd : bd[q];
            const int   ni = ins ? ci : bi[q];
            const float od = ins ? bd[q] : cd;
            const int   oi = ins ? bi[q] : ci;
            bd[q] = nd; bi[q] = ni; cd = od; ci = oi;
        }
        tau = fminf(tau, bd[KNN - 1]);
    };

    auto term_check = [&](int r) -> bool {
        float wtau = bd[KNN - 1];
#pragma unroll
        for (int s = 1; s < 64; s <<= 1) wtau = fminf(wtau, __shfl_xor(wtau, s, 64));
        int cl = 0;
#pragma unroll
        for (int q = 0; q < KNN; ++q) cl += (bd[q] < INFINITY) ? 1 : 0;
#pragma unroll
        for (int s = 1; s < 64; s <<= 1) cl += __shfl_xor(cl, s, 64);

        float mg = INFINITY;
        bool full = true;
        if (cx - r > 0)          { mg = fminf(mg, pix - (GLO + (float)(cx - r) * CELL_E));     full = false; }
        if (cx + r < GRID_R - 1) { mg = fminf(mg, (GLO + (float)(cx + r + 1) * CELL_E) - pix); full = false; }
        if (cy - r > 0)          { mg = fminf(mg, piy - (GLO + (float)(cy - r) * CELL_E));     full = false; }
        if (cy + r < GRID_R - 1) { mg = fminf(mg, (GLO + (float)(cy + r + 1) * CELL_E) - piy); full = false; }
        if (cz - r > 0)          { mg = fminf(mg, piz - (GLO + (float)(cz - r) * CELL_E));     full = false; }
        if (cz + r < GRID_R - 1) { mg = fminf(mg, (GLO + (float)(cz + r + 1) * CELL_E) - piz); full = false; }

        if (full) return true;
        mg = mg - 1e-5f;   // conservative vs cell_of float rounding
        if (cl >= 8) {
            const float need = mg * mg - sqi;   // d_real < mg^2  <=>  d' < need
            if (wtau < need) { tau = fminf(tau, wtau); return true; }
            // exact global 8th-best via destructive merge of list copies
            float cd2[KNN]; int ci2[KNN];
#pragma unroll
            for (int q = 0; q < KNN; ++q) { cd2[q] = bd[q]; ci2[q] = bi[q]; }
            float d8 = INFINITY;
#pragma unroll
            for (int k = 0; k < KNN; ++k) {
                float dw = cd2[0];
                int   iw = ci2[0];
#pragma unroll
                for (int s = 1; s < 64; s <<= 1) {
                    const float od = __shfl_xor(dw, s, 64);
                    const int   oi = __shfl_xor(iw, s, 64);
                    if (od < dw || (od == dw && oi < iw)) { dw = od; iw = oi; }
                }
                if (cd2[0] == dw && ci2[0] == iw) {
#pragma unroll
                    for (int q = 0; q < KNN - 1; ++q) { cd2[q] = cd2[q + 1]; ci2[q] = ci2[q + 1]; }
                    cd2[KNN - 1] = INFINITY; ci2[KNN - 1] = 0x7fffffff;
                }
                d8 = dw;
            }
            if (d8 < need) { tau = fminf(tau, d8); return true; }
            tau = fminf(tau, d8);
        }
        tau = fminf(tau, wtau);
        return false;
    };

    // ---- 1) SAT radius search (uniform across wave) ----
    int r = 1, x0, x1, y0, y1, z0, z1;
    for (;;) {
        x0 = max(cx - r, 0); x1 = min(cx + r, GRID_R - 1);
        y0 = max(cy - r, 0); y1 = min(cy + r, GRID_R - 1);
        z0 = max(cz - r, 0); z1 = min(cz + r, GRID_R - 1);
        if (r >= MAXR) break;
        if (boxcount(sat, x0, x1, y0, y1, z0, z1) >= NBR_MIN) break;
        ++r;
    }

    // ---- 2) stage window rows (contiguous x-run spans) ----
    const int ny = y1 - y0 + 1;
    const int R  = ny * (z1 - z0 + 1);
    int Mtot = 0;
    for (int row0 = 0; row0 < R; row0 += 64) {
        const int row = row0 + lane;
        int cnt_r = 0, st_r = 0;
        if (row < R) {
            const int iz = row / ny;
            const int iy = row - iz * ny;
            const int c0 = ((z0 + iz) * GRID_R + (y0 + iy)) * GRID_R + x0;
            st_r  = cstart[c0];
            cnt_r = cstart[c0 + (x1 - x0) + 1] - st_r;
        }
        int pv = cnt_r;
#pragma unroll
        for (int s = 1; s < 64; s <<= 1) {
            const int u = __shfl_up(pv, s, 64);
            if (lane >= s) pv += u;
        }
        if (row < R) { rs[row] = st_r; pf[row + 1] = Mtot + pv; }
        Mtot += __shfl(pv, 63, 64);
    }
    asm volatile("s_waitcnt lgkmcnt(0)" ::: "memory");  // wave-local LDS visibility

    // ---- candidate-even scan ----
    {
        int p = 0, cur = 0;
        int nxt = pf[1];
        int rst = rs[0];
        for (int t = lane; t < Mtot; t += 64) {
            while (nxt <= t) { ++p; cur = nxt; nxt = pf[p + 1]; rst = rs[p]; }
            const int si = rst + (t - cur);
            const float4 cq = pts4[si];
            const int    pj = pid[si];
            const float d = fmaf(cq.x, pix, fmaf(cq.y, piy, fmaf(cq.z, piz, cq.w)));
            if (pj != i && d <= tau) do_insert(d, pj);
        }
    }

    // ---- 3) termination + exact generic ring fallback ----
    if (!term_check(r)) {
        for (int r2 = r + 1; r2 <= GRID_R; ++r2) {
            const int W = 2 * r2 + 1, W2 = W * W, vol = W2 * W;
            for (int t0 = lane; t0 < vol; t0 += 64) {
                int dz = t0 / W2;
                int rem = t0 - dz * W2;
                int dy = rem / W;
                int dx = rem - dy * W;
                dx -= r2; dy -= r2; dz -= r2;
                const int ax = dx < 0 ? -dx : dx;
                const int ay = dy < 0 ? -dy : dy;
                const int az = dz < 0 ? -dz : dz;
                if (max(ax, max(ay, az)) != r2) continue;
                const int ccx = cx + dx, ccy = cy + dy, ccz = cz + dz;
                if ((unsigned)ccx >= GRID_R || (unsigned)ccy >= GRID_R || (unsigned)ccz >= GRID_R)
                    continue;
                const int c  = (ccz * GRID_R + ccy) * GRID_R + ccx;
                const int s0 = cstart[c];
                const int s1 = cstart[c + 1];
                for (int s = s0; s < s1; ++s) {
                    const float4 cq = pts4[s];
                    const int    pj = pid[s];
                    const float d = fmaf(cq.x, pix, fmaf(cq.y, piy, fmaf(cq.z, piz, cq.w)));
                    if (pj != i && d <= tau) do_insert(d, pj);
                }
            }
            if (term_check(r2)) break;
        }
    }

    // ---- final merge of 64 sorted lists (lex), emit top-8 ----
#pragma unroll
    for (int k = 0; k < KNN; ++k) {
        float dw = bd[0];
        int   iw = bi[0];
#pragma unroll
        for (int s = 1; s < 64; s <<= 1) {
            const float od = __shfl_xor(dw, s, 64);
            const int   oi = __shfl_xor(iw, s, 64);
            if (od < dw || (od == dw && oi < iw)) { dw = od; iw = oi; }
        }
        if (bd[0] == dw && bi[0] == iw) {
#pragma unroll
            for (int q = 0; q < KNN - 1; ++q) { bd[q] = bd[q + 1]; bi[q] = bi[q + 1]; }
            bd[KNN - 1] = INFINITY; bi[KNN - 1] = 0x7fffffff;
        }
        if (lane == 0) idx_out[i * 9 + k] = clamp_idx(iw);
    }
    if (lane == 0) idx_out[i * 9 + 8] = i;
}

__global__ __launch_bounds__(256) void knn_grid_kernel(const void* __restrict__ pos,
                                                       const int* __restrict__ flag,
                                                       const int* __restrict__ cstart,
                                                       const int* __restrict__ sat,
                                                       const float4* __restrict__ pts4,
                                                       const int* __restrict__ pid,
                                                       int* __restrict__ idx_out) {
    __shared__ int rs[4][MAXROWS];
    __shared__ int pf[4][MAXROWS + 1];
    const int wv = threadIdx.x >> 6;
    if (get_dt(flag) == DT_BF16)
        knn_body<__hip_bfloat16>((const __hip_bfloat16*)pos, cstart, sat, pts4, pid, idx_out,
                                 rs[wv], pf[wv]);
    else
        knn_body<float>((const float*)pos, cstart, sat, pts4, pid, idx_out, rs[wv], pf[wv]);
}

// ---------------------------------------------------------------------------
// conv1 (unchanged from r3): first layer factored
//   h1[n] = relu( pos_j@(Wtop+Wbot) - pos_i@Wbot + bA )
// ---------------------------------------------------------------------------
struct Conv1Smem {
    alignas(16) float wB[32 * 64];
    alignas(16) float h1s[4][9 * 32];
    alignas(16) float wsum[3 * 32];
    alignas(16) float wbot[3 * 32];
    alignas(16) float posn[4][9][3];
    float bA[32];
    float bB[64];
};

template <typename T>
__device__ void conv1_body(const T* __restrict__ pos, const int* __restrict__ idx,
                           const T* __restrict__ W1a, const T* __restrict__ b1a,
                           const T* __restrict__ W1b, const T* __restrict__ b1b,
                           float* __restrict__ x1, Conv1Smem& s) {
    const int tid = threadIdx.x;
    for (int e = tid; e < 96; e += 256) {
        const float bot = ldf(W1a, 96 + e);
        s.wsum[e] = ldf(W1a, e) + bot;
        s.wbot[e] = bot;
    }
    if (tid < 32) s.bA[tid] = ldf(b1a, tid);
    for (int e = tid; e < 2048; e += 256) s.wB[e] = ldf(W1b, e);
    if (tid < 64) s.bB[tid] = ldf(b1b, tid);

    const int tl   = tid >> 6;
    const int lane = tid & 63;
    const int i    = blockIdx.x * 4 + tl;

    if (lane < 27) {
        const int n = lane / 3, c = lane % 3;
        const int j = clamp_idx(idx[i * 9 + n]);
        s.posn[tl][n][c] = ldf(pos, 3 * j + c);
    }
    const float pi0 = ldf(pos, 3 * i + 0);
    const float pi1 = ldf(pos, 3 * i + 1);
    const float pi2 = ldf(pos, 3 * i + 2);
    __syncthreads();

    for (int e = lane; e < 288; e += 64) {
        const int n = e >> 5, k = e & 31;
        float b = fmaf(pi0, s.wbot[k], fmaf(pi1, s.wbot[32 + k], pi2 * s.wbot[64 + k]));
        float v = s.bA[k] - b;
        v = fmaf(s.posn[tl][n][0], s.wsum[k], v);
        v = fmaf(s.posn[tl][n][1], s.wsum[32 + k], v);
        v = fmaf(s.posn[tl][n][2], s.wsum[64 + k], v);
        s.h1s[tl][n * 32 + k] = fmaxf(v, 0.0f);
    }
    __syncthreads();

    float wcol[32];
#pragma unroll
    for (int k = 0; k < 32; ++k) wcol[k] = s.wB[k * 64 + lane];

    float acc = -INFINITY;
    for (int n = 0; n < 9; ++n) {
        float v = s.bB[lane];
#pragma unroll
        for (int k = 0; k < 32; ++k) v = fmaf(s.h1s[tl][n * 32 + k], wcol[k], v);
        acc = fmaxf(acc, v);
    }
    x1[i * 64 + lane] = fmaxf(acc, 0.0f);
}

__global__ __launch_bounds__(256) void conv1_kernel(const void* __restrict__ pos,
                                                    const int* __restrict__ flag,
                                                    const int* __restrict__ idx,
                                                    const void* __restrict__ W1a,
                                                    const void* __restrict__ b1a,
                                                    const void* __restrict__ W1b,
                                                    const void* __restrict__ b1b,
                                                    float* __restrict__ x1) {
    __shared__ Conv1Smem s;
    if (get_dt(flag) == DT_BF16)
        conv1_body<__hip_bfloat16>((const __hip_bfloat16*)pos, idx,
            (const __hip_bfloat16*)W1a, (const __hip_bfloat16*)b1a,
            (const __hip_bfloat16*)W1b, (const __hip_bfloat16*)b1b, x1, s);
    else
        conv1_body<float>((const float*)pos, idx, (const float*)W1a, (const float*)b1a,
            (const float*)W1b, (const float*)b1b, x1, s);
}

// ---------------------------------------------------------------------------
// zw (unchanged from r3): per-point precompute for conv2's first layer.
// ---------------------------------------------------------------------------
struct ZwSmem {
    alignas(16) float wA[67 * 64];
    alignas(16) float xrT[4][68][4];
    float bA[64];
};

template <typename T>
__device__ void zw_body(const T* __restrict__ pos, const T* __restrict__ W2a,
                        const T* __restrict__ b2a, float* __restrict__ x1, ZwSmem& s) {
    const int tid  = threadIdx.x;
    const int wv   = tid >> 6;
    const int lane = tid & 63;
    const int j0   = blockIdx.x * 16 + wv * 4;

    for (int e = tid; e < 4288; e += 256) s.wA[e] = ldf(W2a, e);
    if (tid < 64) s.bA[tid] = ldf(b2a, tid);

#pragma unroll
    for (int p = 0; p < 4; ++p)
        s.xrT[wv][lane][p] = x1[(j0 + p) * 64 + lane];
    if (lane < 12) {
        const int p = lane / 3, c = lane % 3;
        s.xrT[wv][64 + c][p] = ldf(pos, 3 * (j0 + p) + c);
    }
    __syncthreads();

    float a0 = s.bA[lane], a1 = a0, a2 = a0, a3 = a0;
    for (int c = 0; c < 67; ++c) {
        const float w = s.wA[c * 64 + lane];
        const float4 xv = *(const float4*)&s.xrT[wv][c][0];
        a0 = fmaf(xv.x, w, a0);
        a1 = fmaf(xv.y, w, a1);
        a2 = fmaf(xv.z, w, a2);
        a3 = fmaf(xv.w, w, a3);
    }
    x1[(j0 + 0) * 64 + lane] = a0;
    x1[(j0 + 1) * 64 + lane] = a1;
    x1[(j0 + 2) * 64 + lane] = a2;
    x1[(j0 + 3) * 64 + lane] = a3;
}

__global__ __launch_bounds__(256) void zw_kernel(const void* __restrict__ pos,
                                                 const int* __restrict__ flag,
                                                 const void* __restrict__ W2a,
                                                 const void* __restrict__ b2a,
                                                 float* __restrict__ x1) {
    __shared__ ZwSmem s;
    if (get_dt(flag) == DT_BF16)
        zw_body<__hip_bfloat16>((const __hip_bfloat16*)pos, (const __hip_bfloat16*)W2a,
                                (const __hip_bfloat16*)b2a, x1, s);
    else
        zw_body<float>((const float*)pos, (const float*)W2a, (const float*)b2a, x1, s);
}

// ---------------------------------------------------------------------------
// conv2+head (unchanged from r3): h1[n] = relu(zw[j_n] - pos_i@W2a_bot).
// ---------------------------------------------------------------------------
struct Conv2Smem {
    alignas(16) float h1s[4][9 * 64];
    alignas(16) float row[4][128];
    alignas(16) float wbot[3 * 64];
    alignas(16) float wc[640];
    float bcs[5];
    float sv[4][5];
    int   nb[4][9];
};

template <typename T>
__device__ void conv2_body(const T* __restrict__ pos, const int* __restrict__ idx,
                           const float* __restrict__ zw,
                           const T* __restrict__ W2a, const T* __restrict__ W2b,
                           const T* __restrict__ b2b, const T* __restrict__ Wc,
                           const T* __restrict__ bc, T* __restrict__ out, Conv2Smem& s) {
    const int tid  = threadIdx.x;
    const int l    = tid & 127;
    const int half = tid >> 7;

    float wcol[64];
#pragma unroll
    for (int k = 0; k < 64; ++k) wcol[k] = ldf(W2b, k * 128 + l);
    const float bBl = ldf(b2b, l);

    for (int e = tid; e < 192; e += 256) s.wbot[e] = ldf(W2a, 4096 + e);
    for (int e = tid; e < 640; e += 256) s.wc[e] = ldf(Wc, e);
    if (tid < 5) s.bcs[tid] = ldf(bc, tid);

    const int tl   = tid >> 6;
    const int lane = tid & 63;
    const int i    = blockIdx.x * 4 + tl;

    if (lane < 9) s.nb[tl][lane] = clamp_idx(idx[i * 9 + lane]);
    const float pi0 = ldf(pos, 3 * i + 0);
    const float pi1 = ldf(pos, 3 * i + 1);
    const float pi2 = ldf(pos, 3 * i + 2);
    __syncthreads();

    {
        const float vi = fmaf(pi0, s.wbot[lane], fmaf(pi1, s.wbot[64 + lane], pi2 * s.wbot[128 + lane]));
#pragma unroll
        for (int n = 0; n < 9; ++n) {
            const int j = s.nb[tl][n];
            s.h1s[tl][n * 64 + lane] = fmaxf(zw[j * 64 + lane] - vi, 0.0f);
        }
    }
    __syncthreads();

#pragma unroll
    for (int tt = 0; tt < 2; ++tt) {
        const int tgt = half * 2 + tt;
        float acc = -INFINITY;
        for (int n = 0; n < 9; ++n) {
            float v = bBl;
            for (int k = 0; k < 64; k += 4) {
                const float4 hv = *(const float4*)&s.h1s[tgt][n * 64 + k];
                v = fmaf(hv.x, wcol[k + 0], v);
                v = fmaf(hv.y, wcol[k + 1], v);
                v = fmaf(hv.z, wcol[k + 2], v);
                v = fmaf(hv.w, wcol[k + 3], v);
            }
            acc = fmaxf(acc, v);
        }
        s.row[tgt][l] = fmaxf(acc, 0.0f);
    }
    __syncthreads();

    if (tid < 20) {
        const int tgt = tid / 5, o = tid % 5;
        float v = s.bcs[o];
        for (int k = 0; k < 128; ++k) v = fmaf(s.row[tgt][k], s.wc[k * 5 + o], v);
        s.sv[tgt][o] = v;
    }
    __syncthreads();
    if (tid < 20) {
        const int tgt = tid / 5, o = tid % 5;
        float m = s.sv[tgt][0];
#pragma unroll
        for (int q = 1; q < 5; ++q) m = fmaxf(m, s.sv[tgt][q]);
        float sum = 0.0f;
#pragma unroll
        for (int q = 0; q < 5; ++q) sum += expf(s.sv[tgt][q] - m);
        const float lse = m + logf(sum);
        stf(out, (blockIdx.x * 4 + tgt) * 5 + o, s.sv[tgt][o] - lse);
    }
}

__global__ __launch_bounds__(256) void conv2_head_kernel(const void* __restrict__ pos,
                                                         const int* __restrict__ flag,
                                                         const int* __restrict__ idx,
                                                         const float* __restrict__ zw,
                                                         const void* __restrict__ W2a,
                                                         const void* __restrict__ W2b,
                                                         const void* __restrict__ b2b,
                                                         const void* __restrict__ Wc,
                                                         const void* __restrict__ bc,
                                                         void* __restrict__ out) {
    __shared__ Conv2Smem s;
    if (get_dt(flag) == DT_BF16)
        conv2_body<__hip_bfloat16>((const __hip_bfloat16*)pos, idx, zw,
            (const __hip_bfloat16*)W2a, (const __hip_bfloat16*)W2b, (const __hip_bfloat16*)b2b,
            (const __hip_bfloat16*)Wc, (const __hip_bfloat16*)bc, (__hip_bfloat16*)out, s);
    else
        conv2_body<float>((const float*)pos, idx, zw, (const float*)W2a, (const float*)W2b,
            (const float*)b2b, (const float*)Wc, (const float*)bc, (float*)out, s);
}

// ---------------------------------------------------------------------------
extern "C" void kernel_launch(void* const* d_in, const int* in_sizes, int n_in,
                              void* d_out, int out_size, void* d_ws, size_t ws_size,
                              hipStream_t stream) {
    if (ws_size < (size_t)WS_NEEDED) return;

    char* ws = (char*)d_ws;
    int*    flag   = (int*)(ws + WS_FLAG_OFF);
    int*    idx    = (int*)(ws + WS_IDX_OFF);
    float*  x1     = (float*)(ws + WS_X1_OFF);
    int*    sat    = (int*)(ws + WS_SAT_OFF);     // cnt -> SAT in place
    int*    cstart = (int*)(ws + WS_START_OFF);
    int*    cursor = (int*)(ws + WS_CURSOR_OFF);
    int*    pid    = (int*)(ws + WS_PID_OFF);
    float4* pts4   = (float4*)(ws + WS_PTS_OFF);

    zero_kernel<<<NCELLS / 256, 256, 0, stream>>>(sat, flag);
    sniff_kernel<<<64, 256, 0, stream>>>((const unsigned short*)d_in[0], flag);
    grid_count_kernel<<<N_PTS / 256, 256, 0, stream>>>(d_in[0], flag, sat);
    grid_scan_kernel<<<1, 1024, 0, stream>>>(sat, cstart, cursor);
    saty_kernel<<<NROWS2D / 256, 256, 0, stream>>>(sat);
    satz_kernel<<<NROWS2D / 256, 256, 0, stream>>>(sat);
    grid_scatter_kernel<<<N_PTS / 256, 256, 0, stream>>>(d_in[0], flag, cursor, pts4, pid);
    knn_grid_kernel<<<N_PTS / 4, 256, 0, stream>>>(d_in[0], flag, cstart, sat, pts4, pid, idx);
    conv1_kernel<<<N_PTS / 4, 256, 0, stream>>>(d_in[0], flag, idx,
        d_in[1], d_in[2], d_in[3], d_in[4], x1);
    zw_kernel<<<N_PTS / 16, 256, 0, stream>>>(d_in[0], flag, d_in[5], d_in[6], x1);
    conv2_head_kernel<<<N_PTS / 4, 256, 0, stream>>>(d_in[0], flag, idx, x1,
        d_in[5], d_in[7], d_in[8], d_in[9], d_in[10], d_out);
}

// Round 5
// 277.060 us; speedup vs baseline: 1.4158x; 1.4158x over previous
//
#include <hip/hip_runtime.h>
#include <hip/hip_bf16.h>
#include <math.h>

#define N_PTS 16384
#define KNN 8

#define DT_BF16 1
#define DT_FP32 2

// Workspace layout:
//   flag : int          @ 0
//   idx  : int  [N*9]   @ 64        -> 589,824 B
//   x1   : f32  [N*64]  @ 589,888   -> 4,194,304 B
// Grid-KNN scratch lives INSIDE the x1 region (dead before conv1 writes x1):
//   sat      : int [110592]  @ x1+0        (counts -> x-prefix -> full 3D SAT)
//   start    : int [110593]  @ x1+442368   (cell starts + sentinel)
//   cursor   : int [110592]  @ x1+884800
//   pid      : int [16384]   @ x1+1327168
//   pts4     : f4  [16384]   @ x1+1392704
//   rowtot   : int [2304]    @ x1+1654848
//   rowstart : int [2304]    @ x1+1664064  (end 1,673,280 <= 4,194,304)
#define WS_FLAG_OFF 0
#define WS_IDX_OFF  64
#define WS_X1_OFF   589888
#define WS_NEEDED   4784192

#define WS_SAT_OFF      (WS_X1_OFF)
#define WS_START_OFF    (WS_X1_OFF + 442368)
#define WS_CURSOR_OFF   (WS_X1_OFF + 884800)
#define WS_PID_OFF      (WS_X1_OFF + 1327168)
#define WS_PTS_OFF      (WS_X1_OFF + 1392704)
#define WS_ROWTOT_OFF   (WS_X1_OFF + 1654848)
#define WS_ROWSTART_OFF (WS_X1_OFF + 1664064)

#define GRID_R   48
#define NROWS2D  (GRID_R * GRID_R)          // 2304 (y,z) rows
#define NCELLS   (GRID_R * GRID_R * GRID_R) // 110592
#define GLO      -4.5f
#define CELL_E   0.1875f
#define CELL_INV 5.3333335f
#define NBR_MIN  26   // SAT window population target (incl. self)
#define MAXROWS  289  // LDS row-staging chunk

__device__ __forceinline__ float bf2f(__hip_bfloat16 v) { return __bfloat162float(v); }

__device__ __forceinline__ float ldf(const float* p, int i) { return p[i]; }
__device__ __forceinline__ float ldf(const __hip_bfloat16* p, int i) { return bf2f(p[i]); }
__device__ __forceinline__ void stf(float* p, int i, float v) { p[i] = v; }
__device__ __forceinline__ void stf(__hip_bfloat16* p, int i, float v) { p[i] = __float2bfloat16(v); }

__device__ __forceinline__ int clamp_idx(int j) {
    return ((unsigned)j < (unsigned)N_PTS) ? j : 0;
}

__device__ __forceinline__ int cell_of(float v) {
    int c = (int)((v - GLO) * CELL_INV);
    return min(max(c, 0), GRID_R - 1);
}

// flag[0] holds the sniffer's bad-count; >16 => fp32 input.
__device__ __forceinline__ int get_dt(const int* flag) {
    return (flag[0] > 16) ? DT_FP32 : DT_BF16;
}

// ---------------------------------------------------------------------------
// zero: cnt[] and flag.
// ---------------------------------------------------------------------------
__global__ __launch_bounds__(256) void zero_kernel(int* __restrict__ cnt, int* __restrict__ flag) {
    const int e = blockIdx.x * 256 + threadIdx.x;
    cnt[e] = 0;
    if (e == 0) flag[0] = 0;
}

// ---------------------------------------------------------------------------
// sniff (multi-block).
// ---------------------------------------------------------------------------
__global__ __launch_bounds__(256) void sniff_kernel(const unsigned short* __restrict__ posu,
                                                    int* __restrict__ flag) {
    __shared__ int red[256];
    int local = 0;
    for (int e = blockIdx.x * 256 + threadIdx.x; e < 3 * N_PTS; e += 64 * 256) {
        const float v = __uint_as_float(((unsigned)posu[e]) << 16);
        if (!(fabsf(v) <= 64.0f)) local++;
    }
    red[threadIdx.x] = local;
    __syncthreads();
    for (int s = 128; s > 0; s >>= 1) {
        if (threadIdx.x < s) red[threadIdx.x] += red[threadIdx.x + s];
        __syncthreads();
    }
    if (threadIdx.x == 0 && red[0] > 0) atomicAdd(flag, red[0]);
}

// ---------------------------------------------------------------------------
// Grid build (parallel; r4's single-block scan was ~40 us serial):
//   count -> rowscan (x-prefix per row, rowtot) -> rowoffset (scan rowtot)
//   -> cellstart (cstart/cursor from row base + x-prefix) -> saty -> satz
//   -> scatter.
// ---------------------------------------------------------------------------
template <typename T>
__device__ __forceinline__ void count_body(const T* __restrict__ pos, int* __restrict__ cnt) {
    const int i = blockIdx.x * 256 + threadIdx.x;
    const float x = ldf(pos, 3 * i + 0);
    const float y = ldf(pos, 3 * i + 1);
    const float z = ldf(pos, 3 * i + 2);
    const int c = (cell_of(z) * GRID_R + cell_of(y)) * GRID_R + cell_of(x);
    atomicAdd(&cnt[c], 1);
}

__global__ __launch_bounds__(256) void grid_count_kernel(const void* __restrict__ pos,
                                                         const int* __restrict__ flag,
                                                         int* __restrict__ cnt) {
    if (get_dt(flag) == DT_BF16) count_body<__hip_bfloat16>((const __hip_bfloat16*)pos, cnt);
    else                         count_body<float>((const float*)pos, cnt);
}

// x-prefix per row (in place over sat), rowtot[row] = row sum.
__global__ __launch_bounds__(256) void rowscan_kernel(int* __restrict__ sat,
                                                      int* __restrict__ rowtot) {
    const int t = blockIdx.x * 256 + threadIdx.x;   // row < 2304
    const int rb = t * GRID_R;
    int acc = 0;
    for (int x = 0; x < GRID_R; ++x) { acc += sat[rb + x]; sat[rb + x] = acc; }
    rowtot[t] = acc;
}

// exclusive scan of 2304 row totals (one block, 256 threads x 9 rows).
__global__ __launch_bounds__(256) void rowoffset_kernel(const int* __restrict__ rowtot,
                                                        int* __restrict__ rowstart) {
    __shared__ int part[256];
    const int t = threadIdx.x;
    int loc[9]; int s = 0;
#pragma unroll
    for (int k = 0; k < 9; ++k) { loc[k] = rowtot[t * 9 + k]; s += loc[k]; }
    part[t] = s;
    __syncthreads();
    for (int off = 1; off < 256; off <<= 1) {
        int v = (t >= off) ? part[t - off] : 0;
        __syncthreads();
        part[t] += v;
        __syncthreads();
    }
    int run = (t == 0) ? 0 : part[t - 1];
#pragma unroll
    for (int k = 0; k < 9; ++k) { rowstart[t * 9 + k] = run; run += loc[k]; }
}

// cstart/cursor per cell = rowstart + in-row exclusive x-prefix; sentinel.
__global__ __launch_bounds__(256) void cellstart_kernel(const int* __restrict__ satx,
                                                        const int* __restrict__ rowstart,
                                                        int* __restrict__ cstart,
                                                        int* __restrict__ cursor) {
    const int t = blockIdx.x * 256 + threadIdx.x;   // row < 2304
    const int rb = t * GRID_R;
    const int base = rowstart[t];
    int prev = 0;
    for (int x = 0; x < GRID_R; ++x) {
        const int v = base + prev;
        cstart[rb + x] = v;
        cursor[rb + x] = v;
        prev = satx[rb + x];
    }
    if (t == NROWS2D - 1) cstart[NCELLS] = base + prev;
}

// SAT pass 2: prefix along y. 2304 threads, one (z,x) column each.
__global__ __launch_bounds__(256) void saty_kernel(int* __restrict__ sat) {
    const int t = blockIdx.x * 256 + threadIdx.x;   // < 2304
    const int z = t / GRID_R, x = t - z * GRID_R;
    const int base = z * NROWS2D + x;
    int run = 0;
#pragma unroll
    for (int y = 0; y < GRID_R; ++y) {
        run += sat[base + y * GRID_R];
        sat[base + y * GRID_R] = run;
    }
}

// SAT pass 3: prefix along z. 2304 threads, one (y,x) column each.
__global__ __launch_bounds__(256) void satz_kernel(int* __restrict__ sat) {
    const int t = blockIdx.x * 256 + threadIdx.x;   // < 2304
    int run = 0;
#pragma unroll
    for (int z = 0; z < GRID_R; ++z) {
        run += sat[t + z * NROWS2D];
        sat[t + z * NROWS2D] = run;
    }
}

template <typename T>
__device__ __forceinline__ void scatter_body(const T* __restrict__ pos, int* __restrict__ cursor,
                                             float4* __restrict__ pts4, int* __restrict__ pid) {
    const int i = blockIdx.x * 256 + threadIdx.x;
    const float x = ldf(pos, 3 * i + 0);
    const float y = ldf(pos, 3 * i + 1);
    const float z = ldf(pos, 3 * i + 2);
    const int c = (cell_of(z) * GRID_R + cell_of(y)) * GRID_R + cell_of(x);
    const int slot = atomicAdd(&cursor[c], 1);
    const float sq = fmaf(x, x, fmaf(y, y, z * z));
    pts4[slot] = make_float4(-2.0f * x, -2.0f * y, -2.0f * z, sq);
    pid[slot] = i;
}

__global__ __launch_bounds__(256) void grid_scatter_kernel(const void* __restrict__ pos,
                                                           const int* __restrict__ flag,
                                                           int* __restrict__ cursor,
                                                           float4* __restrict__ pts4,
                                                           int* __restrict__ pid) {
    if (get_dt(flag) == DT_BF16) scatter_body<__hip_bfloat16>((const __hip_bfloat16*)pos, cursor, pts4, pid);
    else                         scatter_body<float>((const float*)pos, cursor, pts4, pid);
}

// ---------------------------------------------------------------------------
// KNN v6: one wave per target. Bounded work, no ring enumeration.
//  1) Parallel SAT probe: lane l tests radius l+1 (8 concurrent loads/lane);
//     ballot+ffs -> smallest r with >= NBR_MIN points. One load round.
//  2) Scan window(r) via contiguous x-run spans, candidate-even over lanes,
//     chunked LDS row staging.
//  3) One termination check. On failure: exact d8 -> required radius r2
//     (margin >= sqrt(d8_real) per unclipped direction, else clipped),
//     reset lists, seed tau=d8, full rescan window(r2). Provably exact;
//     worst wave ~= 2 window scans (r4's straggler tail eliminated).
// Lex (d, idx) order everywhere -> invariant to scatter order; matches
// stable top_k ties.
// ---------------------------------------------------------------------------
__device__ __forceinline__ int sat_at(const int* __restrict__ sat, int x, int y, int z) {
    if (x < 0 || y < 0 || z < 0) return 0;
    return sat[(z * GRID_R + y) * GRID_R + x];
}

__device__ __forceinline__ int boxcount(const int* __restrict__ sat,
                                        int x0, int x1, int y0, int y1, int z0, int z1) {
    return sat_at(sat, x1, y1, z1) - sat_at(sat, x0 - 1, y1, z1)
         - sat_at(sat, x1, y0 - 1, z1) - sat_at(sat, x1, y1, z0 - 1)
         + sat_at(sat, x0 - 1, y0 - 1, z1) + sat_at(sat, x0 - 1, y1, z0 - 1)
         + sat_at(sat, x1, y0 - 1, z0 - 1) - sat_at(sat, x0 - 1, y0 - 1, z0 - 1);
}

template <typename T>
__device__ void knn_body(const T* __restrict__ pos,
                         const int* __restrict__ cstart, const int* __restrict__ sat,
                         const float4* __restrict__ pts4, const int* __restrict__ pid,
                         int* __restrict__ idx_out,
                         int* __restrict__ rs, int* __restrict__ pf) {
    const int tid  = threadIdx.x;
    const int lane = tid & 63;
    const int i    = blockIdx.x * 4 + (tid >> 6);

    const float pix = ldf(pos, 3 * i + 0);
    const float piy = ldf(pos, 3 * i + 1);
    const float piz = ldf(pos, 3 * i + 2);
    const float sqi = fmaf(pix, pix, fmaf(piy, piy, piz * piz));
    const int cx = cell_of(pix), cy = cell_of(piy), cz = cell_of(piz);

    float bd[KNN];
    int   bi[KNN];
#pragma unroll
    for (int q = 0; q < KNN; ++q) { bd[q] = INFINITY; bi[q] = 0x7fffffff; }
    float tau = INFINITY;

    auto do_insert = [&](float d, int pj) {
        float cd = d; int ci = pj;
#pragma unroll
        for (int q = 0; q < KNN; ++q) {
            const bool ins = (cd < bd[q]) || (cd == bd[q] && ci < bi[q]);
            const float nd = ins ? cd : bd[q];
            const int   ni = ins ? ci : bi[q];
            const float od = ins ? bd[q] : cd;
            const int   oi = ins ? bi[q] : ci;
            bd[q] = nd; bi[q] = ni; cd = od; ci = oi;
        }
        tau = fminf(tau, bd[KNN - 1]);
    };

    // window scan: contiguous x-run spans, chunked LDS staging, even lanes.
    auto scan_win = [&](int rr) {
        const int x0 = max(cx - rr, 0), x1 = min(cx + rr, GRID_R - 1);
        const int y0 = max(cy - rr, 0), y1 = min(cy + rr, GRID_R - 1);
        const int z0 = max(cz - rr, 0), z1 = min(cz + rr, GRID_R - 1);
        const int ny = y1 - y0 + 1;
        const int R  = ny * (z1 - z0 + 1);
        const int xs = x1 - x0 + 1;
        for (int cb = 0; cb < R; cb += MAXROWS) {
            const int CR = min(MAXROWS, R - cb);
            asm volatile("s_waitcnt lgkmcnt(0)" ::: "memory");  // prev chunk reads done
            int Mtot = 0;
            for (int lr0 = 0; lr0 < CR; lr0 += 64) {
                const int lr = lr0 + lane;
                int cnt_r = 0, st_r = 0;
                if (lr < CR) {
                    const int row = cb + lr;
                    const int iz = row / ny;
                    const int iy = row - iz * ny;
                    const int c0 = ((z0 + iz) * GRID_R + (y0 + iy)) * GRID_R + x0;
                    st_r  = cstart[c0];
                    cnt_r = cstart[c0 + xs] - st_r;
                }
                int pv = cnt_r;
#pragma unroll
                for (int s = 1; s < 64; s <<= 1) {
                    const int u = __shfl_up(pv, s, 64);
                    if (lane >= s) pv += u;
                }
                if (lr < CR) { rs[lr] = st_r; pf[lr + 1] = Mtot + pv; }
                Mtot += __shfl(pv, 63, 64);
            }
            asm volatile("s_waitcnt lgkmcnt(0)" ::: "memory");  // staging visible
            int p = 0, cur = 0;
            int nxt = pf[1];
            int rst = rs[0];
            for (int t = lane; t < Mtot; t += 64) {
                while (nxt <= t) { ++p; cur = nxt; nxt = pf[p + 1]; rst = rs[p]; }
                const int si = rst + (t - cur);
                const float4 cq = pts4[si];
                const int    pj = pid[si];
                const float d = fmaf(cq.x, pix, fmaf(cq.y, piy, fmaf(cq.z, piz, cq.w)));
                if (pj != i && d <= tau) do_insert(d, pj);
            }
        }
    };

    // ---- 1) parallel SAT radius probe ----
    int r;
    {
        const int rl = min(lane + 1, GRID_R);
        const int bx0 = max(cx - rl, 0), bx1 = min(cx + rl, GRID_R - 1);
        const int by0 = max(cy - rl, 0), by1 = min(cy + rl, GRID_R - 1);
        const int bz0 = max(cz - rl, 0), bz1 = min(cz + rl, GRID_R - 1);
        const int cntl = boxcount(sat, bx0, bx1, by0, by1, bz0, bz1);
        const unsigned long long m = __ballot(cntl >= NBR_MIN);
        r = m ? min((int)__ffsll(m), GRID_R) : GRID_R;
    }

    // ---- 2) window scan at r ----
    scan_win(r);

    // ---- 3) termination; exact bounded second pass on failure ----
    {
        float wtau = bd[KNN - 1];
#pragma unroll
        for (int s = 1; s < 64; s <<= 1) wtau = fminf(wtau, __shfl_xor(wtau, s, 64));

        float mg = INFINITY;
        bool full = true;
        if (cx - r > 0)          { mg = fminf(mg, pix - (GLO + (float)(cx - r) * CELL_E));     full = false; }
        if (cx + r < GRID_R - 1) { mg = fminf(mg, (GLO + (float)(cx + r + 1) * CELL_E) - pix); full = false; }
        if (cy - r > 0)          { mg = fminf(mg, piy - (GLO + (float)(cy - r) * CELL_E));     full = false; }
        if (cy + r < GRID_R - 1) { mg = fminf(mg, (GLO + (float)(cy + r + 1) * CELL_E) - piy); full = false; }
        if (cz - r > 0)          { mg = fminf(mg, piz - (GLO + (float)(cz - r) * CELL_E));     full = false; }
        if (cz + r < GRID_R - 1) { mg = fminf(mg, (GLO + (float)(cz + r + 1) * CELL_E) - piz); full = false; }

        bool done = full;
        float d8 = INFINITY;
        if (!full) {
            const float mge  = mg - 1e-5f;
            const float need = mge * mge - sqi;   // d_real < mge^2  <=>  d' < need
            if (wtau < need) {
                done = true;
            } else {
                // exact global 8th-best (d' space) via destructive merge of copies
                float cd2[KNN]; int ci2[KNN];
#pragma unroll
                for (int q = 0; q < KNN; ++q) { cd2[q] = bd[q]; ci2[q] = bi[q]; }
#pragma unroll
                for (int k = 0; k < KNN; ++k) {
                    float dw = cd2[0];
                    int   iw = ci2[0];
#pragma unroll
                    for (int s = 1; s < 64; s <<= 1) {
                        const float od = __shfl_xor(dw, s, 64);
                        const int   oi = __shfl_xor(iw, s, 64);
                        if (od < dw || (od == dw && oi < iw)) { dw = od; iw = oi; }
                    }
                    if (cd2[0] == dw && ci2[0] == iw) {
#pragma unroll
                        for (int q = 0; q < KNN - 1; ++q) { cd2[q] = cd2[q + 1]; ci2[q] = ci2[q + 1]; }
                        cd2[KNN - 1] = INFINITY; ci2[KNN - 1] = 0x7fffffff;
                    }
                    d8 = dw;
                }
                if (d8 < need) done = true;
            }
        }

        if (!done) {
            // required radius: per direction, margin >= s2 or clipped.
            float s2 = sqrtf(fmaxf(d8 + sqi, 0.0f)) + 1e-4f;  // real-distance bound
            s2 = fminf(s2, 9.0f);                              // cap -> full grid
            auto dneed = [&](float frac, int clip) -> int {
                int nd = (int)ceilf((s2 - frac) * CELL_INV);
                nd = max(nd, 0);
                return min(nd, clip);
            };
            const float fxm = pix - (GLO + (float)cx * CELL_E);
            const float fxp = (GLO + (float)(cx + 1) * CELL_E) - pix;
            const float fym = piy - (GLO + (float)cy * CELL_E);
            const float fyp = (GLO + (float)(cy + 1) * CELL_E) - piy;
            const float fzm = piz - (GLO + (float)cz * CELL_E);
            const float fzp = (GLO + (float)(cz + 1) * CELL_E) - piz;
            int r2 = r + 1;
            r2 = max(r2, dneed(fxm, cx));
            r2 = max(r2, dneed(fxp, GRID_R - 1 - cx));
            r2 = max(r2, dneed(fym, cy));
            r2 = max(r2, dneed(fyp, GRID_R - 1 - cy));
            r2 = max(r2, dneed(fzm, cz));
            r2 = max(r2, dneed(fzp, GRID_R - 1 - cz));
            r2 = min(r2, GRID_R);

            // fresh lists; tau seeded with pass-1 d8 (superset window => exact)
#pragma unroll
            for (int q = 0; q < KNN; ++q) { bd[q] = INFINITY; bi[q] = 0x7fffffff; }
            tau = d8;
            scan_win(r2);
        }
    }

    // ---- final merge of 64 sorted lists (lex), emit top-8 ----
#pragma unroll
    for (int k = 0; k < KNN; ++k) {
        float dw = bd[0];
        int   iw = bi[0];
#pragma unroll
        for (int s = 1; s < 64; s <<= 1) {
            const float od = __shfl_xor(dw, s, 64);
            const int   oi = __shfl_xor(iw, s, 64);
            if (od < dw || (od == dw && oi < iw)) { dw = od; iw = oi; }
        }
        if (bd[0] == dw && bi[0] == iw) {
#pragma unroll
            for (int q = 0; q < KNN - 1; ++q) { bd[q] = bd[q + 1]; bi[q] = bi[q + 1]; }
            bd[KNN - 1] = INFINITY; bi[KNN - 1] = 0x7fffffff;
        }
        if (lane == 0) idx_out[i * 9 + k] = clamp_idx(iw);
    }
    if (lane == 0) idx_out[i * 9 + 8] = i;
}

__global__ __launch_bounds__(256) void knn_grid_kernel(const void* __restrict__ pos,
                                                       const int* __restrict__ flag,
                                                       const int* __restrict__ cstart,
                                                       const int* __restrict__ sat,
                                                       const float4* __restrict__ pts4,
                                                       const int* __restrict__ pid,
                                                       int* __restrict__ idx_out) {
    __shared__ int rs[4][MAXROWS];
    __shared__ int pf[4][MAXROWS + 1];
    const int wv = threadIdx.x >> 6;
    if (get_dt(flag) == DT_BF16)
        knn_body<__hip_bfloat16>((const __hip_bfloat16*)pos, cstart, sat, pts4, pid, idx_out,
                                 rs[wv], pf[wv]);
    else
        knn_body<float>((const float*)pos, cstart, sat, pts4, pid, idx_out, rs[wv], pf[wv]);
}

// ---------------------------------------------------------------------------
// conv1 (unchanged): first layer factored
//   h1[n] = relu( pos_j@(Wtop+Wbot) - pos_i@Wbot + bA )
// ---------------------------------------------------------------------------
struct Conv1Smem {
    alignas(16) float wB[32 * 64];
    alignas(16) float h1s[4][9 * 32];
    alignas(16) float wsum[3 * 32];
    alignas(16) float wbot[3 * 32];
    alignas(16) float posn[4][9][3];
    float bA[32];
    float bB[64];
};

template <typename T>
__device__ void conv1_body(const T* __restrict__ pos, const int* __restrict__ idx,
                           const T* __restrict__ W1a, const T* __restrict__ b1a,
                           const T* __restrict__ W1b, const T* __restrict__ b1b,
                           float* __restrict__ x1, Conv1Smem& s) {
    const int tid = threadIdx.x;
    for (int e = tid; e < 96; e += 256) {
        const float bot = ldf(W1a, 96 + e);
        s.wsum[e] = ldf(W1a, e) + bot;
        s.wbot[e] = bot;
    }
    if (tid < 32) s.bA[tid] = ldf(b1a, tid);
    for (int e = tid; e < 2048; e += 256) s.wB[e] = ldf(W1b, e);
    if (tid < 64) s.bB[tid] = ldf(b1b, tid);

    const int tl   = tid >> 6;
    const int lane = tid & 63;
    const int i    = blockIdx.x * 4 + tl;

    if (lane < 27) {
        const int n = lane / 3, c = lane % 3;
        const int j = clamp_idx(idx[i * 9 + n]);
        s.posn[tl][n][c] = ldf(pos, 3 * j + c);
    }
    const float pi0 = ldf(pos, 3 * i + 0);
    const float pi1 = ldf(pos, 3 * i + 1);
    const float pi2 = ldf(pos, 3 * i + 2);
    __syncthreads();

    for (int e = lane; e < 288; e += 64) {
        const int n = e >> 5, k = e & 31;
        float b = fmaf(pi0, s.wbot[k], fmaf(pi1, s.wbot[32 + k], pi2 * s.wbot[64 + k]));
        float v = s.bA[k] - b;
        v = fmaf(s.posn[tl][n][0], s.wsum[k], v);
        v = fmaf(s.posn[tl][n][1], s.wsum[32 + k], v);
        v = fmaf(s.posn[tl][n][2], s.wsum[64 + k], v);
        s.h1s[tl][n * 32 + k] = fmaxf(v, 0.0f);
    }
    __syncthreads();

    float wcol[32];
#pragma unroll
    for (int k = 0; k < 32; ++k) wcol[k] = s.wB[k * 64 + lane];

    float acc = -INFINITY;
    for (int n = 0; n < 9; ++n) {
        float v = s.bB[lane];
#pragma unroll
        for (int k = 0; k < 32; ++k) v = fmaf(s.h1s[tl][n * 32 + k], wcol[k], v);
        acc = fmaxf(acc, v);
    }
    x1[i * 64 + lane] = fmaxf(acc, 0.0f);
}

__global__ __launch_bounds__(256) void conv1_kernel(const void* __restrict__ pos,
                                                    const int* __restrict__ flag,
                                                    const int* __restrict__ idx,
                                                    const void* __restrict__ W1a,
                                                    const void* __restrict__ b1a,
                                                    const void* __restrict__ W1b,
                                                    const void* __restrict__ b1b,
                                                    float* __restrict__ x1) {
    __shared__ Conv1Smem s;
    if (get_dt(flag) == DT_BF16)
        conv1_body<__hip_bfloat16>((const __hip_bfloat16*)pos, idx,
            (const __hip_bfloat16*)W1a, (const __hip_bfloat16*)b1a,
            (const __hip_bfloat16*)W1b, (const __hip_bfloat16*)b1b, x1, s);
    else
        conv1_body<float>((const float*)pos, idx, (const float*)W1a, (const float*)b1a,
            (const float*)W1b, (const float*)b1b, x1, s);
}

// ---------------------------------------------------------------------------
// zw (unchanged): per-point precompute for conv2's first layer.
// ---------------------------------------------------------------------------
struct ZwSmem {
    alignas(16) float wA[67 * 64];
    alignas(16) float xrT[4][68][4];
    float bA[64];
};

template <typename T>
__device__ void zw_body(const T* __restrict__ pos, const T* __restrict__ W2a,
                        const T* __restrict__ b2a, float* __restrict__ x1, ZwSmem& s) {
    const int tid  = threadIdx.x;
    const int wv   = tid >> 6;
    const int lane = tid & 63;
    const int j0   = blockIdx.x * 16 + wv * 4;

    for (int e = tid; e < 4288; e += 256) s.wA[e] = ldf(W2a, e);
    if (tid < 64) s.bA[tid] = ldf(b2a, tid);

#pragma unroll
    for (int p = 0; p < 4; ++p)
        s.xrT[wv][lane][p] = x1[(j0 + p) * 64 + lane];
    if (lane < 12) {
        const int p = lane / 3, c = lane % 3;
        s.xrT[wv][64 + c][p] = ldf(pos, 3 * (j0 + p) + c);
    }
    __syncthreads();

    float a0 = s.bA[lane], a1 = a0, a2 = a0, a3 = a0;
    for (int c = 0; c < 67; ++c) {
        const float w = s.wA[c * 64 + lane];
        const float4 xv = *(const float4*)&s.xrT[wv][c][0];
        a0 = fmaf(xv.x, w, a0);
        a1 = fmaf(xv.y, w, a1);
        a2 = fmaf(xv.z, w, a2);
        a3 = fmaf(xv.w, w, a3);
    }
    x1[(j0 + 0) * 64 + lane] = a0;
    x1[(j0 + 1) * 64 + lane] = a1;
    x1[(j0 + 2) * 64 + lane] = a2;
    x1[(j0 + 3) * 64 + lane] = a3;
}

__global__ __launch_bounds__(256) void zw_kernel(const void* __restrict__ pos,
                                                 const int* __restrict__ flag,
                                                 const void* __restrict__ W2a,
                                                 const void* __restrict__ b2a,
                                                 float* __restrict__ x1) {
    __shared__ ZwSmem s;
    if (get_dt(flag) == DT_BF16)
        zw_body<__hip_bfloat16>((const __hip_bfloat16*)pos, (const __hip_bfloat16*)W2a,
                                (const __hip_bfloat16*)b2a, x1, s);
    else
        zw_body<float>((const float*)pos, (const float*)W2a, (const float*)b2a, x1, s);
}

// ---------------------------------------------------------------------------
// conv2+head (unchanged): h1[n] = relu(zw[j_n] - pos_i@W2a_bot).
// ---------------------------------------------------------------------------
struct Conv2Smem {
    alignas(16) float h1s[4][9 * 64];
    alignas(16) float row[4][128];
    alignas(16) float wbot[3 * 64];
    alignas(16) float wc[640];
    float bcs[5];
    float sv[4][5];
    int   nb[4][9];
};

template <typename T>
__device__ void conv2_body(const T* __restrict__ pos, const int* __restrict__ idx,
                           const float* __restrict__ zw,
                           const T* __restrict__ W2a, const T* __restrict__ W2b,
                           const T* __restrict__ b2b, const T* __restrict__ Wc,
                           const T* __restrict__ bc, T* __restrict__ out, Conv2Smem& s) {
    const int tid  = threadIdx.x;
    const int l    = tid & 127;
    const int half = tid >> 7;

    float wcol[64];
#pragma unroll
    for (int k = 0; k < 64; ++k) wcol[k] = ldf(W2b, k * 128 + l);
    const float bBl = ldf(b2b, l);

    for (int e = tid; e < 192; e += 256) s.wbot[e] = ldf(W2a, 4096 + e);
    for (int e = tid; e < 640; e += 256) s.wc[e] = ldf(Wc, e);
    if (tid < 5) s.bcs[tid] = ldf(bc, tid);

    const int tl   = tid >> 6;
    const int lane = tid & 63;
    const int i    = blockIdx.x * 4 + tl;

    if (lane < 9) s.nb[tl][lane] = clamp_idx(idx[i * 9 + lane]);
    const float pi0 = ldf(pos, 3 * i + 0);
    const float pi1 = ldf(pos, 3 * i + 1);
    const float pi2 = ldf(pos, 3 * i + 2);
    __syncthreads();

    {
        const float vi = fmaf(pi0, s.wbot[lane], fmaf(pi1, s.wbot[64 + lane], pi2 * s.wbot[128 + lane]));
#pragma unroll
        for (int n = 0; n < 9; ++n) {
            const int j = s.nb[tl][n];
            s.h1s[tl][n * 64 + lane] = fmaxf(zw[j * 64 + lane] - vi, 0.0f);
        }
    }
    __syncthreads();

#pragma unroll
    for (int tt = 0; tt < 2; ++tt) {
        const int tgt = half * 2 + tt;
        float acc = -INFINITY;
        for (int n = 0; n < 9; ++n) {
            float v = bBl;
            for (int k = 0; k < 64; k += 4) {
                const float4 hv = *(const float4*)&s.h1s[tgt][n * 64 + k];
                v = fmaf(hv.x, wcol[k + 0], v);
                v = fmaf(hv.y, wcol[k + 1], v);
                v = fmaf(hv.z, wcol[k + 2], v);
                v = fmaf(hv.w, wcol[k + 3], v);
            }
            acc = fmaxf(acc, v);
        }
        s.row[tgt][l] = fmaxf(acc, 0.0f);
    }
    __syncthreads();

    if (tid < 20) {
        const int tgt = tid / 5, o = tid % 5;
        float v = s.bcs[o];
        for (int k = 0; k < 128; ++k) v = fmaf(s.row[tgt][k], s.wc[k * 5 + o], v);
        s.sv[tgt][o] = v;
    }
    __syncthreads();
    if (tid < 20) {
        const int tgt = tid / 5, o = tid % 5;
        float m = s.sv[tgt][0];
#pragma unroll
        for (int q = 1; q < 5; ++q) m = fmaxf(m, s.sv[tgt][q]);
        float sum = 0.0f;
#pragma unroll
        for (int q = 0; q < 5; ++q) sum += expf(s.sv[tgt][q] - m);
        const float lse = m + logf(sum);
        stf(out, (blockIdx.x * 4 + tgt) * 5 + o, s.sv[tgt][o] - lse);
    }
}

__global__ __launch_bounds__(256) void conv2_head_kernel(const void* __restrict__ pos,
                                                         const int* __restrict__ flag,
                                                         const int* __restrict__ idx,
                                                         const float* __restrict__ zw,
                                                         const void* __restrict__ W2a,
                                                         const void* __restrict__ W2b,
                                                         const void* __restrict__ b2b,
                                                         const void* __restrict__ Wc,
                                                         const void* __restrict__ bc,
                                                         void* __restrict__ out) {
    __shared__ Conv2Smem s;
    if (get_dt(flag) == DT_BF16)
        conv2_body<__hip_bfloat16>((const __hip_bfloat16*)pos, idx, zw,
            (const __hip_bfloat16*)W2a, (const __hip_bfloat16*)W2b, (const __hip_bfloat16*)b2b,
            (const __hip_bfloat16*)Wc, (const __hip_bfloat16*)bc, (__hip_bfloat16*)out, s);
    else
        conv2_body<float>((const float*)pos, idx, zw, (const float*)W2a, (const float*)W2b,
            (const float*)b2b, (const float*)Wc, (const float*)bc, (float*)out, s);
}

// ---------------------------------------------------------------------------
extern "C" void kernel_launch(void* const* d_in, const int* in_sizes, int n_in,
                              void* d_out, int out_size, void* d_ws, size_t ws_size,
                              hipStream_t stream) {
    if (ws_size < (size_t)WS_NEEDED) return;

    char* ws = (char*)d_ws;
    int*    flag     = (int*)(ws + WS_FLAG_OFF);
    int*    idx      = (int*)(ws + WS_IDX_OFF);
    float*  x1       = (float*)(ws + WS_X1_OFF);
    int*    sat      = (int*)(ws + WS_SAT_OFF);
    int*    cstart   = (int*)(ws + WS_START_OFF);
    int*    cursor   = (int*)(ws + WS_CURSOR_OFF);
    int*    pid      = (int*)(ws + WS_PID_OFF);
    float4* pts4     = (float4*)(ws + WS_PTS_OFF);
    int*    rowtot   = (int*)(ws + WS_ROWTOT_OFF);
    int*    rowstart = (int*)(ws + WS_ROWSTART_OFF);

    zero_kernel<<<NCELLS / 256, 256, 0, stream>>>(sat, flag);
    sniff_kernel<<<64, 256, 0, stream>>>((const unsigned short*)d_in[0], flag);
    grid_count_kernel<<<N_PTS / 256, 256, 0, stream>>>(d_in[0], flag, sat);
    rowscan_kernel<<<NROWS2D / 256, 256, 0, stream>>>(sat, rowtot);
    rowoffset_kernel<<<1, 256, 0, stream>>>(rowtot, rowstart);
    cellstart_kernel<<<NROWS2D / 256, 256, 0, stream>>>(sat, rowstart, cstart, cursor);
    saty_kernel<<<NROWS2D / 256, 256, 0, stream>>>(sat);
    satz_kernel<<<NROWS2D / 256, 256, 0, stream>>>(sat);
    grid_scatter_kernel<<<N_PTS / 256, 256, 0, stream>>>(d_in[0], flag, cursor, pts4, pid);
    knn_grid_kernel<<<N_PTS / 4, 256, 0, stream>>>(d_in[0], flag, cstart, sat, pts4, pid, idx);
    conv1_kernel<<<N_PTS / 4, 256, 0, stream>>>(d_in[0], flag, idx,
        d_in[1], d_in[2], d_in[3], d_in[4], x1);
    zw_kernel<<<N_PTS / 16, 256, 0, stream>>>(d_in[0], flag, d_in[5], d_in[6], x1);
    conv2_head_kernel<<<N_PTS / 4, 256, 0, stream>>>(d_in[0], flag, idx, x1,
        d_in[5], d_in[7], d_in[8], d_in[9], d_in[10], d_out);
}

// Round 6
// 274.266 us; speedup vs baseline: 1.4302x; 1.0102x over previous
//
#include <hip/hip_runtime.h>
#include <hip/hip_bf16.h>
#include <math.h>

#define N_PTS 16384
#define KNN 8

#define DT_BF16 1
#define DT_FP32 2

// Workspace layout:
//   flag : int          @ 0
//   idx  : int  [N*9]   @ 64        -> 589,824 B
//   x1   : f32  [N*64]  @ 589,888   -> 4,194,304 B
// Grid-KNN scratch lives INSIDE the x1 region (dead before conv1 writes x1):
//   sat      : int [110592]  @ x1+0        (counts -> x-prefix -> full 3D SAT)
//   start    : int [110593]  @ x1+442368   (cell starts + sentinel)
//   cursor   : int [110592]  @ x1+884800
//   pid      : int [16384]   @ x1+1327168
//   pts4     : f4  [16384]   @ x1+1392704
//   rowtot   : int [2304]    @ x1+1654848
//   rowstart : int [2304]    @ x1+1664064  (end 1,673,280 <= 4,194,304)
#define WS_FLAG_OFF 0
#define WS_IDX_OFF  64
#define WS_X1_OFF   589888
#define WS_NEEDED   4784192

#define WS_SAT_OFF      (WS_X1_OFF)
#define WS_START_OFF    (WS_X1_OFF + 442368)
#define WS_CURSOR_OFF   (WS_X1_OFF + 884800)
#define WS_PID_OFF      (WS_X1_OFF + 1327168)
#define WS_PTS_OFF      (WS_X1_OFF + 1392704)
#define WS_ROWTOT_OFF   (WS_X1_OFF + 1654848)
#define WS_ROWSTART_OFF (WS_X1_OFF + 1664064)

#define GRID_R   48
#define NROWS2D  (GRID_R * GRID_R)          // 2304 (y,z) rows
#define NCELLS   (GRID_R * GRID_R * GRID_R) // 110592
#define GLO      -4.5f
#define CELL_E   0.1875f
#define CELL_INV 5.3333335f
#define NBR_MIN  26   // SAT window population target (incl. self)
#define MAXROWS  289  // LDS row-staging chunk

__device__ __forceinline__ float bf2f(__hip_bfloat16 v) { return __bfloat162float(v); }

__device__ __forceinline__ float ldf(const float* p, int i) { return p[i]; }
__device__ __forceinline__ float ldf(const __hip_bfloat16* p, int i) { return bf2f(p[i]); }
__device__ __forceinline__ void stf(float* p, int i, float v) { p[i] = v; }
__device__ __forceinline__ void stf(__hip_bfloat16* p, int i, float v) { p[i] = __float2bfloat16(v); }

__device__ __forceinline__ int clamp_idx(int j) {
    return ((unsigned)j < (unsigned)N_PTS) ? j : 0;
}

__device__ __forceinline__ int cell_of(float v) {
    int c = (int)((v - GLO) * CELL_INV);
    return min(max(c, 0), GRID_R - 1);
}

// flag[0] holds the sniffer's bad-count; >16 => fp32 input.
__device__ __forceinline__ int get_dt(const int* flag) {
    return (flag[0] > 16) ? DT_FP32 : DT_BF16;
}

// ---------------------------------------------------------------------------
// zero: cnt[] and flag.
// ---------------------------------------------------------------------------
__global__ __launch_bounds__(256) void zero_kernel(int* __restrict__ cnt, int* __restrict__ flag) {
    const int e = blockIdx.x * 256 + threadIdx.x;
    cnt[e] = 0;
    if (e == 0) flag[0] = 0;
}

// ---------------------------------------------------------------------------
// sniff (multi-block).
// ---------------------------------------------------------------------------
__global__ __launch_bounds__(256) void sniff_kernel(const unsigned short* __restrict__ posu,
                                                    int* __restrict__ flag) {
    __shared__ int red[256];
    int local = 0;
    for (int e = blockIdx.x * 256 + threadIdx.x; e < 3 * N_PTS; e += 64 * 256) {
        const float v = __uint_as_float(((unsigned)posu[e]) << 16);
        if (!(fabsf(v) <= 64.0f)) local++;
    }
    red[threadIdx.x] = local;
    __syncthreads();
    for (int s = 128; s > 0; s >>= 1) {
        if (threadIdx.x < s) red[threadIdx.x] += red[threadIdx.x + s];
        __syncthreads();
    }
    if (threadIdx.x == 0 && red[0] > 0) atomicAdd(flag, red[0]);
}

// ---------------------------------------------------------------------------
// Grid build (parallel): count -> rowscan -> rowoffset -> cellstart ->
// saty -> satz -> scatter.
// ---------------------------------------------------------------------------
template <typename T>
__device__ __forceinline__ void count_body(const T* __restrict__ pos, int* __restrict__ cnt) {
    const int i = blockIdx.x * 256 + threadIdx.x;
    const float x = ldf(pos, 3 * i + 0);
    const float y = ldf(pos, 3 * i + 1);
    const float z = ldf(pos, 3 * i + 2);
    const int c = (cell_of(z) * GRID_R + cell_of(y)) * GRID_R + cell_of(x);
    atomicAdd(&cnt[c], 1);
}

__global__ __launch_bounds__(256) void grid_count_kernel(const void* __restrict__ pos,
                                                         const int* __restrict__ flag,
                                                         int* __restrict__ cnt) {
    if (get_dt(flag) == DT_BF16) count_body<__hip_bfloat16>((const __hip_bfloat16*)pos, cnt);
    else                         count_body<float>((const float*)pos, cnt);
}

// x-prefix per row (in place over sat), rowtot[row] = row sum.
__global__ __launch_bounds__(256) void rowscan_kernel(int* __restrict__ sat,
                                                      int* __restrict__ rowtot) {
    const int t = blockIdx.x * 256 + threadIdx.x;   // row < 2304
    const int rb = t * GRID_R;
    int acc = 0;
    for (int x = 0; x < GRID_R; ++x) { acc += sat[rb + x]; sat[rb + x] = acc; }
    rowtot[t] = acc;
}

// exclusive scan of 2304 row totals (one block, 256 threads x 9 rows).
__global__ __launch_bounds__(256) void rowoffset_kernel(const int* __restrict__ rowtot,
                                                        int* __restrict__ rowstart) {
    __shared__ int part[256];
    const int t = threadIdx.x;
    int loc[9]; int s = 0;
#pragma unroll
    for (int k = 0; k < 9; ++k) { loc[k] = rowtot[t * 9 + k]; s += loc[k]; }
    part[t] = s;
    __syncthreads();
    for (int off = 1; off < 256; off <<= 1) {
        int v = (t >= off) ? part[t - off] : 0;
        __syncthreads();
        part[t] += v;
        __syncthreads();
    }
    int run = (t == 0) ? 0 : part[t - 1];
#pragma unroll
    for (int k = 0; k < 9; ++k) { rowstart[t * 9 + k] = run; run += loc[k]; }
}

// cstart/cursor per cell = rowstart + in-row exclusive x-prefix; sentinel.
__global__ __launch_bounds__(256) void cellstart_kernel(const int* __restrict__ satx,
                                                        const int* __restrict__ rowstart,
                                                        int* __restrict__ cstart,
                                                        int* __restrict__ cursor) {
    const int t = blockIdx.x * 256 + threadIdx.x;   // row < 2304
    const int rb = t * GRID_R;
    const int base = rowstart[t];
    int prev = 0;
    for (int x = 0; x < GRID_R; ++x) {
        const int v = base + prev;
        cstart[rb + x] = v;
        cursor[rb + x] = v;
        prev = satx[rb + x];
    }
    if (t == NROWS2D - 1) cstart[NCELLS] = base + prev;
}

// SAT pass 2: prefix along y.
__global__ __launch_bounds__(256) void saty_kernel(int* __restrict__ sat) {
    const int t = blockIdx.x * 256 + threadIdx.x;   // < 2304
    const int z = t / GRID_R, x = t - z * GRID_R;
    const int base = z * NROWS2D + x;
    int run = 0;
#pragma unroll
    for (int y = 0; y < GRID_R; ++y) {
        run += sat[base + y * GRID_R];
        sat[base + y * GRID_R] = run;
    }
}

// SAT pass 3: prefix along z.
__global__ __launch_bounds__(256) void satz_kernel(int* __restrict__ sat) {
    const int t = blockIdx.x * 256 + threadIdx.x;   // < 2304
    int run = 0;
#pragma unroll
    for (int z = 0; z < GRID_R; ++z) {
        run += sat[t + z * NROWS2D];
        sat[t + z * NROWS2D] = run;
    }
}

template <typename T>
__device__ __forceinline__ void scatter_body(const T* __restrict__ pos, int* __restrict__ cursor,
                                             float4* __restrict__ pts4, int* __restrict__ pid) {
    const int i = blockIdx.x * 256 + threadIdx.x;
    const float x = ldf(pos, 3 * i + 0);
    const float y = ldf(pos, 3 * i + 1);
    const float z = ldf(pos, 3 * i + 2);
    const int c = (cell_of(z) * GRID_R + cell_of(y)) * GRID_R + cell_of(x);
    const int slot = atomicAdd(&cursor[c], 1);
    const float sq = fmaf(x, x, fmaf(y, y, z * z));
    pts4[slot] = make_float4(-2.0f * x, -2.0f * y, -2.0f * z, sq);
    pid[slot] = i;
}

__global__ __launch_bounds__(256) void grid_scatter_kernel(const void* __restrict__ pos,
                                                           const int* __restrict__ flag,
                                                           int* __restrict__ cursor,
                                                           float4* __restrict__ pts4,
                                                           int* __restrict__ pid) {
    if (get_dt(flag) == DT_BF16) scatter_body<__hip_bfloat16>((const __hip_bfloat16*)pos, cursor, pts4, pid);
    else                         scatter_body<float>((const float*)pos, cursor, pts4, pid);
}

// ---------------------------------------------------------------------------
// KNN v7: TWO targets per wave (32-lane subgroups) + fused single merge.
// r5 counters: knn was per-target-overhead bound (~3000 instr/wave for ~150
// insert-chain instr of useful scan). v7: (a) all wave-collective per-target
// costs (probe ballot, staging prefix, merge butterflies) are shared by two
// targets in one wave -> per-target overhead halved, 5-level butterflies;
// (b) the exact-d8 merge IS the output (picks captured in order) -> one
// merge per target in the common path (was two; the old wtau fast path was
// dead code since per-lane lists rarely fill).
// Lex (d, idx) order everywhere -> invariant to scatter order; matches
// stable top_k ties. Exact second-pass fallback unchanged.
// ---------------------------------------------------------------------------
__device__ __forceinline__ int sat_at(const int* __restrict__ sat, int x, int y, int z) {
    if (x < 0 || y < 0 || z < 0) return 0;
    return sat[(z * GRID_R + y) * GRID_R + x];
}

__device__ __forceinline__ int boxcount(const int* __restrict__ sat,
                                        int x0, int x1, int y0, int y1, int z0, int z1) {
    return sat_at(sat, x1, y1, z1) - sat_at(sat, x0 - 1, y1, z1)
         - sat_at(sat, x1, y0 - 1, z1) - sat_at(sat, x1, y1, z0 - 1)
         + sat_at(sat, x0 - 1, y0 - 1, z1) + sat_at(sat, x0 - 1, y1, z0 - 1)
         + sat_at(sat, x1, y0 - 1, z0 - 1) - sat_at(sat, x0 - 1, y0 - 1, z0 - 1);
}

template <typename T>
__device__ void knn_body(const T* __restrict__ pos,
                         const int* __restrict__ cstart, const int* __restrict__ sat,
                         const float4* __restrict__ pts4, const int* __restrict__ pid,
                         int* __restrict__ idx_out,
                         int* __restrict__ rs, int* __restrict__ pf) {
    const int tid  = threadIdx.x;
    const int lane = tid & 31;                 // lane within 32-lane subgroup
    const int i    = blockIdx.x * 8 + (tid >> 5);

    const float pix = ldf(pos, 3 * i + 0);
    const float piy = ldf(pos, 3 * i + 1);
    const float piz = ldf(pos, 3 * i + 2);
    const float sqi = fmaf(pix, pix, fmaf(piy, piy, piz * piz));
    const int cx = cell_of(pix), cy = cell_of(piy), cz = cell_of(piz);

    float bd[KNN];
    int   bi[KNN];
#pragma unroll
    for (int q = 0; q < KNN; ++q) { bd[q] = INFINITY; bi[q] = 0x7fffffff; }
    float tau = INFINITY;

    auto do_insert = [&](float d, int pj) {
        float cd = d; int ci = pj;
#pragma unroll
        for (int q = 0; q < KNN; ++q) {
            const bool ins = (cd < bd[q]) || (cd == bd[q] && ci < bi[q]);
            const float nd = ins ? cd : bd[q];
            const int   ni = ins ? ci : bi[q];
            const float od = ins ? bd[q] : cd;
            const int   oi = ins ? bi[q] : ci;
            bd[q] = nd; bi[q] = ni; cd = od; ci = oi;
        }
        tau = fminf(tau, bd[KNN - 1]);
    };

    // window scan: contiguous x-run spans, chunked LDS staging, even lanes.
    auto scan_win = [&](int rr) {
        const int x0 = max(cx - rr, 0), x1 = min(cx + rr, GRID_R - 1);
        const int y0 = max(cy - rr, 0), y1 = min(cy + rr, GRID_R - 1);
        const int z0 = max(cz - rr, 0), z1 = min(cz + rr, GRID_R - 1);
        const int ny = y1 - y0 + 1;
        const int R  = ny * (z1 - z0 + 1);
        const int xs = x1 - x0 + 1;
        for (int cb = 0; cb < R; cb += MAXROWS) {
            const int CR = min(MAXROWS, R - cb);
            asm volatile("s_waitcnt lgkmcnt(0)" ::: "memory");  // prev chunk reads done
            int Mtot = 0;
            for (int lr0 = 0; lr0 < CR; lr0 += 32) {
                const int lr = lr0 + lane;
                int cnt_r = 0, st_r = 0;
                if (lr < CR) {
                    const int row = cb + lr;
                    const int iz = row / ny;
                    const int iy = row - iz * ny;
                    const int c0 = ((z0 + iz) * GRID_R + (y0 + iy)) * GRID_R + x0;
                    st_r  = cstart[c0];
                    cnt_r = cstart[c0 + xs] - st_r;
                }
                int pv = cnt_r;
#pragma unroll
                for (int s = 1; s < 32; s <<= 1) {
                    const int u = __shfl_up(pv, s, 32);
                    if (lane >= s) pv += u;
                }
                if (lr < CR) { rs[lr] = st_r; pf[lr + 1] = Mtot + pv; }
                Mtot += __shfl(pv, 31, 32);
            }
            asm volatile("s_waitcnt lgkmcnt(0)" ::: "memory");  // staging visible
            int p = 0, cur = 0;
            int nxt = pf[1];
            int rst = rs[0];
            for (int t = lane; t < Mtot; t += 32) {
                while (nxt <= t) { ++p; cur = nxt; nxt = pf[p + 1]; rst = rs[p]; }
                const int si = rst + (t - cur);
                const float4 cq = pts4[si];
                const int    pj = pid[si];
                const float d = fmaf(cq.x, pix, fmaf(cq.y, piy, fmaf(cq.z, piz, cq.w)));
                if (pj != i && d <= tau) do_insert(d, pj);
            }
        }
    };

    float od[KNN];
    int   oi[KNN];
    // destructive 8-pick lex merge of the 32 per-lane sorted lists; picks
    // captured in order -> doubles as the output. Returns via od/oi.
    auto merge_out = [&]() {
#pragma unroll
        for (int k = 0; k < KNN; ++k) {
            float dw = bd[0];
            int   iw = bi[0];
#pragma unroll
            for (int s = 1; s < 32; s <<= 1) {
                const float dx = __shfl_xor(dw, s, 32);
                const int   ix = __shfl_xor(iw, s, 32);
                if (dx < dw || (dx == dw && ix < iw)) { dw = dx; iw = ix; }
            }
            if (bd[0] == dw && bi[0] == iw) {
#pragma unroll
                for (int q = 0; q < KNN - 1; ++q) { bd[q] = bd[q + 1]; bi[q] = bi[q + 1]; }
                bd[KNN - 1] = INFINITY; bi[KNN - 1] = 0x7fffffff;
            }
            od[k] = dw; oi[k] = iw;
        }
    };

    // ---- 1) parallel SAT radius probe: lane l tests radius l+1 (<=32) ----
    int r;
    {
        const int rl = lane + 1;
        const int bx0 = max(cx - rl, 0), bx1 = min(cx + rl, GRID_R - 1);
        const int by0 = max(cy - rl, 0), by1 = min(cy + rl, GRID_R - 1);
        const int bz0 = max(cz - rl, 0), bz1 = min(cz + rl, GRID_R - 1);
        const int cntl = boxcount(sat, bx0, bx1, by0, by1, bz0, bz1);
        const unsigned long long m = __ballot(cntl >= NBR_MIN);
        const unsigned mh = (unsigned)(m >> (tid & 32));   // this subgroup's 32 bits
        r = mh ? (int)__ffs(mh) : 32;
    }

    // ---- 2) window scan at r ----
    scan_win(r);

    // ---- 3) fused merge + termination; exact bounded second pass on failure ----
    {
        float mg = INFINITY;
        bool full = true;
        if (cx - r > 0)          { mg = fminf(mg, pix - (GLO + (float)(cx - r) * CELL_E));     full = false; }
        if (cx + r < GRID_R - 1) { mg = fminf(mg, (GLO + (float)(cx + r + 1) * CELL_E) - pix); full = false; }
        if (cy - r > 0)          { mg = fminf(mg, piy - (GLO + (float)(cy - r) * CELL_E));     full = false; }
        if (cy + r < GRID_R - 1) { mg = fminf(mg, (GLO + (float)(cy + r + 1) * CELL_E) - piy); full = false; }
        if (cz - r > 0)          { mg = fminf(mg, piz - (GLO + (float)(cz - r) * CELL_E));     full = false; }
        if (cz + r < GRID_R - 1) { mg = fminf(mg, (GLO + (float)(cz + r + 1) * CELL_E) - piz); full = false; }

        merge_out();                             // common path: the ONLY merge
        bool done = full;
        const float d8 = od[KNN - 1];
        if (!full) {
            const float mge  = mg - 1e-5f;
            const float need = mge * mge - sqi;  // d_real < mge^2  <=>  d' < need
            done = (d8 < need);                  // strict: boundary ties keep scanning
        }

        if (!done) {
            // required radius: per direction, margin >= s2 or clipped.
            float s2 = sqrtf(fmaxf(d8 + sqi, 0.0f)) + 1e-4f;  // real-distance bound
            s2 = fminf(s2, 9.0f);                              // cap -> full grid
            auto dneed = [&](float frac, int clip) -> int {
                int nd = (int)ceilf((s2 - frac) * CELL_INV);
                nd = max(nd, 0);
                return min(nd, clip);
            };
            const float fxm = pix - (GLO + (float)cx * CELL_E);
            const float fxp = (GLO + (float)(cx + 1) * CELL_E) - pix;
            const float fym = piy - (GLO + (float)cy * CELL_E);
            const float fyp = (GLO + (float)(cy + 1) * CELL_E) - piy;
            const float fzm = piz - (GLO + (float)cz * CELL_E);
            const float fzp = (GLO + (float)(cz + 1) * CELL_E) - piz;
            int r2 = r + 1;
            r2 = max(r2, dneed(fxm, cx));
            r2 = max(r2, dneed(fxp, GRID_R - 1 - cx));
            r2 = max(r2, dneed(fym, cy));
            r2 = max(r2, dneed(fyp, GRID_R - 1 - cy));
            r2 = max(r2, dneed(fzm, cz));
            r2 = max(r2, dneed(fzp, GRID_R - 1 - cz));
            r2 = min(r2, GRID_R);

            // fresh lists; tau seeded with pass-1 d8 (superset window => exact:
            // every true top-8 distance is <= d8, so the gate admits them all)
#pragma unroll
            for (int q = 0; q < KNN; ++q) { bd[q] = INFINITY; bi[q] = 0x7fffffff; }
            tau = d8;
            scan_win(r2);
            merge_out();
        }
    }

    if (lane == 0) {
#pragma unroll
        for (int k = 0; k < KNN; ++k) idx_out[i * 9 + k] = clamp_idx(oi[k]);
        idx_out[i * 9 + 8] = i;
    }
}

__global__ __launch_bounds__(256) void knn_grid_kernel(const void* __restrict__ pos,
                                                       const int* __restrict__ flag,
                                                       const int* __restrict__ cstart,
                                                       const int* __restrict__ sat,
                                                       const float4* __restrict__ pts4,
                                                       const int* __restrict__ pid,
                                                       int* __restrict__ idx_out) {
    __shared__ int rs[8][MAXROWS];
    __shared__ int pf[8][MAXROWS + 1];
    const int sg = threadIdx.x >> 5;
    if (get_dt(flag) == DT_BF16)
        knn_body<__hip_bfloat16>((const __hip_bfloat16*)pos, cstart, sat, pts4, pid, idx_out,
                                 rs[sg], pf[sg]);
    else
        knn_body<float>((const float*)pos, cstart, sat, pts4, pid, idx_out, rs[sg], pf[sg]);
}

// ---------------------------------------------------------------------------
// conv1 (unchanged): first layer factored
//   h1[n] = relu( pos_j@(Wtop+Wbot) - pos_i@Wbot + bA )
// ---------------------------------------------------------------------------
struct Conv1Smem {
    alignas(16) float wB[32 * 64];
    alignas(16) float h1s[4][9 * 32];
    alignas(16) float wsum[3 * 32];
    alignas(16) float wbot[3 * 32];
    alignas(16) float posn[4][9][3];
    float bA[32];
    float bB[64];
};

template <typename T>
__device__ void conv1_body(const T* __restrict__ pos, const int* __restrict__ idx,
                           const T* __restrict__ W1a, const T* __restrict__ b1a,
                           const T* __restrict__ W1b, const T* __restrict__ b1b,
                           float* __restrict__ x1, Conv1Smem& s) {
    const int tid = threadIdx.x;
    for (int e = tid; e < 96; e += 256) {
        const float bot = ldf(W1a, 96 + e);
        s.wsum[e] = ldf(W1a, e) + bot;
        s.wbot[e] = bot;
    }
    if (tid < 32) s.bA[tid] = ldf(b1a, tid);
    for (int e = tid; e < 2048; e += 256) s.wB[e] = ldf(W1b, e);
    if (tid < 64) s.bB[tid] = ldf(b1b, tid);

    const int tl   = tid >> 6;
    const int lane = tid & 63;
    const int i    = blockIdx.x * 4 + tl;

    if (lane < 27) {
        const int n = lane / 3, c = lane % 3;
        const int j = clamp_idx(idx[i * 9 + n]);
        s.posn[tl][n][c] = ldf(pos, 3 * j + c);
    }
    const float pi0 = ldf(pos, 3 * i + 0);
    const float pi1 = ldf(pos, 3 * i + 1);
    const float pi2 = ldf(pos, 3 * i + 2);
    __syncthreads();

    for (int e = lane; e < 288; e += 64) {
        const int n = e >> 5, k = e & 31;
        float b = fmaf(pi0, s.wbot[k], fmaf(pi1, s.wbot[32 + k], pi2 * s.wbot[64 + k]));
        float v = s.bA[k] - b;
        v = fmaf(s.posn[tl][n][0], s.wsum[k], v);
        v = fmaf(s.posn[tl][n][1], s.wsum[32 + k], v);
        v = fmaf(s.posn[tl][n][2], s.wsum[64 + k], v);
        s.h1s[tl][n * 32 + k] = fmaxf(v, 0.0f);
    }
    __syncthreads();

    float wcol[32];
#pragma unroll
    for (int k = 0; k < 32; ++k) wcol[k] = s.wB[k * 64 + lane];

    float acc = -INFINITY;
    for (int n = 0; n < 9; ++n) {
        float v = s.bB[lane];
#pragma unroll
        for (int k = 0; k < 32; ++k) v = fmaf(s.h1s[tl][n * 32 + k], wcol[k], v);
        acc = fmaxf(acc, v);
    }
    x1[i * 64 + lane] = fmaxf(acc, 0.0f);
}

__global__ __launch_bounds__(256) void conv1_kernel(const void* __restrict__ pos,
                                                    const int* __restrict__ flag,
                                                    const int* __restrict__ idx,
                                                    const void* __restrict__ W1a,
                                                    const void* __restrict__ b1a,
                                                    const void* __restrict__ W1b,
                                                    const void* __restrict__ b1b,
                                                    float* __restrict__ x1) {
    __shared__ Conv1Smem s;
    if (get_dt(flag) == DT_BF16)
        conv1_body<__hip_bfloat16>((const __hip_bfloat16*)pos, idx,
            (const __hip_bfloat16*)W1a, (const __hip_bfloat16*)b1a,
            (const __hip_bfloat16*)W1b, (const __hip_bfloat16*)b1b, x1, s);
    else
        conv1_body<float>((const float*)pos, idx, (const float*)W1a, (const float*)b1a,
            (const float*)W1b, (const float*)b1b, x1, s);
}

// ---------------------------------------------------------------------------
// zw (unchanged): per-point precompute for conv2's first layer.
// ---------------------------------------------------------------------------
struct ZwSmem {
    alignas(16) float wA[67 * 64];
    alignas(16) float xrT[4][68][4];
    float bA[64];
};

template <typename T>
__device__ void zw_body(const T* __restrict__ pos, const T* __restrict__ W2a,
                        const T* __restrict__ b2a, float* __restrict__ x1, ZwSmem& s) {
    const int tid  = threadIdx.x;
    const int wv   = tid >> 6;
    const int lane = tid & 63;
    const int j0   = blockIdx.x * 16 + wv * 4;

    for (int e = tid; e < 4288; e += 256) s.wA[e] = ldf(W2a, e);
    if (tid < 64) s.bA[tid] = ldf(b2a, tid);

#pragma unroll
    for (int p = 0; p < 4; ++p)
        s.xrT[wv][lane][p] = x1[(j0 + p) * 64 + lane];
    if (lane < 12) {
        const int p = lane / 3, c = lane % 3;
        s.xrT[wv][64 + c][p] = ldf(pos, 3 * (j0 + p) + c);
    }
    __syncthreads();

    float a0 = s.bA[lane], a1 = a0, a2 = a0, a3 = a0;
    for (int c = 0; c < 67; ++c) {
        const float w = s.wA[c * 64 + lane];
        const float4 xv = *(const float4*)&s.xrT[wv][c][0];
        a0 = fmaf(xv.x, w, a0);
        a1 = fmaf(xv.y, w, a1);
        a2 = fmaf(xv.z, w, a2);
        a3 = fmaf(xv.w, w, a3);
    }
    x1[(j0 + 0) * 64 + lane] = a0;
    x1[(j0 + 1) * 64 + lane] = a1;
    x1[(j0 + 2) * 64 + lane] = a2;
    x1[(j0 + 3) * 64 + lane] = a3;
}

__global__ __launch_bounds__(256) void zw_kernel(const void* __restrict__ pos,
                                                 const int* __restrict__ flag,
                                                 const void* __restrict__ W2a,
                                                 const void* __restrict__ b2a,
                                                 float* __restrict__ x1) {
    __shared__ ZwSmem s;
    if (get_dt(flag) == DT_BF16)
        zw_body<__hip_bfloat16>((const __hip_bfloat16*)pos, (const __hip_bfloat16*)W2a,
                                (const __hip_bfloat16*)b2a, x1, s);
    else
        zw_body<float>((const float*)pos, (const float*)W2a, (const float*)b2a, x1, s);
}

// ---------------------------------------------------------------------------
// conv2+head (unchanged): h1[n] = relu(zw[j_n] - pos_i@W2a_bot).
// ---------------------------------------------------------------------------
struct Conv2Smem {
    alignas(16) float h1s[4][9 * 64];
    alignas(16) float row[4][128];
    alignas(16) float wbot[3 * 64];
    alignas(16) float wc[640];
    float bcs[5];
    float sv[4][5];
    int   nb[4][9];
};

template <typename T>
__device__ void conv2_body(const T* __restrict__ pos, const int* __restrict__ idx,
                           const float* __restrict__ zw,
                           const T* __restrict__ W2a, const T* __restrict__ W2b,
                           const T* __restrict__ b2b, const T* __restrict__ Wc,
                           const T* __restrict__ bc, T* __restrict__ out, Conv2Smem& s) {
    const int tid  = threadIdx.x;
    const int l    = tid & 127;
    const int half = tid >> 7;

    float wcol[64];
#pragma unroll
    for (int k = 0; k < 64; ++k) wcol[k] = ldf(W2b, k * 128 + l);
    const float bBl = ldf(b2b, l);

    for (int e = tid; e < 192; e += 256) s.wbot[e] = ldf(W2a, 4096 + e);
    for (int e = tid; e < 640; e += 256) s.wc[e] = ldf(Wc, e);
    if (tid < 5) s.bcs[tid] = ldf(bc, tid);

    const int tl   = tid >> 6;
    const int lane = tid & 63;
    const int i    = blockIdx.x * 4 + tl;

    if (lane < 9) s.nb[tl][lane] = clamp_idx(idx[i * 9 + lane]);
    const float pi0 = ldf(pos, 3 * i + 0);
    const float pi1 = ldf(pos, 3 * i + 1);
    const float pi2 = ldf(pos, 3 * i + 2);
    __syncthreads();

    {
        const float vi = fmaf(pi0, s.wbot[lane], fmaf(pi1, s.wbot[64 + lane], pi2 * s.wbot[128 + lane]));
#pragma unroll
        for (int n = 0; n < 9; ++n) {
            const int j = s.nb[tl][n];
            s.h1s[tl][n * 64 + lane] = fmaxf(zw[j * 64 + lane] - vi, 0.0f);
        }
    }
    __syncthreads();

#pragma unroll
    for (int tt = 0; tt < 2; ++tt) {
        const int tgt = half * 2 + tt;
        float acc = -INFINITY;
        for (int n = 0; n < 9; ++n) {
            float v = bBl;
            for (int k = 0; k < 64; k += 4) {
                const float4 hv = *(const float4*)&s.h1s[tgt][n * 64 + k];
                v = fmaf(hv.x, wcol[k + 0], v);
                v = fmaf(hv.y, wcol[k + 1], v);
                v = fmaf(hv.z, wcol[k + 2], v);
                v = fmaf(hv.w, wcol[k + 3], v);
            }
            acc = fmaxf(acc, v);
        }
        s.row[tgt][l] = fmaxf(acc, 0.0f);
    }
    __syncthreads();

    if (tid < 20) {
        const int tgt = tid / 5, o = tid % 5;
        float v = s.bcs[o];
        for (int k = 0; k < 128; ++k) v = fmaf(s.row[tgt][k], s.wc[k * 5 + o], v);
        s.sv[tgt][o] = v;
    }
    __syncthreads();
    if (tid < 20) {
        const int tgt = tid / 5, o = tid % 5;
        float m = s.sv[tgt][0];
#pragma unroll
        for (int q = 1; q < 5; ++q) m = fmaxf(m, s.sv[tgt][q]);
        float sum = 0.0f;
#pragma unroll
        for (int q = 0; q < 5; ++q) sum += expf(s.sv[tgt][q] - m);
        const float lse = m + logf(sum);
        stf(out, (blockIdx.x * 4 + tgt) * 5 + o, s.sv[tgt][o] - lse);
    }
}

__global__ __launch_bounds__(256) void conv2_head_kernel(const void* __restrict__ pos,
                                                         const int* __restrict__ flag,
                                                         const int* __restrict__ idx,
                                                         const float* __restrict__ zw,
                                                         const void* __restrict__ W2a,
                                                         const void* __restrict__ W2b,
                                                         const void* __restrict__ b2b,
                                                         const void* __restrict__ Wc,
                                                         const void* __restrict__ bc,
                                                         void* __restrict__ out) {
    __shared__ Conv2Smem s;
    if (get_dt(flag) == DT_BF16)
        conv2_body<__hip_bfloat16>((const __hip_bfloat16*)pos, idx, zw,
            (const __hip_bfloat16*)W2a, (const __hip_bfloat16*)W2b, (const __hip_bfloat16*)b2b,
            (const __hip_bfloat16*)Wc, (const __hip_bfloat16*)bc, (__hip_bfloat16*)out, s);
    else
        conv2_body<float>((const float*)pos, idx, zw, (const float*)W2a, (const float*)W2b,
            (const float*)b2b, (const float*)Wc, (const float*)bc, (float*)out, s);
}

// ---------------------------------------------------------------------------
extern "C" void kernel_launch(void* const* d_in, const int* in_sizes, int n_in,
                              void* d_out, int out_size, void* d_ws, size_t ws_size,
                              hipStream_t stream) {
    if (ws_size < (size_t)WS_NEEDED) return;

    char* ws = (char*)d_ws;
    int*    flag     = (int*)(ws + WS_FLAG_OFF);
    int*    idx      = (int*)(ws + WS_IDX_OFF);
    float*  x1       = (float*)(ws + WS_X1_OFF);
    int*    sat      = (int*)(ws + WS_SAT_OFF);
    int*    cstart   = (int*)(ws + WS_START_OFF);
    int*    cursor   = (int*)(ws + WS_CURSOR_OFF);
    int*    pid      = (int*)(ws + WS_PID_OFF);
    float4* pts4     = (float4*)(ws + WS_PTS_OFF);
    int*    rowtot   = (int*)(ws + WS_ROWTOT_OFF);
    int*    rowstart = (int*)(ws + WS_ROWSTART_OFF);

    zero_kernel<<<NCELLS / 256, 256, 0, stream>>>(sat, flag);
    sniff_kernel<<<64, 256, 0, stream>>>((const unsigned short*)d_in[0], flag);
    grid_count_kernel<<<N_PTS / 256, 256, 0, stream>>>(d_in[0], flag, sat);
    rowscan_kernel<<<NROWS2D / 256, 256, 0, stream>>>(sat, rowtot);
    rowoffset_kernel<<<1, 256, 0, stream>>>(rowtot, rowstart);
    cellstart_kernel<<<NROWS2D / 256, 256, 0, stream>>>(sat, rowstart, cstart, cursor);
    saty_kernel<<<NROWS2D / 256, 256, 0, stream>>>(sat);
    satz_kernel<<<NROWS2D / 256, 256, 0, stream>>>(sat);
    grid_scatter_kernel<<<N_PTS / 256, 256, 0, stream>>>(d_in[0], flag, cursor, pts4, pid);
    knn_grid_kernel<<<N_PTS / 8, 256, 0, stream>>>(d_in[0], flag, cstart, sat, pts4, pid, idx);
    conv1_kernel<<<N_PTS / 4, 256, 0, stream>>>(d_in[0], flag, idx,
        d_in[1], d_in[2], d_in[3], d_in[4], x1);
    zw_kernel<<<N_PTS / 16, 256, 0, stream>>>(d_in[0], flag, d_in[5], d_in[6], x1);
    conv2_head_kernel<<<N_PTS / 4, 256, 0, stream>>>(d_in[0], flag, idx, x1,
        d_in[5], d_in[7], d_in[8], d_in[9], d_in[10], d_out);
}

// Round 7
// 244.387 us; speedup vs baseline: 1.6050x; 1.1223x over previous
//
#include <hip/hip_runtime.h>
#include <hip/hip_bf16.h>
#include <math.h>

#define N_PTS 16384
#define KNN 8

#define DT_BF16 1
#define DT_FP32 2

// Workspace layout:
//   flag : int          @ 0
//   idx  : int  [N*9]   @ 64        -> 589,824 B
//   x1   : f32  [N*64]  @ 589,888   -> 4,194,304 B
// Grid-KNN scratch lives INSIDE the x1 region (dead before conv1 writes x1):
//   sat      : int [110592]  @ x1+0        (counts -> x-prefix -> full 3D SAT)
//   start    : int [110593]  @ x1+442368   (cell starts + sentinel)
//   cursor   : int [110592]  @ x1+884800
//   pid      : int [16384]   @ x1+1327168
//   pts4     : f4  [16384]   @ x1+1392704
//   rowtot   : int [2304]    @ x1+1654848
//   rowstart : int [2304]    @ x1+1664064  (end 1,673,280 <= 4,194,304)
#define WS_FLAG_OFF 0
#define WS_IDX_OFF  64
#define WS_X1_OFF   589888
#define WS_NEEDED   4784192

#define WS_SAT_OFF      (WS_X1_OFF)
#define WS_START_OFF    (WS_X1_OFF + 442368)
#define WS_CURSOR_OFF   (WS_X1_OFF + 884800)
#define WS_PID_OFF      (WS_X1_OFF + 1327168)
#define WS_PTS_OFF      (WS_X1_OFF + 1392704)
#define WS_ROWTOT_OFF   (WS_X1_OFF + 1654848)
#define WS_ROWSTART_OFF (WS_X1_OFF + 1664064)

#define GRID_R   48
#define NROWS2D  (GRID_R * GRID_R)          // 2304 (y,z) rows
#define NCELLS   (GRID_R * GRID_R * GRID_R) // 110592
#define GLO      -4.5f
#define CELL_E   0.1875f
#define CELL_INV 5.3333335f
#define NBR_MIN  26   // SAT window population target (incl. self)

__device__ __forceinline__ float bf2f(__hip_bfloat16 v) { return __bfloat162float(v); }

__device__ __forceinline__ float ldf(const float* p, int i) { return p[i]; }
__device__ __forceinline__ float ldf(const __hip_bfloat16* p, int i) { return bf2f(p[i]); }
__device__ __forceinline__ void stf(float* p, int i, float v) { p[i] = v; }
__device__ __forceinline__ void stf(__hip_bfloat16* p, int i, float v) { p[i] = __float2bfloat16(v); }

__device__ __forceinline__ int clamp_idx(int j) {
    return ((unsigned)j < (unsigned)N_PTS) ? j : 0;
}

__device__ __forceinline__ int cell_of(float v) {
    int c = (int)((v - GLO) * CELL_INV);
    return min(max(c, 0), GRID_R - 1);
}

// flag[0] holds the sniffer's bad-count; >16 => fp32 input.
__device__ __forceinline__ int get_dt(const int* flag) {
    return (flag[0] > 16) ? DT_FP32 : DT_BF16;
}

// ---------------------------------------------------------------------------
// zero: cnt[] and flag.
// ---------------------------------------------------------------------------
__global__ __launch_bounds__(256) void zero_kernel(int* __restrict__ cnt, int* __restrict__ flag) {
    const int e = blockIdx.x * 256 + threadIdx.x;
    cnt[e] = 0;
    if (e == 0) flag[0] = 0;
}

// ---------------------------------------------------------------------------
// sniff (multi-block).
// ---------------------------------------------------------------------------
__global__ __launch_bounds__(256) void sniff_kernel(const unsigned short* __restrict__ posu,
                                                    int* __restrict__ flag) {
    __shared__ int red[256];
    int local = 0;
    for (int e = blockIdx.x * 256 + threadIdx.x; e < 3 * N_PTS; e += 64 * 256) {
        const float v = __uint_as_float(((unsigned)posu[e]) << 16);
        if (!(fabsf(v) <= 64.0f)) local++;
    }
    red[threadIdx.x] = local;
    __syncthreads();
    for (int s = 128; s > 0; s >>= 1) {
        if (threadIdx.x < s) red[threadIdx.x] += red[threadIdx.x + s];
        __syncthreads();
    }
    if (threadIdx.x == 0 && red[0] > 0) atomicAdd(flag, red[0]);
}

// ---------------------------------------------------------------------------
// Grid build (parallel): count -> rowscan -> rowoffset -> cellstart ->
// saty -> satz -> scatter.
// ---------------------------------------------------------------------------
template <typename T>
__device__ __forceinline__ void count_body(const T* __restrict__ pos, int* __restrict__ cnt) {
    const int i = blockIdx.x * 256 + threadIdx.x;
    const float x = ldf(pos, 3 * i + 0);
    const float y = ldf(pos, 3 * i + 1);
    const float z = ldf(pos, 3 * i + 2);
    const int c = (cell_of(z) * GRID_R + cell_of(y)) * GRID_R + cell_of(x);
    atomicAdd(&cnt[c], 1);
}

__global__ __launch_bounds__(256) void grid_count_kernel(const void* __restrict__ pos,
                                                         const int* __restrict__ flag,
                                                         int* __restrict__ cnt) {
    if (get_dt(flag) == DT_BF16) count_body<__hip_bfloat16>((const __hip_bfloat16*)pos, cnt);
    else                         count_body<float>((const float*)pos, cnt);
}

// x-prefix per row (in place over sat), rowtot[row] = row sum.
__global__ __launch_bounds__(256) void rowscan_kernel(int* __restrict__ sat,
                                                      int* __restrict__ rowtot) {
    const int t = blockIdx.x * 256 + threadIdx.x;   // row < 2304
    const int rb = t * GRID_R;
    int acc = 0;
    for (int x = 0; x < GRID_R; ++x) { acc += sat[rb + x]; sat[rb + x] = acc; }
    rowtot[t] = acc;
}

// exclusive scan of 2304 row totals (one block, 256 threads x 9 rows).
__global__ __launch_bounds__(256) void rowoffset_kernel(const int* __restrict__ rowtot,
                                                        int* __restrict__ rowstart) {
    __shared__ int part[256];
    const int t = threadIdx.x;
    int loc[9]; int s = 0;
#pragma unroll
    for (int k = 0; k < 9; ++k) { loc[k] = rowtot[t * 9 + k]; s += loc[k]; }
    part[t] = s;
    __syncthreads();
    for (int off = 1; off < 256; off <<= 1) {
        int v = (t >= off) ? part[t - off] : 0;
        __syncthreads();
        part[t] += v;
        __syncthreads();
    }
    int run = (t == 0) ? 0 : part[t - 1];
#pragma unroll
    for (int k = 0; k < 9; ++k) { rowstart[t * 9 + k] = run; run += loc[k]; }
}

// cstart/cursor per cell = rowstart + in-row exclusive x-prefix; sentinel.
__global__ __launch_bounds__(256) void cellstart_kernel(const int* __restrict__ satx,
                                                        const int* __restrict__ rowstart,
                                                        int* __restrict__ cstart,
                                                        int* __restrict__ cursor) {
    const int t = blockIdx.x * 256 + threadIdx.x;   // row < 2304
    const int rb = t * GRID_R;
    const int base = rowstart[t];
    int prev = 0;
    for (int x = 0; x < GRID_R; ++x) {
        const int v = base + prev;
        cstart[rb + x] = v;
        cursor[rb + x] = v;
        prev = satx[rb + x];
    }
    if (t == NROWS2D - 1) cstart[NCELLS] = base + prev;
}

// SAT pass 2: prefix along y.
__global__ __launch_bounds__(256) void saty_kernel(int* __restrict__ sat) {
    const int t = blockIdx.x * 256 + threadIdx.x;   // < 2304
    const int z = t / GRID_R, x = t - z * GRID_R;
    const int base = z * NROWS2D + x;
    int run = 0;
#pragma unroll
    for (int y = 0; y < GRID_R; ++y) {
        run += sat[base + y * GRID_R];
        sat[base + y * GRID_R] = run;
    }
}

// SAT pass 3: prefix along z.
__global__ __launch_bounds__(256) void satz_kernel(int* __restrict__ sat) {
    const int t = blockIdx.x * 256 + threadIdx.x;   // < 2304
    int run = 0;
#pragma unroll
    for (int z = 0; z < GRID_R; ++z) {
        run += sat[t + z * NROWS2D];
        sat[t + z * NROWS2D] = run;
    }
}

template <typename T>
__device__ __forceinline__ void scatter_body(const T* __restrict__ pos, int* __restrict__ cursor,
                                             float4* __restrict__ pts4, int* __restrict__ pid) {
    const int i = blockIdx.x * 256 + threadIdx.x;
    const float x = ldf(pos, 3 * i + 0);
    const float y = ldf(pos, 3 * i + 1);
    const float z = ldf(pos, 3 * i + 2);
    const int c = (cell_of(z) * GRID_R + cell_of(y)) * GRID_R + cell_of(x);
    const int slot = atomicAdd(&cursor[c], 1);
    const float sq = fmaf(x, x, fmaf(y, y, z * z));
    pts4[slot] = make_float4(-2.0f * x, -2.0f * y, -2.0f * z, sq);
    pid[slot] = i;
}

__global__ __launch_bounds__(256) void grid_scatter_kernel(const void* __restrict__ pos,
                                                           const int* __restrict__ flag,
                                                           int* __restrict__ cursor,
                                                           float4* __restrict__ pts4,
                                                           int* __restrict__ pid) {
    if (get_dt(flag) == DT_BF16) scatter_body<__hip_bfloat16>((const __hip_bfloat16*)pos, cursor, pts4, pid);
    else                         scatter_body<float>((const float*)pos, cursor, pts4, pid);
}

// ---------------------------------------------------------------------------
// KNN v8: two targets per wave (32-lane subgroups), fused single merge (v7),
// PLUS latency fix (r6 counters: VALUBusy 20%, Occ 19% -> serial-gather
// bound with outlier-wave tail). v7's candidate loop walked the row prefix
// serially (`while (nxt <= t)`), so every pts4 gather waited on the prior
// one; outlier targets (window swallowing the dense core, M~10k) paid
// ~300 serial gathers = ~37 us in ONE wave = the tail. v8: rows chunked at
// 32 (one lane per row, one shfl-prefix), and each candidate finds its row
// by BINARY SEARCH over the exclusive prefix in LDS (5 independent reads);
// the candidate loop is manually pipelined 4-wide (search+gather for 4
// candidates issued before any insert) -> gathers overlap, straggler waves
// drop ~8x. Selection semantics identical: lex (d, idx) everywhere.
// ---------------------------------------------------------------------------
__device__ __forceinline__ int sat_at(const int* __restrict__ sat, int x, int y, int z) {
    if (x < 0 || y < 0 || z < 0) return 0;
    return sat[(z * GRID_R + y) * GRID_R + x];
}

__device__ __forceinline__ int boxcount(const int* __restrict__ sat,
                                        int x0, int x1, int y0, int y1, int z0, int z1) {
    return sat_at(sat, x1, y1, z1) - sat_at(sat, x0 - 1, y1, z1)
         - sat_at(sat, x1, y0 - 1, z1) - sat_at(sat, x1, y1, z0 - 1)
         + sat_at(sat, x0 - 1, y0 - 1, z1) + sat_at(sat, x0 - 1, y1, z0 - 1)
         + sat_at(sat, x1, y0 - 1, z0 - 1) - sat_at(sat, x0 - 1, y0 - 1, z0 - 1);
}

template <typename T>
__device__ void knn_body(const T* __restrict__ pos,
                         const int* __restrict__ cstart, const int* __restrict__ sat,
                         const float4* __restrict__ pts4, const int* __restrict__ pid,
                         int* __restrict__ idx_out,
                         int* __restrict__ rs, int* __restrict__ epf) {
    const int tid  = threadIdx.x;
    const int lane = tid & 31;                 // lane within 32-lane subgroup
    const int i    = blockIdx.x * 8 + (tid >> 5);

    const float pix = ldf(pos, 3 * i + 0);
    const float piy = ldf(pos, 3 * i + 1);
    const float piz = ldf(pos, 3 * i + 2);
    const float sqi = fmaf(pix, pix, fmaf(piy, piy, piz * piz));
    const int cx = cell_of(pix), cy = cell_of(piy), cz = cell_of(piz);

    float bd[KNN];
    int   bi[KNN];
#pragma unroll
    for (int q = 0; q < KNN; ++q) { bd[q] = INFINITY; bi[q] = 0x7fffffff; }
    float tau = INFINITY;

    auto do_insert = [&](float d, int pj) {
        float cd = d; int ci = pj;
#pragma unroll
        for (int q = 0; q < KNN; ++q) {
            const bool ins = (cd < bd[q]) || (cd == bd[q] && ci < bi[q]);
            const float nd = ins ? cd : bd[q];
            const int   ni = ins ? ci : bi[q];
            const float od = ins ? bd[q] : cd;
            const int   oi = ins ? bi[q] : ci;
            bd[q] = nd; bi[q] = ni; cd = od; ci = oi;
        }
        tau = fminf(tau, bd[KNN - 1]);
    };

    // window scan: 32-row chunks; exclusive prefix in LDS; per-candidate
    // binary search (independent) + 4-wide pipelined gathers.
    auto scan_win = [&](int rr) {
        const int x0 = max(cx - rr, 0), x1 = min(cx + rr, GRID_R - 1);
        const int y0 = max(cy - rr, 0), y1 = min(cy + rr, GRID_R - 1);
        const int z0 = max(cz - rr, 0), z1 = min(cz + rr, GRID_R - 1);
        const int ny = y1 - y0 + 1;
        const int R  = ny * (z1 - z0 + 1);
        const int xs = x1 - x0 + 1;
        for (int cb = 0; cb < R; cb += 32) {
            const int lr = cb + lane;
            int cnt_r = 0, st_r = 0;
            if (lr < R) {
                const int iz = lr / ny;
                const int iy = lr - iz * ny;
                const int c0 = ((z0 + iz) * GRID_R + (y0 + iy)) * GRID_R + x0;
                st_r  = cstart[c0];
                cnt_r = cstart[c0 + xs] - st_r;
            }
            int pv = cnt_r;
#pragma unroll
            for (int s = 1; s < 32; s <<= 1) {
                const int u = __shfl_up(pv, s, 32);
                if (lane >= s) pv += u;
            }
            const int Mtot = __shfl(pv, 31, 32);
            asm volatile("s_waitcnt lgkmcnt(0)" ::: "memory");  // prev chunk reads done
            rs[lane]  = st_r;
            epf[lane] = (lr < R) ? (pv - cnt_r) : 0x7fffffff;   // exclusive prefix / +inf
            asm volatile("s_waitcnt lgkmcnt(0)" ::: "memory");  // staging visible
            for (int tb = 0; tb < Mtot; tb += 128) {
                float dls[4]; int pjs[4];
#pragma unroll
                for (int k = 0; k < 4; ++k) {
                    const int t = tb + (k << 5) + lane;
                    dls[k] = INFINITY; pjs[k] = i;              // sentinel: skipped
                    if (t < Mtot) {
                        // largest p with epf[p] <= t (epf[0] = 0)
                        int p = 0;
#pragma unroll
                        for (int st = 16; st >= 1; st >>= 1)
                            if (epf[p + st] <= t) p += st;
                        const int si = rs[p] + (t - epf[p]);
                        const float4 cq = pts4[si];
                        pjs[k] = pid[si];
                        dls[k] = fmaf(cq.x, pix, fmaf(cq.y, piy, fmaf(cq.z, piz, cq.w)));
                    }
                }
#pragma unroll
                for (int k = 0; k < 4; ++k)
                    if (pjs[k] != i && dls[k] <= tau) do_insert(dls[k], pjs[k]);
            }
        }
    };

    float od[KNN];
    int   oi[KNN];
    // destructive 8-pick lex merge of the 32 per-lane sorted lists; picks
    // captured in order -> doubles as the output.
    auto merge_out = [&]() {
#pragma unroll
        for (int k = 0; k < KNN; ++k) {
            float dw = bd[0];
            int   iw = bi[0];
#pragma unroll
            for (int s = 1; s < 32; s <<= 1) {
                const float dx = __shfl_xor(dw, s, 32);
                const int   ix = __shfl_xor(iw, s, 32);
                if (dx < dw || (dx == dw && ix < iw)) { dw = dx; iw = ix; }
            }
            if (bd[0] == dw && bi[0] == iw) {
#pragma unroll
                for (int q = 0; q < KNN - 1; ++q) { bd[q] = bd[q + 1]; bi[q] = bi[q + 1]; }
                bd[KNN - 1] = INFINITY; bi[KNN - 1] = 0x7fffffff;
            }
            od[k] = dw; oi[k] = iw;
        }
    };

    // ---- 1) parallel SAT radius probe: lane l tests radius l+1 (<=32) ----
    int r;
    {
        const int rl = lane + 1;
        const int bx0 = max(cx - rl, 0), bx1 = min(cx + rl, GRID_R - 1);
        const int by0 = max(cy - rl, 0), by1 = min(cy + rl, GRID_R - 1);
        const int bz0 = max(cz - rl, 0), bz1 = min(cz + rl, GRID_R - 1);
        const int cntl = boxcount(sat, bx0, bx1, by0, by1, bz0, bz1);
        const unsigned long long m = __ballot(cntl >= NBR_MIN);
        const unsigned mh = (unsigned)(m >> (tid & 32));   // this subgroup's 32 bits
        r = mh ? (int)__ffs(mh) : 32;
    }

    // ---- 2) window scan at r ----
    scan_win(r);

    // ---- 3) fused merge + termination; exact bounded second pass on failure ----
    {
        float mg = INFINITY;
        bool full = true;
        if (cx - r > 0)          { mg = fminf(mg, pix - (GLO + (float)(cx - r) * CELL_E));     full = false; }
        if (cx + r < GRID_R - 1) { mg = fminf(mg, (GLO + (float)(cx + r + 1) * CELL_E) - pix); full = false; }
        if (cy - r > 0)          { mg = fminf(mg, piy - (GLO + (float)(cy - r) * CELL_E));     full = false; }
        if (cy + r < GRID_R - 1) { mg = fminf(mg, (GLO + (float)(cy + r + 1) * CELL_E) - piy); full = false; }
        if (cz - r > 0)          { mg = fminf(mg, piz - (GLO + (float)(cz - r) * CELL_E));     full = false; }
        if (cz + r < GRID_R - 1) { mg = fminf(mg, (GLO + (float)(cz + r + 1) * CELL_E) - piz); full = false; }

        merge_out();                             // common path: the ONLY merge
        bool done = full;
        const float d8 = od[KNN - 1];
        if (!full) {
            const float mge  = mg - 1e-5f;
            const float need = mge * mge - sqi;  // d_real < mge^2  <=>  d' < need
            done = (d8 < need);                  // strict: boundary ties keep scanning
        }

        if (!done) {
            // required radius: per direction, margin >= s2 or clipped.
            float s2 = sqrtf(fmaxf(d8 + sqi, 0.0f)) + 1e-4f;  // real-distance bound
            s2 = fminf(s2, 9.0f);                              // cap -> full grid
            auto dneed = [&](float frac, int clip) -> int {
                int nd = (int)ceilf((s2 - frac) * CELL_INV);
                nd = max(nd, 0);
                return min(nd, clip);
            };
            const float fxm = pix - (GLO + (float)cx * CELL_E);
            const float fxp = (GLO + (float)(cx + 1) * CELL_E) - pix;
            const float fym = piy - (GLO + (float)cy * CELL_E);
            const float fyp = (GLO + (float)(cy + 1) * CELL_E) - piy;
            const float fzm = piz - (GLO + (float)cz * CELL_E);
            const float fzp = (GLO + (float)(cz + 1) * CELL_E) - piz;
            int r2 = r + 1;
            r2 = max(r2, dneed(fxm, cx));
            r2 = max(r2, dneed(fxp, GRID_R - 1 - cx));
            r2 = max(r2, dneed(fym, cy));
            r2 = max(r2, dneed(fyp, GRID_R - 1 - cy));
            r2 = max(r2, dneed(fzm, cz));
            r2 = max(r2, dneed(fzp, GRID_R - 1 - cz));
            r2 = min(r2, GRID_R);

            // fresh lists; tau seeded with pass-1 d8 (superset window => exact:
            // every true top-8 distance is <= d8, so the gate admits them all)
#pragma unroll
            for (int q = 0; q < KNN; ++q) { bd[q] = INFINITY; bi[q] = 0x7fffffff; }
            tau = d8;
            scan_win(r2);
            merge_out();
        }
    }

    if (lane == 0) {
#pragma unroll
        for (int k = 0; k < KNN; ++k) idx_out[i * 9 + k] = clamp_idx(oi[k]);
        idx_out[i * 9 + 8] = i;
    }
}

__global__ __launch_bounds__(256) void knn_grid_kernel(const void* __restrict__ pos,
                                                       const int* __restrict__ flag,
                                                       const int* __restrict__ cstart,
                                                       const int* __restrict__ sat,
                                                       const float4* __restrict__ pts4,
                                                       const int* __restrict__ pid,
                                                       int* __restrict__ idx_out) {
    __shared__ int rs[8][32];
    __shared__ int epf[8][32];
    const int sg = threadIdx.x >> 5;
    if (get_dt(flag) == DT_BF16)
        knn_body<__hip_bfloat16>((const __hip_bfloat16*)pos, cstart, sat, pts4, pid, idx_out,
                                 rs[sg], epf[sg]);
    else
        knn_body<float>((const float*)pos, cstart, sat, pts4, pid, idx_out, rs[sg], epf[sg]);
}

// ---------------------------------------------------------------------------
// conv1 (unchanged): first layer factored
//   h1[n] = relu( pos_j@(Wtop+Wbot) - pos_i@Wbot + bA )
// ---------------------------------------------------------------------------
struct Conv1Smem {
    alignas(16) float wB[32 * 64];
    alignas(16) float h1s[4][9 * 32];
    alignas(16) float wsum[3 * 32];
    alignas(16) float wbot[3 * 32];
    alignas(16) float posn[4][9][3];
    float bA[32];
    float bB[64];
};

template <typename T>
__device__ void conv1_body(const T* __restrict__ pos, const int* __restrict__ idx,
                           const T* __restrict__ W1a, const T* __restrict__ b1a,
                           const T* __restrict__ W1b, const T* __restrict__ b1b,
                           float* __restrict__ x1, Conv1Smem& s) {
    const int tid = threadIdx.x;
    for (int e = tid; e < 96; e += 256) {
        const float bot = ldf(W1a, 96 + e);
        s.wsum[e] = ldf(W1a, e) + bot;
        s.wbot[e] = bot;
    }
    if (tid < 32) s.bA[tid] = ldf(b1a, tid);
    for (int e = tid; e < 2048; e += 256) s.wB[e] = ldf(W1b, e);
    if (tid < 64) s.bB[tid] = ldf(b1b, tid);

    const int tl   = tid >> 6;
    const int lane = tid & 63;
    const int i    = blockIdx.x * 4 + tl;

    if (lane < 27) {
        const int n = lane / 3, c = lane % 3;
        const int j = clamp_idx(idx[i * 9 + n]);
        s.posn[tl][n][c] = ldf(pos, 3 * j + c);
    }
    const float pi0 = ldf(pos, 3 * i + 0);
    const float pi1 = ldf(pos, 3 * i + 1);
    const float pi2 = ldf(pos, 3 * i + 2);
    __syncthreads();

    for (int e = lane; e < 288; e += 64) {
        const int n = e >> 5, k = e & 31;
        float b = fmaf(pi0, s.wbot[k], fmaf(pi1, s.wbot[32 + k], pi2 * s.wbot[64 + k]));
        float v = s.bA[k] - b;
        v = fmaf(s.posn[tl][n][0], s.wsum[k], v);
        v = fmaf(s.posn[tl][n][1], s.wsum[32 + k], v);
        v = fmaf(s.posn[tl][n][2], s.wsum[64 + k], v);
        s.h1s[tl][n * 32 + k] = fmaxf(v, 0.0f);
    }
    __syncthreads();

    float wcol[32];
#pragma unroll
    for (int k = 0; k < 32; ++k) wcol[k] = s.wB[k * 64 + lane];

    float acc = -INFINITY;
    for (int n = 0; n < 9; ++n) {
        float v = s.bB[lane];
#pragma unroll
        for (int k = 0; k < 32; ++k) v = fmaf(s.h1s[tl][n * 32 + k], wcol[k], v);
        acc = fmaxf(acc, v);
    }
    x1[i * 64 + lane] = fmaxf(acc, 0.0f);
}

__global__ __launch_bounds__(256) void conv1_kernel(const void* __restrict__ pos,
                                                    const int* __restrict__ flag,
                                                    const int* __restrict__ idx,
                                                    const void* __restrict__ W1a,
                                                    const void* __restrict__ b1a,
                                                    const void* __restrict__ W1b,
                                                    const void* __restrict__ b1b,
                                                    float* __restrict__ x1) {
    __shared__ Conv1Smem s;
    if (get_dt(flag) == DT_BF16)
        conv1_body<__hip_bfloat16>((const __hip_bfloat16*)pos, idx,
            (const __hip_bfloat16*)W1a, (const __hip_bfloat16*)b1a,
            (const __hip_bfloat16*)W1b, (const __hip_bfloat16*)b1b, x1, s);
    else
        conv1_body<float>((const float*)pos, idx, (const float*)W1a, (const float*)b1a,
            (const float*)W1b, (const float*)b1b, x1, s);
}

// ---------------------------------------------------------------------------
// zw (unchanged): per-point precompute for conv2's first layer.
// ---------------------------------------------------------------------------
struct ZwSmem {
    alignas(16) float wA[67 * 64];
    alignas(16) float xrT[4][68][4];
    float bA[64];
};

template <typename T>
__device__ void zw_body(const T* __restrict__ pos, const T* __restrict__ W2a,
                        const T* __restrict__ b2a, float* __restrict__ x1, ZwSmem& s) {
    const int tid  = threadIdx.x;
    const int wv   = tid >> 6;
    const int lane = tid & 63;
    const int j0   = blockIdx.x * 16 + wv * 4;

    for (int e = tid; e < 4288; e += 256) s.wA[e] = ldf(W2a, e);
    if (tid < 64) s.bA[tid] = ldf(b2a, tid);

#pragma unroll
    for (int p = 0; p < 4; ++p)
        s.xrT[wv][lane][p] = x1[(j0 + p) * 64 + lane];
    if (lane < 12) {
        const int p = lane / 3, c = lane % 3;
        s.xrT[wv][64 + c][p] = ldf(pos, 3 * (j0 + p) + c);
    }
    __syncthreads();

    float a0 = s.bA[lane], a1 = a0, a2 = a0, a3 = a0;
    for (int c = 0; c < 67; ++c) {
        const float w = s.wA[c * 64 + lane];
        const float4 xv = *(const float4*)&s.xrT[wv][c][0];
        a0 = fmaf(xv.x, w, a0);
        a1 = fmaf(xv.y, w, a1);
        a2 = fmaf(xv.z, w, a2);
        a3 = fmaf(xv.w, w, a3);
    }
    x1[(j0 + 0) * 64 + lane] = a0;
    x1[(j0 + 1) * 64 + lane] = a1;
    x1[(j0 + 2) * 64 + lane] = a2;
    x1[(j0 + 3) * 64 + lane] = a3;
}

__global__ __launch_bounds__(256) void zw_kernel(const void* __restrict__ pos,
                                                 const int* __restrict__ flag,
                                                 const void* __restrict__ W2a,
                                                 const void* __restrict__ b2a,
                                                 float* __restrict__ x1) {
    __shared__ ZwSmem s;
    if (get_dt(flag) == DT_BF16)
        zw_body<__hip_bfloat16>((const __hip_bfloat16*)pos, (const __hip_bfloat16*)W2a,
                                (const __hip_bfloat16*)b2a, x1, s);
    else
        zw_body<float>((const float*)pos, (const float*)W2a, (const float*)b2a, x1, s);
}

// ---------------------------------------------------------------------------
// conv2+head (unchanged): h1[n] = relu(zw[j_n] - pos_i@W2a_bot).
// ---------------------------------------------------------------------------
struct Conv2Smem {
    alignas(16) float h1s[4][9 * 64];
    alignas(16) float row[4][128];
    alignas(16) float wbot[3 * 64];
    alignas(16) float wc[640];
    float bcs[5];
    float sv[4][5];
    int   nb[4][9];
};

template <typename T>
__device__ void conv2_body(const T* __restrict__ pos, const int* __restrict__ idx,
                           const float* __restrict__ zw,
                           const T* __restrict__ W2a, const T* __restrict__ W2b,
                           const T* __restrict__ b2b, const T* __restrict__ Wc,
                           const T* __restrict__ bc, T* __restrict__ out, Conv2Smem& s) {
    const int tid  = threadIdx.x;
    const int l    = tid & 127;
    const int half = tid >> 7;

    float wcol[64];
#pragma unroll
    for (int k = 0; k < 64; ++k) wcol[k] = ldf(W2b, k * 128 + l);
    const float bBl = ldf(b2b, l);

    for (int e = tid; e < 192; e += 256) s.wbot[e] = ldf(W2a, 4096 + e);
    for (int e = tid; e < 640; e += 256) s.wc[e] = ldf(Wc, e);
    if (tid < 5) s.bcs[tid] = ldf(bc, tid);

    const int tl   = tid >> 6;
    const int lane = tid & 63;
    const int i    = blockIdx.x * 4 + tl;

    if (lane < 9) s.nb[tl][lane] = clamp_idx(idx[i * 9 + lane]);
    const float pi0 = ldf(pos, 3 * i + 0);
    const float pi1 = ldf(pos, 3 * i + 1);
    const float pi2 = ldf(pos, 3 * i + 2);
    __syncthreads();

    {
        const float vi = fmaf(pi0, s.wbot[lane], fmaf(pi1, s.wbot[64 + lane], pi2 * s.wbot[128 + lane]));
#pragma unroll
        for (int n = 0; n < 9; ++n) {
            const int j = s.nb[tl][n];
            s.h1s[tl][n * 64 + lane] = fmaxf(zw[j * 64 + lane] - vi, 0.0f);
        }
    }
    __syncthreads();

#pragma unroll
    for (int tt = 0; tt < 2; ++tt) {
        const int tgt = half * 2 + tt;
        float acc = -INFINITY;
        for (int n = 0; n < 9; ++n) {
            float v = bBl;
            for (int k = 0; k < 64; k += 4) {
                const float4 hv = *(const float4*)&s.h1s[tgt][n * 64 + k];
                v = fmaf(hv.x, wcol[k + 0], v);
                v = fmaf(hv.y, wcol[k + 1], v);
                v = fmaf(hv.z, wcol[k + 2], v);
                v = fmaf(hv.w, wcol[k + 3], v);
            }
            acc = fmaxf(acc, v);
        }
        s.row[tgt][l] = fmaxf(acc, 0.0f);
    }
    __syncthreads();

    if (tid < 20) {
        const int tgt = tid / 5, o = tid % 5;
        float v = s.bcs[o];
        for (int k = 0; k < 128; ++k) v = fmaf(s.row[tgt][k], s.wc[k * 5 + o], v);
        s.sv[tgt][o] = v;
    }
    __syncthreads();
    if (tid < 20) {
        const int tgt = tid / 5, o = tid % 5;
        float m = s.sv[tgt][0];
#pragma unroll
        for (int q = 1; q < 5; ++q) m = fmaxf(m, s.sv[tgt][q]);
        float sum = 0.0f;
#pragma unroll
        for (int q = 0; q < 5; ++q) sum += expf(s.sv[tgt][q] - m);
        const float lse = m + logf(sum);
        stf(out, (blockIdx.x * 4 + tgt) * 5 + o, s.sv[tgt][o] - lse);
    }
}

__global__ __launch_bounds__(256) void conv2_head_kernel(const void* __restrict__ pos,
                                                         const int* __restrict__ flag,
                                                         const int* __restrict__ idx,
                                                         const float* __restrict__ zw,
                                                         const void* __restrict__ W2a,
                                                         const void* __restrict__ W2b,
                                                         const void* __restrict__ b2b,
                                                         const void* __restrict__ Wc,
                                                         const void* __restrict__ bc,
                                                         void* __restrict__ out) {
    __shared__ Conv2Smem s;
    if (get_dt(flag) == DT_BF16)
        conv2_body<__hip_bfloat16>((const __hip_bfloat16*)pos, idx, zw,
            (const __hip_bfloat16*)W2a, (const __hip_bfloat16*)W2b, (const __hip_bfloat16*)b2b,
            (const __hip_bfloat16*)Wc, (const __hip_bfloat16*)bc, (__hip_bfloat16*)out, s);
    else
        conv2_body<float>((const float*)pos, idx, zw, (const float*)W2a, (const float*)W2b,
            (const float*)b2b, (const float*)Wc, (const float*)bc, (float*)out, s);
}

// ---------------------------------------------------------------------------
extern "C" void kernel_launch(void* const* d_in, const int* in_sizes, int n_in,
                              void* d_out, int out_size, void* d_ws, size_t ws_size,
                              hipStream_t stream) {
    if (ws_size < (size_t)WS_NEEDED) return;

    char* ws = (char*)d_ws;
    int*    flag     = (int*)(ws + WS_FLAG_OFF);
    int*    idx      = (int*)(ws + WS_IDX_OFF);
    float*  x1       = (float*)(ws + WS_X1_OFF);
    int*    sat      = (int*)(ws + WS_SAT_OFF);
    int*    cstart   = (int*)(ws + WS_START_OFF);
    int*    cursor   = (int*)(ws + WS_CURSOR_OFF);
    int*    pid      = (int*)(ws + WS_PID_OFF);
    float4* pts4     = (float4*)(ws + WS_PTS_OFF);
    int*    rowtot   = (int*)(ws + WS_ROWTOT_OFF);
    int*    rowstart = (int*)(ws + WS_ROWSTART_OFF);

    zero_kernel<<<NCELLS / 256, 256, 0, stream>>>(sat, flag);
    sniff_kernel<<<64, 256, 0, stream>>>((const unsigned short*)d_in[0], flag);
    grid_count_kernel<<<N_PTS / 256, 256, 0, stream>>>(d_in[0], flag, sat);
    rowscan_kernel<<<NROWS2D / 256, 256, 0, stream>>>(sat, rowtot);
    rowoffset_kernel<<<1, 256, 0, stream>>>(rowtot, rowstart);
    cellstart_kernel<<<NROWS2D / 256, 256, 0, stream>>>(sat, rowstart, cstart, cursor);
    saty_kernel<<<NROWS2D / 256, 256, 0, stream>>>(sat);
    satz_kernel<<<NROWS2D / 256, 256, 0, stream>>>(sat);
    grid_scatter_kernel<<<N_PTS / 256, 256, 0, stream>>>(d_in[0], flag, cursor, pts4, pid);
    knn_grid_kernel<<<N_PTS / 8, 256, 0, stream>>>(d_in[0], flag, cstart, sat, pts4, pid, idx);
    conv1_kernel<<<N_PTS / 4, 256, 0, stream>>>(d_in[0], flag, idx,
        d_in[1], d_in[2], d_in[3], d_in[4], x1);
    zw_kernel<<<N_PTS / 16, 256, 0, stream>>>(d_in[0], flag, d_in[5], d_in[6], x1);
    conv2_head_kernel<<<N_PTS / 4, 256, 0, stream>>>(d_in[0], flag, idx, x1,
        d_in[5], d_in[7], d_in[8], d_in[9], d_in[10], d_out);
}

// Round 8
// 241.604 us; speedup vs baseline: 1.6235x; 1.0115x over previous
//
#include <hip/hip_runtime.h>
#include <hip/hip_bf16.h>
#include <math.h>

#define N_PTS 16384
#define KNN 8

#define DT_BF16 1
#define DT_FP32 2

// Workspace layout:
//   flag : int          @ 0
//   idx  : int  [N*9]   @ 64        -> 589,824 B
//   x1   : f32  [N*64]  @ 589,888   -> 4,194,304 B
// Grid-KNN scratch lives INSIDE the x1 region (dead before conv1 writes x1):
//   sat      : int [110592]  @ x1+0        (counts -> x-prefix -> full 3D SAT)
//   start    : int [110593]  @ x1+442368   (cell starts + sentinel)
//   cursor   : int [110592]  @ x1+884800
//   pid      : int [16384]   @ x1+1327168
//   pts4     : f4  [16384]   @ x1+1392704
//   rowtot   : int [2304]    @ x1+1654848
//   rowstart : int [2304]    @ x1+1664064
//   xpre     : int [110592]  @ x1+1673280  (x-prefix copy; end 2,115,648 <= 4,194,304)
#define WS_FLAG_OFF 0
#define WS_IDX_OFF  64
#define WS_X1_OFF   589888
#define WS_NEEDED   4784192

#define WS_SAT_OFF      (WS_X1_OFF)
#define WS_START_OFF    (WS_X1_OFF + 442368)
#define WS_CURSOR_OFF   (WS_X1_OFF + 884800)
#define WS_PID_OFF      (WS_X1_OFF + 1327168)
#define WS_PTS_OFF      (WS_X1_OFF + 1392704)
#define WS_ROWTOT_OFF   (WS_X1_OFF + 1654848)
#define WS_ROWSTART_OFF (WS_X1_OFF + 1664064)
#define WS_XPRE_OFF     (WS_X1_OFF + 1673280)

#define GRID_R   48
#define NROWS2D  (GRID_R * GRID_R)          // 2304 (y,z) rows
#define NCELLS   (GRID_R * GRID_R * GRID_R) // 110592
#define GLO      -4.5f
#define CELL_E   0.1875f
#define CELL_INV 5.3333335f
#define NBR_MIN  26   // preferred SAT window population (incl. self)
#define NBR_LO   9    // minimum population: 8 neighbors + self -> finite d8
#define M_CAP    768  // if the NBR_MIN window holds more than this, use the LO window

__device__ __forceinline__ float bf2f(__hip_bfloat16 v) { return __bfloat162float(v); }

__device__ __forceinline__ float ldf(const float* p, int i) { return p[i]; }
__device__ __forceinline__ float ldf(const __hip_bfloat16* p, int i) { return bf2f(p[i]); }
__device__ __forceinline__ void stf(float* p, int i, float v) { p[i] = v; }
__device__ __forceinline__ void stf(__hip_bfloat16* p, int i, float v) { p[i] = __float2bfloat16(v); }

__device__ __forceinline__ int clamp_idx(int j) {
    return ((unsigned)j < (unsigned)N_PTS) ? j : 0;
}

__device__ __forceinline__ int cell_of(float v) {
    int c = (int)((v - GLO) * CELL_INV);
    return min(max(c, 0), GRID_R - 1);
}

// flag[0] holds the sniffer's bad-count; >16 => fp32 input.
__device__ __forceinline__ int get_dt(const int* flag) {
    return (flag[0] > 16) ? DT_FP32 : DT_BF16;
}

// ---------------------------------------------------------------------------
// zero: cnt[] and flag.
// ---------------------------------------------------------------------------
__global__ __launch_bounds__(256) void zero_kernel(int* __restrict__ cnt, int* __restrict__ flag) {
    const int e = blockIdx.x * 256 + threadIdx.x;
    cnt[e] = 0;
    if (e == 0) flag[0] = 0;
}

// ---------------------------------------------------------------------------
// sniff (multi-block).
// ---------------------------------------------------------------------------
__global__ __launch_bounds__(256) void sniff_kernel(const unsigned short* __restrict__ posu,
                                                    int* __restrict__ flag) {
    __shared__ int red[256];
    int local = 0;
    for (int e = blockIdx.x * 256 + threadIdx.x; e < 3 * N_PTS; e += 64 * 256) {
        const float v = __uint_as_float(((unsigned)posu[e]) << 16);
        if (!(fabsf(v) <= 64.0f)) local++;
    }
    red[threadIdx.x] = local;
    __syncthreads();
    for (int s = 128; s > 0; s >>= 1) {
        if (threadIdx.x < s) red[threadIdx.x] += red[threadIdx.x + s];
        __syncthreads();
    }
    if (threadIdx.x == 0 && red[0] > 0) atomicAdd(flag, red[0]);
}

// ---------------------------------------------------------------------------
// Grid build (parallel): count -> rowscan(+xpre) -> rowoffset ->
// {cellstart+saty fused} -> {satz+scatter fused}.
// ---------------------------------------------------------------------------
template <typename T>
__device__ __forceinline__ void count_body(const T* __restrict__ pos, int* __restrict__ cnt) {
    const int i = blockIdx.x * 256 + threadIdx.x;
    const float x = ldf(pos, 3 * i + 0);
    const float y = ldf(pos, 3 * i + 1);
    const float z = ldf(pos, 3 * i + 2);
    const int c = (cell_of(z) * GRID_R + cell_of(y)) * GRID_R + cell_of(x);
    atomicAdd(&cnt[c], 1);
}

__global__ __launch_bounds__(256) void grid_count_kernel(const void* __restrict__ pos,
                                                         const int* __restrict__ flag,
                                                         int* __restrict__ cnt) {
    if (get_dt(flag) == DT_BF16) count_body<__hip_bfloat16>((const __hip_bfloat16*)pos, cnt);
    else                         count_body<float>((const float*)pos, cnt);
}

// x-prefix per row (in place over sat, plus copy to xpre), rowtot = row sum.
__global__ __launch_bounds__(256) void rowscan_kernel(int* __restrict__ sat,
                                                      int* __restrict__ xpre,
                                                      int* __restrict__ rowtot) {
    const int t = blockIdx.x * 256 + threadIdx.x;   // row < 2304
    const int rb = t * GRID_R;
    int acc = 0;
    for (int x = 0; x < GRID_R; ++x) {
        acc += sat[rb + x];
        sat[rb + x]  = acc;
        xpre[rb + x] = acc;
    }
    rowtot[t] = acc;
}

// exclusive scan of 2304 row totals (one block, 256 threads x 9 rows).
__global__ __launch_bounds__(256) void rowoffset_kernel(const int* __restrict__ rowtot,
                                                        int* __restrict__ rowstart) {
    __shared__ int part[256];
    const int t = threadIdx.x;
    int loc[9]; int s = 0;
#pragma unroll
    for (int k = 0; k < 9; ++k) { loc[k] = rowtot[t * 9 + k]; s += loc[k]; }
    part[t] = s;
    __syncthreads();
    for (int off = 1; off < 256; off <<= 1) {
        int v = (t >= off) ? part[t - off] : 0;
        __syncthreads();
        part[t] += v;
        __syncthreads();
    }
    int run = (t == 0) ? 0 : part[t - 1];
#pragma unroll
    for (int k = 0; k < 9; ++k) { rowstart[t * 9 + k] = run; run += loc[k]; }
}

// FUSED: cellstart (from xpre copy -> no dependence on sat) + SAT y-pass.
// Each sat element is written by exactly one block's saty column and read by
// none -> no cross-block hazard.
__global__ __launch_bounds__(256) void cellsaty_kernel(const int* __restrict__ xpre,
                                                       const int* __restrict__ rowstart,
                                                       int* __restrict__ cstart,
                                                       int* __restrict__ cursor,
                                                       int* __restrict__ sat) {
    const int t = blockIdx.x * 256 + threadIdx.x;   // < 2304
    // cellstart for row t
    const int rb = t * GRID_R;
    const int base = rowstart[t];
    int prev = 0;
    for (int x = 0; x < GRID_R; ++x) {
        const int v = base + prev;
        cstart[rb + x] = v;
        cursor[rb + x] = v;
        prev = xpre[rb + x];
    }
    if (t == NROWS2D - 1) cstart[NCELLS] = base + prev;
    // saty for (z,x) column t
    const int z = t / GRID_R, x = t - z * GRID_R;
    const int b2 = z * NROWS2D + x;
    int run = 0;
#pragma unroll
    for (int y = 0; y < GRID_R; ++y) {
        run += sat[b2 + y * GRID_R];
        sat[b2 + y * GRID_R] = run;
    }
}

// FUSED: SAT z-pass (blocks 0..8) + scatter (blocks 9..72). Independent data.
template <typename T>
__device__ __forceinline__ void scatter_body(const T* __restrict__ pos, int i,
                                             int* __restrict__ cursor,
                                             float4* __restrict__ pts4, int* __restrict__ pid) {
    const float x = ldf(pos, 3 * i + 0);
    const float y = ldf(pos, 3 * i + 1);
    const float z = ldf(pos, 3 * i + 2);
    const int c = (cell_of(z) * GRID_R + cell_of(y)) * GRID_R + cell_of(x);
    const int slot = atomicAdd(&cursor[c], 1);
    const float sq = fmaf(x, x, fmaf(y, y, z * z));
    pts4[slot] = make_float4(-2.0f * x, -2.0f * y, -2.0f * z, sq);
    pid[slot] = i;
}

__global__ __launch_bounds__(256) void satzscatter_kernel(const void* __restrict__ pos,
                                                          const int* __restrict__ flag,
                                                          int* __restrict__ sat,
                                                          int* __restrict__ cursor,
                                                          float4* __restrict__ pts4,
                                                          int* __restrict__ pid) {
    if (blockIdx.x < 9) {
        const int t = blockIdx.x * 256 + threadIdx.x;   // < 2304
        int run = 0;
#pragma unroll
        for (int z = 0; z < GRID_R; ++z) {
            run += sat[t + z * NROWS2D];
            sat[t + z * NROWS2D] = run;
        }
    } else {
        const int i = (blockIdx.x - 9) * 256 + threadIdx.x;
        if (get_dt(flag) == DT_BF16) scatter_body<__hip_bfloat16>((const __hip_bfloat16*)pos, i, cursor, pts4, pid);
        else                         scatter_body<float>((const float*)pos, i, cursor, pts4, pid);
    }
}

// ---------------------------------------------------------------------------
// KNN v9: v8 + two-level probe (outlier straggler fix).
// r7 counters: knn VALUBusy 27%, Occ 26% -> straggler waves again. Cause:
// extreme outliers whose 26-point window reaches r~32 scan M~16k candidates
// in ONE wave (~25 us). v9 probes BOTH r9 (>=9 points: 8 nbrs + self ->
// finite d8) and r26 from the same ballot round; uses the 26-window only if
// its population <= M_CAP. Outliers scan a tiny first window; the exact
// distance-bounded second pass (geometry caps M to ~hundreds) guarantees
// exactness as before. Lex (d, idx) order everywhere.
// ---------------------------------------------------------------------------
__device__ __forceinline__ int sat_at(const int* __restrict__ sat, int x, int y, int z) {
    if (x < 0 || y < 0 || z < 0) return 0;
    return sat[(z * GRID_R + y) * GRID_R + x];
}

__device__ __forceinline__ int boxcount(const int* __restrict__ sat,
                                        int x0, int x1, int y0, int y1, int z0, int z1) {
    return sat_at(sat, x1, y1, z1) - sat_at(sat, x0 - 1, y1, z1)
         - sat_at(sat, x1, y0 - 1, z1) - sat_at(sat, x1, y1, z0 - 1)
         + sat_at(sat, x0 - 1, y0 - 1, z1) + sat_at(sat, x0 - 1, y1, z0 - 1)
         + sat_at(sat, x1, y0 - 1, z0 - 1) - sat_at(sat, x0 - 1, y0 - 1, z0 - 1);
}

template <typename T>
__device__ void knn_body(const T* __restrict__ pos,
                         const int* __restrict__ cstart, const int* __restrict__ sat,
                         const float4* __restrict__ pts4, const int* __restrict__ pid,
                         int* __restrict__ idx_out,
                         int* __restrict__ rs, int* __restrict__ epf) {
    const int tid  = threadIdx.x;
    const int lane = tid & 31;                 // lane within 32-lane subgroup
    const int i    = blockIdx.x * 8 + (tid >> 5);

    const float pix = ldf(pos, 3 * i + 0);
    const float piy = ldf(pos, 3 * i + 1);
    const float piz = ldf(pos, 3 * i + 2);
    const float sqi = fmaf(pix, pix, fmaf(piy, piy, piz * piz));
    const int cx = cell_of(pix), cy = cell_of(piy), cz = cell_of(piz);

    float bd[KNN];
    int   bi[KNN];
#pragma unroll
    for (int q = 0; q < KNN; ++q) { bd[q] = INFINITY; bi[q] = 0x7fffffff; }
    float tau = INFINITY;

    auto do_insert = [&](float d, int pj) {
        float cd = d; int ci = pj;
#pragma unroll
        for (int q = 0; q < KNN; ++q) {
            const bool ins = (cd < bd[q]) || (cd == bd[q] && ci < bi[q]);
            const float nd = ins ? cd : bd[q];
            const int   ni = ins ? ci : bi[q];
            const float od = ins ? bd[q] : cd;
            const int   oi = ins ? bi[q] : ci;
            bd[q] = nd; bi[q] = ni; cd = od; ci = oi;
        }
        tau = fminf(tau, bd[KNN - 1]);
    };

    // window scan: 32-row chunks; exclusive prefix in LDS; per-candidate
    // binary search (independent) + 4-wide pipelined gathers.
    auto scan_win = [&](int rr) {
        const int x0 = max(cx - rr, 0), x1 = min(cx + rr, GRID_R - 1);
        const int y0 = max(cy - rr, 0), y1 = min(cy + rr, GRID_R - 1);
        const int z0 = max(cz - rr, 0), z1 = min(cz + rr, GRID_R - 1);
        const int ny = y1 - y0 + 1;
        const int R  = ny * (z1 - z0 + 1);
        const int xs = x1 - x0 + 1;
        for (int cb = 0; cb < R; cb += 32) {
            const int lr = cb + lane;
            int cnt_r = 0, st_r = 0;
            if (lr < R) {
                const int iz = lr / ny;
                const int iy = lr - iz * ny;
                const int c0 = ((z0 + iz) * GRID_R + (y0 + iy)) * GRID_R + x0;
                st_r  = cstart[c0];
                cnt_r = cstart[c0 + xs] - st_r;
            }
            int pv = cnt_r;
#pragma unroll
            for (int s = 1; s < 32; s <<= 1) {
                const int u = __shfl_up(pv, s, 32);
                if (lane >= s) pv += u;
            }
            const int Mtot = __shfl(pv, 31, 32);
            asm volatile("s_waitcnt lgkmcnt(0)" ::: "memory");  // prev chunk reads done
            rs[lane]  = st_r;
            epf[lane] = (lr < R) ? (pv - cnt_r) : 0x7fffffff;   // exclusive prefix / +inf
            asm volatile("s_waitcnt lgkmcnt(0)" ::: "memory");  // staging visible
            for (int tb = 0; tb < Mtot; tb += 128) {
                float dls[4]; int pjs[4];
#pragma unroll
                for (int k = 0; k < 4; ++k) {
                    const int t = tb + (k << 5) + lane;
                    dls[k] = INFINITY; pjs[k] = i;              // sentinel: skipped
                    if (t < Mtot) {
                        // largest p with epf[p] <= t (epf[0] = 0)
                        int p = 0;
#pragma unroll
                        for (int st = 16; st >= 1; st >>= 1)
                            if (epf[p + st] <= t) p += st;
                        const int si = rs[p] + (t - epf[p]);
                        const float4 cq = pts4[si];
                        pjs[k] = pid[si];
                        dls[k] = fmaf(cq.x, pix, fmaf(cq.y, piy, fmaf(cq.z, piz, cq.w)));
                    }
                }
#pragma unroll
                for (int k = 0; k < 4; ++k)
                    if (pjs[k] != i && dls[k] <= tau) do_insert(dls[k], pjs[k]);
            }
        }
    };

    float od[KNN];
    int   oi[KNN];
    // destructive 8-pick lex merge of the 32 per-lane sorted lists; picks
    // captured in order -> doubles as the output.
    auto merge_out = [&]() {
#pragma unroll
        for (int k = 0; k < KNN; ++k) {
            float dw = bd[0];
            int   iw = bi[0];
#pragma unroll
            for (int s = 1; s < 32; s <<= 1) {
                const float dx = __shfl_xor(dw, s, 32);
                const int   ix = __shfl_xor(iw, s, 32);
                if (dx < dw || (dx == dw && ix < iw)) { dw = dx; iw = ix; }
            }
            if (bd[0] == dw && bi[0] == iw) {
#pragma unroll
                for (int q = 0; q < KNN - 1; ++q) { bd[q] = bd[q + 1]; bi[q] = bi[q + 1]; }
                bd[KNN - 1] = INFINITY; bi[KNN - 1] = 0x7fffffff;
            }
            od[k] = dw; oi[k] = iw;
        }
    };

    // ---- 1) two-level SAT radius probe: lane l tests radius l+1 (<=32) ----
    int r;
    {
        const int rl = lane + 1;
        const int bx0 = max(cx - rl, 0), bx1 = min(cx + rl, GRID_R - 1);
        const int by0 = max(cy - rl, 0), by1 = min(cy + rl, GRID_R - 1);
        const int bz0 = max(cz - rl, 0), bz1 = min(cz + rl, GRID_R - 1);
        const int cntl = boxcount(sat, bx0, bx1, by0, by1, bz0, bz1);
        const unsigned long long m9  = __ballot(cntl >= NBR_LO);
        const unsigned long long m26 = __ballot(cntl >= NBR_MIN);
        const unsigned sh  = (unsigned)(tid & 32);
        const unsigned mh9  = (unsigned)(m9  >> sh);
        const unsigned mh26 = (unsigned)(m26 >> sh);
        const int r9  = mh9  ? (int)__ffs(mh9)  : 32;
        const int r26 = mh26 ? (int)__ffs(mh26) : 32;
        const int cnt26 = __shfl(cntl, r26 - 1, 32);   // population of 26-window
        r = (cnt26 <= M_CAP) ? r26 : r9;
    }

    // ---- 2) window scan at r ----
    scan_win(r);

    // ---- 3) fused merge + termination; exact bounded second pass on failure ----
    {
        float mg = INFINITY;
        bool full = true;
        if (cx - r > 0)          { mg = fminf(mg, pix - (GLO + (float)(cx - r) * CELL_E));     full = false; }
        if (cx + r < GRID_R - 1) { mg = fminf(mg, (GLO + (float)(cx + r + 1) * CELL_E) - pix); full = false; }
        if (cy - r > 0)          { mg = fminf(mg, piy - (GLO + (float)(cy - r) * CELL_E));     full = false; }
        if (cy + r < GRID_R - 1) { mg = fminf(mg, (GLO + (float)(cy + r + 1) * CELL_E) - piy); full = false; }
        if (cz - r > 0)          { mg = fminf(mg, piz - (GLO + (float)(cz - r) * CELL_E));     full = false; }
        if (cz + r < GRID_R - 1) { mg = fminf(mg, (GLO + (float)(cz + r + 1) * CELL_E) - piz); full = false; }

        merge_out();                             // common path: the ONLY merge
        bool done = full;
        const float d8 = od[KNN - 1];
        if (!full) {
            const float mge  = mg - 1e-5f;
            const float need = mge * mge - sqi;  // d_real < mge^2  <=>  d' < need
            done = (d8 < need);                  // strict: boundary ties keep scanning
        }

        if (!done) {
            // required radius: per direction, margin >= s2 or clipped.
            float s2 = sqrtf(fmaxf(d8 + sqi, 0.0f)) + 1e-4f;  // real-distance bound
            s2 = fminf(s2, 9.0f);                              // cap -> full grid
            auto dneed = [&](float frac, int clip) -> int {
                int nd = (int)ceilf((s2 - frac) * CELL_INV);
                nd = max(nd, 0);
                return min(nd, clip);
            };
            const float fxm = pix - (GLO + (float)cx * CELL_E);
            const float fxp = (GLO + (float)(cx + 1) * CELL_E) - pix;
            const float fym = piy - (GLO + (float)cy * CELL_E);
            const float fyp = (GLO + (float)(cy + 1) * CELL_E) - piy;
            const float fzm = piz - (GLO + (float)cz * CELL_E);
            const float fzp = (GLO + (float)(cz + 1) * CELL_E) - piz;
            int r2 = r + 1;
            r2 = max(r2, dneed(fxm, cx));
            r2 = max(r2, dneed(fxp, GRID_R - 1 - cx));
            r2 = max(r2, dneed(fym, cy));
            r2 = max(r2, dneed(fyp, GRID_R - 1 - cy));
            r2 = max(r2, dneed(fzm, cz));
            r2 = max(r2, dneed(fzp, GRID_R - 1 - cz));
            r2 = min(r2, GRID_R);

            // fresh lists; tau seeded with pass-1 d8 (superset window => exact:
            // every true top-8 distance is <= d8, so the gate admits them all)
#pragma unroll
            for (int q = 0; q < KNN; ++q) { bd[q] = INFINITY; bi[q] = 0x7fffffff; }
            tau = d8;
            scan_win(r2);
            merge_out();
        }
    }

    if (lane == 0) {
#pragma unroll
        for (int k = 0; k < KNN; ++k) idx_out[i * 9 + k] = clamp_idx(oi[k]);
        idx_out[i * 9 + 8] = i;
    }
}

__global__ __launch_bounds__(256) void knn_grid_kernel(const void* __restrict__ pos,
                                                       const int* __restrict__ flag,
                                                       const int* __restrict__ cstart,
                                                       const int* __restrict__ sat,
                                                       const float4* __restrict__ pts4,
                                                       const int* __restrict__ pid,
                                                       int* __restrict__ idx_out) {
    __shared__ int rs[8][32];
    __shared__ int epf[8][32];
    const int sg = threadIdx.x >> 5;
    if (get_dt(flag) == DT_BF16)
        knn_body<__hip_bfloat16>((const __hip_bfloat16*)pos, cstart, sat, pts4, pid, idx_out,
                                 rs[sg], epf[sg]);
    else
        knn_body<float>((const float*)pos, cstart, sat, pts4, pid, idx_out, rs[sg], epf[sg]);
}

// ---------------------------------------------------------------------------
// conv1: first layer factored; wB dot now uses 4 independent partial sums
// (r7: the 32-deep serial fma chain stalled at ~3 waves/SIMD occupancy).
// Re-association noise ~1e-6 << tolerance (order already differs from jax).
// ---------------------------------------------------------------------------
struct Conv1Smem {
    alignas(16) float wB[32 * 64];
    alignas(16) float h1s[4][9 * 32];
    alignas(16) float wsum[3 * 32];
    alignas(16) float wbot[3 * 32];
    alignas(16) float posn[4][9][3];
    float bA[32];
    float bB[64];
};

template <typename T>
__device__ void conv1_body(const T* __restrict__ pos, const int* __restrict__ idx,
                           const T* __restrict__ W1a, const T* __restrict__ b1a,
                           const T* __restrict__ W1b, const T* __restrict__ b1b,
                           float* __restrict__ x1, Conv1Smem& s) {
    const int tid = threadIdx.x;
    for (int e = tid; e < 96; e += 256) {
        const float bot = ldf(W1a, 96 + e);
        s.wsum[e] = ldf(W1a, e) + bot;
        s.wbot[e] = bot;
    }
    if (tid < 32) s.bA[tid] = ldf(b1a, tid);
    for (int e = tid; e < 2048; e += 256) s.wB[e] = ldf(W1b, e);
    if (tid < 64) s.bB[tid] = ldf(b1b, tid);

    const int tl   = tid >> 6;
    const int lane = tid & 63;
    const int i    = blockIdx.x * 4 + tl;

    if (lane < 27) {
        const int n = lane / 3, c = lane % 3;
        const int j = clamp_idx(idx[i * 9 + n]);
        s.posn[tl][n][c] = ldf(pos, 3 * j + c);
    }
    const float pi0 = ldf(pos, 3 * i + 0);
    const float pi1 = ldf(pos, 3 * i + 1);
    const float pi2 = ldf(pos, 3 * i + 2);
    __syncthreads();

    for (int e = lane; e < 288; e += 64) {
        const int n = e >> 5, k = e & 31;
        float b = fmaf(pi0, s.wbot[k], fmaf(pi1, s.wbot[32 + k], pi2 * s.wbot[64 + k]));
        float v = s.bA[k] - b;
        v = fmaf(s.posn[tl][n][0], s.wsum[k], v);
        v = fmaf(s.posn[tl][n][1], s.wsum[32 + k], v);
        v = fmaf(s.posn[tl][n][2], s.wsum[64 + k], v);
        s.h1s[tl][n * 32 + k] = fmaxf(v, 0.0f);
    }
    __syncthreads();

    float wcol[32];
#pragma unroll
    for (int k = 0; k < 32; ++k) wcol[k] = s.wB[k * 64 + lane];

    float acc = -INFINITY;
    for (int n = 0; n < 9; ++n) {
        float s0 = s.bB[lane], s1 = 0.0f, s2 = 0.0f, s3 = 0.0f;
#pragma unroll
        for (int k = 0; k < 32; k += 4) {
            s0 = fmaf(s.h1s[tl][n * 32 + k + 0], wcol[k + 0], s0);
            s1 = fmaf(s.h1s[tl][n * 32 + k + 1], wcol[k + 1], s1);
            s2 = fmaf(s.h1s[tl][n * 32 + k + 2], wcol[k + 2], s2);
            s3 = fmaf(s.h1s[tl][n * 32 + k + 3], wcol[k + 3], s3);
        }
        acc = fmaxf(acc, (s0 + s1) + (s2 + s3));
    }
    x1[i * 64 + lane] = fmaxf(acc, 0.0f);
}

__global__ __launch_bounds__(256) void conv1_kernel(const void* __restrict__ pos,
                                                    const int* __restrict__ flag,
                                                    const int* __restrict__ idx,
                                                    const void* __restrict__ W1a,
                                                    const void* __restrict__ b1a,
                                                    const void* __restrict__ W1b,
                                                    const void* __restrict__ b1b,
                                                    float* __restrict__ x1) {
    __shared__ Conv1Smem s;
    if (get_dt(flag) == DT_BF16)
        conv1_body<__hip_bfloat16>((const __hip_bfloat16*)pos, idx,
            (const __hip_bfloat16*)W1a, (const __hip_bfloat16*)b1a,
            (const __hip_bfloat16*)W1b, (const __hip_bfloat16*)b1b, x1, s);
    else
        conv1_body<float>((const float*)pos, idx, (const float*)W1a, (const float*)b1a,
            (const float*)W1b, (const float*)b1b, x1, s);
}

// ---------------------------------------------------------------------------
// zw (unchanged): per-point precompute for conv2's first layer.
// ---------------------------------------------------------------------------
struct ZwSmem {
    alignas(16) float wA[67 * 64];
    alignas(16) float xrT[4][68][4];
    float bA[64];
};

template <typename T>
__device__ void zw_body(const T* __restrict__ pos, const T* __restrict__ W2a,
                        const T* __restrict__ b2a, float* __restrict__ x1, ZwSmem& s) {
    const int tid  = threadIdx.x;
    const int wv   = tid >> 6;
    const int lane = tid & 63;
    const int j0   = blockIdx.x * 16 + wv * 4;

    for (int e = tid; e < 4288; e += 256) s.wA[e] = ldf(W2a, e);
    if (tid < 64) s.bA[tid] = ldf(b2a, tid);

#pragma unroll
    for (int p = 0; p < 4; ++p)
        s.xrT[wv][lane][p] = x1[(j0 + p) * 64 + lane];
    if (lane < 12) {
        const int p = lane / 3, c = lane % 3;
        s.xrT[wv][64 + c][p] = ldf(pos, 3 * (j0 + p) + c);
    }
    __syncthreads();

    float a0 = s.bA[lane], a1 = a0, a2 = a0, a3 = a0;
    for (int c = 0; c < 67; ++c) {
        const float w = s.wA[c * 64 + lane];
        const float4 xv = *(const float4*)&s.xrT[wv][c][0];
        a0 = fmaf(xv.x, w, a0);
        a1 = fmaf(xv.y, w, a1);
        a2 = fmaf(xv.z, w, a2);
        a3 = fmaf(xv.w, w, a3);
    }
    x1[(j0 + 0) * 64 + lane] = a0;
    x1[(j0 + 1) * 64 + lane] = a1;
    x1[(j0 + 2) * 64 + lane] = a2;
    x1[(j0 + 3) * 64 + lane] = a3;
}

__global__ __launch_bounds__(256) void zw_kernel(const void* __restrict__ pos,
                                                 const int* __restrict__ flag,
                                                 const void* __restrict__ W2a,
                                                 const void* __restrict__ b2a,
                                                 float* __restrict__ x1) {
    __shared__ ZwSmem s;
    if (get_dt(flag) == DT_BF16)
        zw_body<__hip_bfloat16>((const __hip_bfloat16*)pos, (const __hip_bfloat16*)W2a,
                                (const __hip_bfloat16*)b2a, x1, s);
    else
        zw_body<float>((const float*)pos, (const float*)W2a, (const float*)b2a, x1, s);
}

// ---------------------------------------------------------------------------
// conv2+head: h1[n] = relu(zw[j_n] - pos_i@W2a_bot). wB dot now 4 partial
// sums (break the 64-deep serial fma chain — r7's main stall).
// ---------------------------------------------------------------------------
struct Conv2Smem {
    alignas(16) float h1s[4][9 * 64];
    alignas(16) float row[4][128];
    alignas(16) float wbot[3 * 64];
    alignas(16) float wc[640];
    float bcs[5];
    float sv[4][5];
    int   nb[4][9];
};

template <typename T>
__device__ void conv2_body(const T* __restrict__ pos, const int* __restrict__ idx,
                           const float* __restrict__ zw,
                           const T* __restrict__ W2a, const T* __restrict__ W2b,
                           const T* __restrict__ b2b, const T* __restrict__ Wc,
                           const T* __restrict__ bc, T* __restrict__ out, Conv2Smem& s) {
    const int tid  = threadIdx.x;
    const int l    = tid & 127;
    const int half = tid >> 7;

    float wcol[64];
#pragma unroll
    for (int k = 0; k < 64; ++k) wcol[k] = ldf(W2b, k * 128 + l);
    const float bBl = ldf(b2b, l);

    for (int e = tid; e < 192; e += 256) s.wbot[e] = ldf(W2a, 4096 + e);
    for (int e = tid; e < 640; e += 256) s.wc[e] = ldf(Wc, e);
    if (tid < 5) s.bcs[tid] = ldf(bc, tid);

    const int tl   = tid >> 6;
    const int lane = tid & 63;
    const int i    = blockIdx.x * 4 + tl;

    if (lane < 9) s.nb[tl][lane] = clamp_idx(idx[i * 9 + lane]);
    const float pi0 = ldf(pos, 3 * i + 0);
    const float pi1 = ldf(pos, 3 * i + 1);
    const float pi2 = ldf(pos, 3 * i + 2);
    __syncthreads();

    {
        const float vi = fmaf(pi0, s.wbot[lane], fmaf(pi1, s.wbot[64 + lane], pi2 * s.wbot[128 + lane]));
#pragma unroll
        for (int n = 0; n < 9; ++n) {
            const int j = s.nb[tl][n];
            s.h1s[tl][n * 64 + lane] = fmaxf(zw[j * 64 + lane] - vi, 0.0f);
        }
    }
    __syncthreads();

#pragma unroll
    for (int tt = 0; tt < 2; ++tt) {
        const int tgt = half * 2 + tt;
        float acc = -INFINITY;
        for (int n = 0; n < 9; ++n) {
            float s0 = bBl, s1 = 0.0f, s2 = 0.0f, s3 = 0.0f;
#pragma unroll
            for (int k = 0; k < 64; k += 16) {
                const float4 h0 = *(const float4*)&s.h1s[tgt][n * 64 + k + 0];
                const float4 h1 = *(const float4*)&s.h1s[tgt][n * 64 + k + 4];
                const float4 h2 = *(const float4*)&s.h1s[tgt][n * 64 + k + 8];
                const float4 h3 = *(const float4*)&s.h1s[tgt][n * 64 + k + 12];
                s0 = fmaf(h0.x, wcol[k + 0], s0);
                s0 = fmaf(h0.y, wcol[k + 1], s0);
                s0 = fmaf(h0.z, wcol[k + 2], s0);
                s0 = fmaf(h0.w, wcol[k + 3], s0);
                s1 = fmaf(h1.x, wcol[k + 4], s1);
                s1 = fmaf(h1.y, wcol[k + 5], s1);
                s1 = fmaf(h1.z, wcol[k + 6], s1);
                s1 = fmaf(h1.w, wcol[k + 7], s1);
                s2 = fmaf(h2.x, wcol[k + 8], s2);
                s2 = fmaf(h2.y, wcol[k + 9], s2);
                s2 = fmaf(h2.z, wcol[k + 10], s2);
                s2 = fmaf(h2.w, wcol[k + 11], s2);
                s3 = fmaf(h3.x, wcol[k + 12], s3);
                s3 = fmaf(h3.y, wcol[k + 13], s3);
                s3 = fmaf(h3.z, wcol[k + 14], s3);
                s3 = fmaf(h3.w, wcol[k + 15], s3);
            }
            acc = fmaxf(acc, (s0 + s1) + (s2 + s3));
        }
        s.row[tgt][l] = fmaxf(acc, 0.0f);
    }
    __syncthreads();

    if (tid < 20) {
        const int tgt = tid / 5, o = tid % 5;
        float v = s.bcs[o];
        for (int k = 0; k < 128; ++k) v = fmaf(s.row[tgt][k], s.wc[k * 5 + o], v);
        s.sv[tgt][o] = v;
    }
    __syncthreads();
    if (tid < 20) {
        const int tgt = tid / 5, o = tid % 5;
        float m = s.sv[tgt][0];
#pragma unroll
        for (int q = 1; q < 5; ++q) m = fmaxf(m, s.sv[tgt][q]);
        float sum = 0.0f;
#pragma unroll
        for (int q = 0; q < 5; ++q) sum += expf(s.sv[tgt][q] - m);
        const float lse = m + logf(sum);
        stf(out, (blockIdx.x * 4 + tgt) * 5 + o, s.sv[tgt][o] - lse);
    }
}

__global__ __launch_bounds__(256) void conv2_head_kernel(const void* __restrict__ pos,
                                                         const int* __restrict__ flag,
                                                         const int* __restrict__ idx,
                                                         const float* __restrict__ zw,
                                                         const void* __restrict__ W2a,
                                                         const void* __restrict__ W2b,
                                                         const void* __restrict__ b2b,
                                                         const void* __restrict__ Wc,
                                                         const void* __restrict__ bc,
                                                         void* __restrict__ out) {
    __shared__ Conv2Smem s;
    if (get_dt(flag) == DT_BF16)
        conv2_body<__hip_bfloat16>((const __hip_bfloat16*)pos, idx, zw,
            (const __hip_bfloat16*)W2a, (const __hip_bfloat16*)W2b, (const __hip_bfloat16*)b2b,
            (const __hip_bfloat16*)Wc, (const __hip_bfloat16*)bc, (__hip_bfloat16*)out, s);
    else
        conv2_body<float>((const float*)pos, idx, zw, (const float*)W2a, (const float*)W2b,
            (const float*)b2b, (const float*)Wc, (const float*)bc, (float*)out, s);
}

// ---------------------------------------------------------------------------
extern "C" void kernel_launch(void* const* d_in, const int* in_sizes, int n_in,
                              void* d_out, int out_size, void* d_ws, size_t ws_size,
                              hipStream_t stream) {
    if (ws_size < (size_t)WS_NEEDED) return;

    char* ws = (char*)d_ws;
    int*    flag     = (int*)(ws + WS_FLAG_OFF);
    int*    idx      = (int*)(ws + WS_IDX_OFF);
    float*  x1       = (float*)(ws + WS_X1_OFF);
    int*    sat      = (int*)(ws + WS_SAT_OFF);
    int*    cstart   = (int*)(ws + WS_START_OFF);
    int*    cursor   = (int*)(ws + WS_CURSOR_OFF);
    int*    pid      = (int*)(ws + WS_PID_OFF);
    float4* pts4     = (float4*)(ws + WS_PTS_OFF);
    int*    rowtot   = (int*)(ws + WS_ROWTOT_OFF);
    int*    rowstart = (int*)(ws + WS_ROWSTART_OFF);
    int*    xpre     = (int*)(ws + WS_XPRE_OFF);

    zero_kernel<<<NCELLS / 256, 256, 0, stream>>>(sat, flag);
    sniff_kernel<<<64, 256, 0, stream>>>((const unsigned short*)d_in[0], flag);
    grid_count_kernel<<<N_PTS / 256, 256, 0, stream>>>(d_in[0], flag, sat);
    rowscan_kernel<<<NROWS2D / 256, 256, 0, stream>>>(sat, xpre, rowtot);
    rowoffset_kernel<<<1, 256, 0, stream>>>(rowtot, rowstart);
    cellsaty_kernel<<<NROWS2D / 256, 256, 0, stream>>>(xpre, rowstart, cstart, cursor, sat);
    satzscatter_kernel<<<9 + N_PTS / 256, 256, 0, stream>>>(d_in[0], flag, sat, cursor, pts4, pid);
    knn_grid_kernel<<<N_PTS / 8, 256, 0, stream>>>(d_in[0], flag, cstart, sat, pts4, pid, idx);
    conv1_kernel<<<N_PTS / 4, 256, 0, stream>>>(d_in[0], flag, idx,
        d_in[1], d_in[2], d_in[3], d_in[4], x1);
    zw_kernel<<<N_PTS / 16, 256, 0, stream>>>(d_in[0], flag, d_in[5], d_in[6], x1);
    conv2_head_kernel<<<N_PTS / 4, 256, 0, stream>>>(d_in[0], flag, idx, x1,
        d_in[5], d_in[7], d_in[8], d_in[9], d_in[10], d_out);
}

// Round 9
// 235.379 us; speedup vs baseline: 1.6665x; 1.0264x over previous
//
#include <hip/hip_runtime.h>
#include <hip/hip_bf16.h>
#include <math.h>

#define N_PTS 16384
#define KNN 8

#define DT_BF16 1
#define DT_FP32 2

// Workspace layout:
//   flag : int          @ 0
//   idx  : int  [N*9]   @ 64        -> 589,824 B
//   x1   : f32  [N*64]  @ 589,888   -> 4,194,304 B
// Grid-KNN scratch lives INSIDE the x1 region (dead before conv1 writes x1):
//   sat      : int [110592]  @ x1+0        (counts -> x-prefix -> full 3D SAT)
//   start    : int [110593]  @ x1+442368   (cell starts + sentinel)
//   cursor   : int [110592]  @ x1+884800
//   pid      : int [16384]   @ x1+1327168
//   pts4     : f4  [16384]   @ x1+1392704
//   rowtot   : int [2304]    @ x1+1654848
//   rowstart : int [2304]    @ x1+1664064
//   xpre     : int [110592]  @ x1+1673280  (x-prefix copy; end 2,115,648 <= 4,194,304)
#define WS_FLAG_OFF 0
#define WS_IDX_OFF  64
#define WS_X1_OFF   589888
#define WS_NEEDED   4784192

#define WS_SAT_OFF      (WS_X1_OFF)
#define WS_START_OFF    (WS_X1_OFF + 442368)
#define WS_CURSOR_OFF   (WS_X1_OFF + 884800)
#define WS_PID_OFF      (WS_X1_OFF + 1327168)
#define WS_PTS_OFF      (WS_X1_OFF + 1392704)
#define WS_ROWTOT_OFF   (WS_X1_OFF + 1654848)
#define WS_ROWSTART_OFF (WS_X1_OFF + 1664064)
#define WS_XPRE_OFF     (WS_X1_OFF + 1673280)

#define GRID_R   48
#define NROWS2D  (GRID_R * GRID_R)          // 2304 (y,z) rows
#define NCELLS   (GRID_R * GRID_R * GRID_R) // 110592
#define GLO      -4.5f
#define CELL_E   0.1875f
#define CELL_INV 5.3333335f
#define NBR_MIN  40   // r8->r9: 26->40. At 26 the expected d8^2 ~ mg^2 (borderline)
                      // -> ~half of targets failed term-check and rescanned 2x
                      // window. 40 gives d8^2 ~ 0.5*mg^2 -> rare second pass.
#define NBR_LO   9    // minimum population: 8 neighbors + self -> finite d8
#define M_CAP    1024 // if the NBR_MIN window holds more than this, use the LO window

__device__ __forceinline__ float bf2f(__hip_bfloat16 v) { return __bfloat162float(v); }

__device__ __forceinline__ float ldf(const float* p, int i) { return p[i]; }
__device__ __forceinline__ float ldf(const __hip_bfloat16* p, int i) { return bf2f(p[i]); }
__device__ __forceinline__ void stf(float* p, int i, float v) { p[i] = v; }
__device__ __forceinline__ void stf(__hip_bfloat16* p, int i, float v) { p[i] = __float2bfloat16(v); }

__device__ __forceinline__ int clamp_idx(int j) {
    return ((unsigned)j < (unsigned)N_PTS) ? j : 0;
}

__device__ __forceinline__ int cell_of(float v) {
    int c = (int)((v - GLO) * CELL_INV);
    return min(max(c, 0), GRID_R - 1);
}

// flag[0] holds the sniffer's bad-count; >16 => fp32 input.
__device__ __forceinline__ int get_dt(const int* flag) {
    return (flag[0] > 16) ? DT_FP32 : DT_BF16;
}

// ---------------------------------------------------------------------------
// zero: cnt[] and flag.
// ---------------------------------------------------------------------------
__global__ __launch_bounds__(256) void zero_kernel(int* __restrict__ cnt, int* __restrict__ flag) {
    const int e = blockIdx.x * 256 + threadIdx.x;
    cnt[e] = 0;
    if (e == 0) flag[0] = 0;
}

// ---------------------------------------------------------------------------
// sniff (multi-block).
// ---------------------------------------------------------------------------
__global__ __launch_bounds__(256) void sniff_kernel(const unsigned short* __restrict__ posu,
                                                    int* __restrict__ flag) {
    __shared__ int red[256];
    int local = 0;
    for (int e = blockIdx.x * 256 + threadIdx.x; e < 3 * N_PTS; e += 64 * 256) {
        const float v = __uint_as_float(((unsigned)posu[e]) << 16);
        if (!(fabsf(v) <= 64.0f)) local++;
    }
    red[threadIdx.x] = local;
    __syncthreads();
    for (int s = 128; s > 0; s >>= 1) {
        if (threadIdx.x < s) red[threadIdx.x] += red[threadIdx.x + s];
        __syncthreads();
    }
    if (threadIdx.x == 0 && red[0] > 0) atomicAdd(flag, red[0]);
}

// ---------------------------------------------------------------------------
// Grid build (parallel): count -> rowscan(+xpre) -> rowoffset ->
// {cellstart+saty fused} -> {satz+scatter fused}.
// ---------------------------------------------------------------------------
template <typename T>
__device__ __forceinline__ void count_body(const T* __restrict__ pos, int* __restrict__ cnt) {
    const int i = blockIdx.x * 256 + threadIdx.x;
    const float x = ldf(pos, 3 * i + 0);
    const float y = ldf(pos, 3 * i + 1);
    const float z = ldf(pos, 3 * i + 2);
    const int c = (cell_of(z) * GRID_R + cell_of(y)) * GRID_R + cell_of(x);
    atomicAdd(&cnt[c], 1);
}

__global__ __launch_bounds__(256) void grid_count_kernel(const void* __restrict__ pos,
                                                         const int* __restrict__ flag,
                                                         int* __restrict__ cnt) {
    if (get_dt(flag) == DT_BF16) count_body<__hip_bfloat16>((const __hip_bfloat16*)pos, cnt);
    else                         count_body<float>((const float*)pos, cnt);
}

// x-prefix per row (in place over sat, plus copy to xpre), rowtot = row sum.
__global__ __launch_bounds__(256) void rowscan_kernel(int* __restrict__ sat,
                                                      int* __restrict__ xpre,
                                                      int* __restrict__ rowtot) {
    const int t = blockIdx.x * 256 + threadIdx.x;   // row < 2304
    const int rb = t * GRID_R;
    int acc = 0;
    for (int x = 0; x < GRID_R; ++x) {
        acc += sat[rb + x];
        sat[rb + x]  = acc;
        xpre[rb + x] = acc;
    }
    rowtot[t] = acc;
}

// exclusive scan of 2304 row totals (one block, 256 threads x 9 rows).
__global__ __launch_bounds__(256) void rowoffset_kernel(const int* __restrict__ rowtot,
                                                        int* __restrict__ rowstart) {
    __shared__ int part[256];
    const int t = threadIdx.x;
    int loc[9]; int s = 0;
#pragma unroll
    for (int k = 0; k < 9; ++k) { loc[k] = rowtot[t * 9 + k]; s += loc[k]; }
    part[t] = s;
    __syncthreads();
    for (int off = 1; off < 256; off <<= 1) {
        int v = (t >= off) ? part[t - off] : 0;
        __syncthreads();
        part[t] += v;
        __syncthreads();
    }
    int run = (t == 0) ? 0 : part[t - 1];
#pragma unroll
    for (int k = 0; k < 9; ++k) { rowstart[t * 9 + k] = run; run += loc[k]; }
}

// FUSED: cellstart (from xpre copy -> no dependence on sat) + SAT y-pass.
__global__ __launch_bounds__(256) void cellsaty_kernel(const int* __restrict__ xpre,
                                                       const int* __restrict__ rowstart,
                                                       int* __restrict__ cstart,
                                                       int* __restrict__ cursor,
                                                       int* __restrict__ sat) {
    const int t = blockIdx.x * 256 + threadIdx.x;   // < 2304
    const int rb = t * GRID_R;
    const int base = rowstart[t];
    int prev = 0;
    for (int x = 0; x < GRID_R; ++x) {
        const int v = base + prev;
        cstart[rb + x] = v;
        cursor[rb + x] = v;
        prev = xpre[rb + x];
    }
    if (t == NROWS2D - 1) cstart[NCELLS] = base + prev;
    const int z = t / GRID_R, x = t - z * GRID_R;
    const int b2 = z * NROWS2D + x;
    int run = 0;
#pragma unroll
    for (int y = 0; y < GRID_R; ++y) {
        run += sat[b2 + y * GRID_R];
        sat[b2 + y * GRID_R] = run;
    }
}

// FUSED: SAT z-pass (blocks 0..8) + scatter (blocks 9..72).
template <typename T>
__device__ __forceinline__ void scatter_body(const T* __restrict__ pos, int i,
                                             int* __restrict__ cursor,
                                             float4* __restrict__ pts4, int* __restrict__ pid) {
    const float x = ldf(pos, 3 * i + 0);
    const float y = ldf(pos, 3 * i + 1);
    const float z = ldf(pos, 3 * i + 2);
    const int c = (cell_of(z) * GRID_R + cell_of(y)) * GRID_R + cell_of(x);
    const int slot = atomicAdd(&cursor[c], 1);
    const float sq = fmaf(x, x, fmaf(y, y, z * z));
    pts4[slot] = make_float4(-2.0f * x, -2.0f * y, -2.0f * z, sq);
    pid[slot] = i;
}

__global__ __launch_bounds__(256) void satzscatter_kernel(const void* __restrict__ pos,
                                                          const int* __restrict__ flag,
                                                          int* __restrict__ sat,
                                                          int* __restrict__ cursor,
                                                          float4* __restrict__ pts4,
                                                          int* __restrict__ pid) {
    if (blockIdx.x < 9) {
        const int t = blockIdx.x * 256 + threadIdx.x;   // < 2304
        int run = 0;
#pragma unroll
        for (int z = 0; z < GRID_R; ++z) {
            run += sat[t + z * NROWS2D];
            sat[t + z * NROWS2D] = run;
        }
    } else {
        const int i = (blockIdx.x - 9) * 256 + threadIdx.x;
        if (get_dt(flag) == DT_BF16) scatter_body<__hip_bfloat16>((const __hip_bfloat16*)pos, i, cursor, pts4, pid);
        else                         scatter_body<float>((const float*)pos, i, cursor, pts4, pid);
    }
}

// ---------------------------------------------------------------------------
// KNN v10 = v9 with NBR_MIN 40 (second-pass-rate fix, see #define comment).
// Structure unchanged: two targets per wave (32-lane subgroups), two-level
// probe, binary-search + 4-wide pipelined candidate scan, fused merge-as-
// output, exact distance-bounded second pass. Lex (d, idx) everywhere.
// ---------------------------------------------------------------------------
__device__ __forceinline__ int sat_at(const int* __restrict__ sat, int x, int y, int z) {
    if (x < 0 || y < 0 || z < 0) return 0;
    return sat[(z * GRID_R + y) * GRID_R + x];
}

__device__ __forceinline__ int boxcount(const int* __restrict__ sat,
                                        int x0, int x1, int y0, int y1, int z0, int z1) {
    return sat_at(sat, x1, y1, z1) - sat_at(sat, x0 - 1, y1, z1)
         - sat_at(sat, x1, y0 - 1, z1) - sat_at(sat, x1, y1, z0 - 1)
         + sat_at(sat, x0 - 1, y0 - 1, z1) + sat_at(sat, x0 - 1, y1, z0 - 1)
         + sat_at(sat, x1, y0 - 1, z0 - 1) - sat_at(sat, x0 - 1, y0 - 1, z0 - 1);
}

template <typename T>
__device__ void knn_body(const T* __restrict__ pos,
                         const int* __restrict__ cstart, const int* __restrict__ sat,
                         const float4* __restrict__ pts4, const int* __restrict__ pid,
                         int* __restrict__ idx_out,
                         int* __restrict__ rs, int* __restrict__ epf) {
    const int tid  = threadIdx.x;
    const int lane = tid & 31;                 // lane within 32-lane subgroup
    const int i    = blockIdx.x * 8 + (tid >> 5);

    const float pix = ldf(pos, 3 * i + 0);
    const float piy = ldf(pos, 3 * i + 1);
    const float piz = ldf(pos, 3 * i + 2);
    const float sqi = fmaf(pix, pix, fmaf(piy, piy, piz * piz));
    const int cx = cell_of(pix), cy = cell_of(piy), cz = cell_of(piz);

    float bd[KNN];
    int   bi[KNN];
#pragma unroll
    for (int q = 0; q < KNN; ++q) { bd[q] = INFINITY; bi[q] = 0x7fffffff; }
    float tau = INFINITY;

    auto do_insert = [&](float d, int pj) {
        float cd = d; int ci = pj;
#pragma unroll
        for (int q = 0; q < KNN; ++q) {
            const bool ins = (cd < bd[q]) || (cd == bd[q] && ci < bi[q]);
            const float nd = ins ? cd : bd[q];
            const int   ni = ins ? ci : bi[q];
            const float od = ins ? bd[q] : cd;
            const int   oi = ins ? bi[q] : ci;
            bd[q] = nd; bi[q] = ni; cd = od; ci = oi;
        }
        tau = fminf(tau, bd[KNN - 1]);
    };

    auto scan_win = [&](int rr) {
        const int x0 = max(cx - rr, 0), x1 = min(cx + rr, GRID_R - 1);
        const int y0 = max(cy - rr, 0), y1 = min(cy + rr, GRID_R - 1);
        const int z0 = max(cz - rr, 0), z1 = min(cz + rr, GRID_R - 1);
        const int ny = y1 - y0 + 1;
        const int R  = ny * (z1 - z0 + 1);
        const int xs = x1 - x0 + 1;
        for (int cb = 0; cb < R; cb += 32) {
            const int lr = cb + lane;
            int cnt_r = 0, st_r = 0;
            if (lr < R) {
                const int iz = lr / ny;
                const int iy = lr - iz * ny;
                const int c0 = ((z0 + iz) * GRID_R + (y0 + iy)) * GRID_R + x0;
                st_r  = cstart[c0];
                cnt_r = cstart[c0 + xs] - st_r;
            }
            int pv = cnt_r;
#pragma unroll
            for (int s = 1; s < 32; s <<= 1) {
                const int u = __shfl_up(pv, s, 32);
                if (lane >= s) pv += u;
            }
            const int Mtot = __shfl(pv, 31, 32);
            asm volatile("s_waitcnt lgkmcnt(0)" ::: "memory");  // prev chunk reads done
            rs[lane]  = st_r;
            epf[lane] = (lr < R) ? (pv - cnt_r) : 0x7fffffff;   // exclusive prefix / +inf
            asm volatile("s_waitcnt lgkmcnt(0)" ::: "memory");  // staging visible
            for (int tb = 0; tb < Mtot; tb += 128) {
                float dls[4]; int pjs[4];
#pragma unroll
                for (int k = 0; k < 4; ++k) {
                    const int t = tb + (k << 5) + lane;
                    dls[k] = INFINITY; pjs[k] = i;              // sentinel: skipped
                    if (t < Mtot) {
                        int p = 0;
#pragma unroll
                        for (int st = 16; st >= 1; st >>= 1)
                            if (epf[p + st] <= t) p += st;
                        const int si = rs[p] + (t - epf[p]);
                        const float4 cq = pts4[si];
                        pjs[k] = pid[si];
                        dls[k] = fmaf(cq.x, pix, fmaf(cq.y, piy, fmaf(cq.z, piz, cq.w)));
                    }
                }
#pragma unroll
                for (int k = 0; k < 4; ++k)
                    if (pjs[k] != i && dls[k] <= tau) do_insert(dls[k], pjs[k]);
            }
        }
    };

    float od[KNN];
    int   oi[KNN];
    auto merge_out = [&]() {
#pragma unroll
        for (int k = 0; k < KNN; ++k) {
            float dw = bd[0];
            int   iw = bi[0];
#pragma unroll
            for (int s = 1; s < 32; s <<= 1) {
                const float dx = __shfl_xor(dw, s, 32);
                const int   ix = __shfl_xor(iw, s, 32);
                if (dx < dw || (dx == dw && ix < iw)) { dw = dx; iw = ix; }
            }
            if (bd[0] == dw && bi[0] == iw) {
#pragma unroll
                for (int q = 0; q < KNN - 1; ++q) { bd[q] = bd[q + 1]; bi[q] = bi[q + 1]; }
                bd[KNN - 1] = INFINITY; bi[KNN - 1] = 0x7fffffff;
            }
            od[k] = dw; oi[k] = iw;
        }
    };

    // ---- 1) two-level SAT radius probe: lane l tests radius l+1 (<=32) ----
    int r;
    {
        const int rl = lane + 1;
        const int bx0 = max(cx - rl, 0), bx1 = min(cx + rl, GRID_R - 1);
        const int by0 = max(cy - rl, 0), by1 = min(cy + rl, GRID_R - 1);
        const int bz0 = max(cz - rl, 0), bz1 = min(cz + rl, GRID_R - 1);
        const int cntl = boxcount(sat, bx0, bx1, by0, by1, bz0, bz1);
        const unsigned long long m9  = __ballot(cntl >= NBR_LO);
        const unsigned long long m26 = __ballot(cntl >= NBR_MIN);
        const unsigned sh  = (unsigned)(tid & 32);
        const unsigned mh9  = (unsigned)(m9  >> sh);
        const unsigned mh26 = (unsigned)(m26 >> sh);
        const int r9  = mh9  ? (int)__ffs(mh9)  : 32;
        const int r26 = mh26 ? (int)__ffs(mh26) : 32;
        const int cnt26 = __shfl(cntl, r26 - 1, 32);   // population of preferred window
        r = (cnt26 <= M_CAP) ? r26 : r9;
    }

    // ---- 2) window scan at r ----
    scan_win(r);

    // ---- 3) fused merge + termination; exact bounded second pass on failure ----
    {
        float mg = INFINITY;
        bool full = true;
        if (cx - r > 0)          { mg = fminf(mg, pix - (GLO + (float)(cx - r) * CELL_E));     full = false; }
        if (cx + r < GRID_R - 1) { mg = fminf(mg, (GLO + (float)(cx + r + 1) * CELL_E) - pix); full = false; }
        if (cy - r > 0)          { mg = fminf(mg, piy - (GLO + (float)(cy - r) * CELL_E));     full = false; }
        if (cy + r < GRID_R - 1) { mg = fminf(mg, (GLO + (float)(cy + r + 1) * CELL_E) - piy); full = false; }
        if (cz - r > 0)          { mg = fminf(mg, piz - (GLO + (float)(cz - r) * CELL_E));     full = false; }
        if (cz + r < GRID_R - 1) { mg = fminf(mg, (GLO + (float)(cz + r + 1) * CELL_E) - piz); full = false; }

        merge_out();                             // common path: the ONLY merge
        bool done = full;
        const float d8 = od[KNN - 1];
        if (!full) {
            const float mge  = mg - 1e-5f;
            const float need = mge * mge - sqi;  // d_real < mge^2  <=>  d' < need
            done = (d8 < need);                  // strict: boundary ties keep scanning
        }

        if (!done) {
            float s2 = sqrtf(fmaxf(d8 + sqi, 0.0f)) + 1e-4f;  // real-distance bound
            s2 = fminf(s2, 9.0f);                              // cap -> full grid
            auto dneed = [&](float frac, int clip) -> int {
                int nd = (int)ceilf((s2 - frac) * CELL_INV);
                nd = max(nd, 0);
                return min(nd, clip);
            };
            const float fxm = pix - (GLO + (float)cx * CELL_E);
            const float fxp = (GLO + (float)(cx + 1) * CELL_E) - pix;
            const float fym = piy - (GLO + (float)cy * CELL_E);
            const float fyp = (GLO + (float)(cy + 1) * CELL_E) - piy;
            const float fzm = piz - (GLO + (float)cz * CELL_E);
            const float fzp = (GLO + (float)(cz + 1) * CELL_E) - piz;
            int r2 = r + 1;
            r2 = max(r2, dneed(fxm, cx));
            r2 = max(r2, dneed(fxp, GRID_R - 1 - cx));
            r2 = max(r2, dneed(fym, cy));
            r2 = max(r2, dneed(fyp, GRID_R - 1 - cy));
            r2 = max(r2, dneed(fzm, cz));
            r2 = max(r2, dneed(fzp, GRID_R - 1 - cz));
            r2 = min(r2, GRID_R);

#pragma unroll
            for (int q = 0; q < KNN; ++q) { bd[q] = INFINITY; bi[q] = 0x7fffffff; }
            tau = d8;
            scan_win(r2);
            merge_out();
        }
    }

    if (lane == 0) {
#pragma unroll
        for (int k = 0; k < KNN; ++k) idx_out[i * 9 + k] = clamp_idx(oi[k]);
        idx_out[i * 9 + 8] = i;
    }
}

__global__ __launch_bounds__(256) void knn_grid_kernel(const void* __restrict__ pos,
                                                       const int* __restrict__ flag,
                                                       const int* __restrict__ cstart,
                                                       const int* __restrict__ sat,
                                                       const float4* __restrict__ pts4,
                                                       const int* __restrict__ pid,
                                                       int* __restrict__ idx_out) {
    __shared__ int rs[8][32];
    __shared__ int epf[8][32];
    const int sg = threadIdx.x >> 5;
    if (get_dt(flag) == DT_BF16)
        knn_body<__hip_bfloat16>((const __hip_bfloat16*)pos, cstart, sat, pts4, pid, idx_out,
                                 rs[sg], epf[sg]);
    else
        knn_body<float>((const float*)pos, cstart, sat, pts4, pid, idx_out, rs[sg], epf[sg]);
}

// ---------------------------------------------------------------------------
// conv1 v10: wB phase k-tiled with NAMED weight registers (r8 post-mortem:
// wcol[32] array was not register-promoted -> hidden scratch traffic).
// ---------------------------------------------------------------------------
struct Conv1Smem {
    alignas(16) float wB[32 * 64];
    alignas(16) float h1s[4][9 * 32];
    alignas(16) float wsum[3 * 32];
    alignas(16) float wbot[3 * 32];
    alignas(16) float posn[4][9][3];
    float bA[32];
    float bB[64];
};

template <typename T>
__device__ void conv1_body(const T* __restrict__ pos, const int* __restrict__ idx,
                           const T* __restrict__ W1a, const T* __restrict__ b1a,
                           const T* __restrict__ W1b, const T* __restrict__ b1b,
                           float* __restrict__ x1, Conv1Smem& s) {
    const int tid = threadIdx.x;
    for (int e = tid; e < 96; e += 256) {
        const float bot = ldf(W1a, 96 + e);
        s.wsum[e] = ldf(W1a, e) + bot;
        s.wbot[e] = bot;
    }
    if (tid < 32) s.bA[tid] = ldf(b1a, tid);
    for (int e = tid; e < 2048; e += 256) s.wB[e] = ldf(W1b, e);
    if (tid < 64) s.bB[tid] = ldf(b1b, tid);

    const int tl   = tid >> 6;
    const int lane = tid & 63;
    const int i    = blockIdx.x * 4 + tl;

    if (lane < 27) {
        const int n = lane / 3, c = lane % 3;
        const int j = clamp_idx(idx[i * 9 + n]);
        s.posn[tl][n][c] = ldf(pos, 3 * j + c);
    }
    const float pi0 = ldf(pos, 3 * i + 0);
    const float pi1 = ldf(pos, 3 * i + 1);
    const float pi2 = ldf(pos, 3 * i + 2);
    __syncthreads();

    for (int e = lane; e < 288; e += 64) {
        const int n = e >> 5, k = e & 31;
        float b = fmaf(pi0, s.wbot[k], fmaf(pi1, s.wbot[32 + k], pi2 * s.wbot[64 + k]));
        float v = s.bA[k] - b;
        v = fmaf(s.posn[tl][n][0], s.wsum[k], v);
        v = fmaf(s.posn[tl][n][1], s.wsum[32 + k], v);
        v = fmaf(s.posn[tl][n][2], s.wsum[64 + k], v);
        s.h1s[tl][n * 32 + k] = fmaxf(v, 0.0f);
    }
    __syncthreads();

    // wB: k-tiles of 8 named weight regs; 9 accumulators (bias hoisted past max)
    float acc[9];
#pragma unroll
    for (int n = 0; n < 9; ++n) acc[n] = 0.0f;
#pragma unroll
    for (int kt = 0; kt < 32; kt += 8) {
        float w0 = s.wB[(kt + 0) * 64 + lane];
        float w1 = s.wB[(kt + 1) * 64 + lane];
        float w2 = s.wB[(kt + 2) * 64 + lane];
        float w3 = s.wB[(kt + 3) * 64 + lane];
        float w4 = s.wB[(kt + 4) * 64 + lane];
        float w5 = s.wB[(kt + 5) * 64 + lane];
        float w6 = s.wB[(kt + 6) * 64 + lane];
        float w7 = s.wB[(kt + 7) * 64 + lane];
#pragma unroll
        for (int n = 0; n < 9; ++n) {
            const float4 ha = *(const float4*)&s.h1s[tl][n * 32 + kt];
            const float4 hb = *(const float4*)&s.h1s[tl][n * 32 + kt + 4];
            float a = acc[n];
            a = fmaf(ha.x, w0, a); a = fmaf(ha.y, w1, a);
            a = fmaf(ha.z, w2, a); a = fmaf(ha.w, w3, a);
            a = fmaf(hb.x, w4, a); a = fmaf(hb.y, w5, a);
            a = fmaf(hb.z, w6, a); a = fmaf(hb.w, w7, a);
            acc[n] = a;
        }
    }
    float m = acc[0];
#pragma unroll
    for (int n = 1; n < 9; ++n) m = fmaxf(m, acc[n]);
    x1[i * 64 + lane] = fmaxf(m + s.bB[lane], 0.0f);
}

__global__ __launch_bounds__(256) void conv1_kernel(const void* __restrict__ pos,
                                                    const int* __restrict__ flag,
                                                    const int* __restrict__ idx,
                                                    const void* __restrict__ W1a,
                                                    const void* __restrict__ b1a,
                                                    const void* __restrict__ W1b,
                                                    const void* __restrict__ b1b,
                                                    float* __restrict__ x1) {
    __shared__ Conv1Smem s;
    if (get_dt(flag) == DT_BF16)
        conv1_body<__hip_bfloat16>((const __hip_bfloat16*)pos, idx,
            (const __hip_bfloat16*)W1a, (const __hip_bfloat16*)b1a,
            (const __hip_bfloat16*)W1b, (const __hip_bfloat16*)b1b, x1, s);
    else
        conv1_body<float>((const float*)pos, idx, (const float*)W1a, (const float*)b1a,
            (const float*)W1b, (const float*)b1b, x1, s);
}

// ---------------------------------------------------------------------------
// zw (unchanged): per-point precompute for conv2's first layer.
// ---------------------------------------------------------------------------
struct ZwSmem {
    alignas(16) float wA[67 * 64];
    alignas(16) float xrT[4][68][4];
    float bA[64];
};

template <typename T>
__device__ void zw_body(const T* __restrict__ pos, const T* __restrict__ W2a,
                        const T* __restrict__ b2a, float* __restrict__ x1, ZwSmem& s) {
    const int tid  = threadIdx.x;
    const int wv   = tid >> 6;
    const int lane = tid & 63;
    const int j0   = blockIdx.x * 16 + wv * 4;

    for (int e = tid; e < 4288; e += 256) s.wA[e] = ldf(W2a, e);
    if (tid < 64) s.bA[tid] = ldf(b2a, tid);

#pragma unroll
    for (int p = 0; p < 4; ++p)
        s.xrT[wv][lane][p] = x1[(j0 + p) * 64 + lane];
    if (lane < 12) {
        const int p = lane / 3, c = lane % 3;
        s.xrT[wv][64 + c][p] = ldf(pos, 3 * (j0 + p) + c);
    }
    __syncthreads();

    float a0 = s.bA[lane], a1 = a0, a2 = a0, a3 = a0;
    for (int c = 0; c < 67; ++c) {
        const float w = s.wA[c * 64 + lane];
        const float4 xv = *(const float4*)&s.xrT[wv][c][0];
        a0 = fmaf(xv.x, w, a0);
        a1 = fmaf(xv.y, w, a1);
        a2 = fmaf(xv.z, w, a2);
        a3 = fmaf(xv.w, w, a3);
    }
    x1[(j0 + 0) * 64 + lane] = a0;
    x1[(j0 + 1) * 64 + lane] = a1;
    x1[(j0 + 2) * 64 + lane] = a2;
    x1[(j0 + 3) * 64 + lane] = a3;
}

__global__ __launch_bounds__(256) void zw_kernel(const void* __restrict__ pos,
                                                 const int* __restrict__ flag,
                                                 const void* __restrict__ W2a,
                                                 const void* __restrict__ b2a,
                                                 float* __restrict__ x1) {
    __shared__ ZwSmem s;
    if (get_dt(flag) == DT_BF16)
        zw_body<__hip_bfloat16>((const __hip_bfloat16*)pos, (const __hip_bfloat16*)W2a,
                                (const __hip_bfloat16*)b2a, x1, s);
    else
        zw_body<float>((const float*)pos, (const float*)W2a, (const float*)b2a, x1, s);
}

// ---------------------------------------------------------------------------
// conv2+head v10: thread = (target tl, channels lane & lane+64). Weight regs
// are NAMED k-tiles loaded straight from global (coalesced, L2-hot) — fixes
// the r8 wcol[64]-not-promoted scratch traffic (VGPR_Count was 60 < 64).
// Sharing h1s reads across the thread's 2 channels halves LDS b128 reads.
// Bias hoisted past max (exact in reals; float noise << tolerance).
// ---------------------------------------------------------------------------
struct Conv2Smem {
    alignas(16) float h1s[4][9 * 64];
    alignas(16) float row[4][128];
    alignas(16) float wbot[3 * 64];
    alignas(16) float wc[640];
    float bcs[5];
    float sv[4][5];
    int   nb[4][9];
};

template <typename T>
__device__ void conv2_body(const T* __restrict__ pos, const int* __restrict__ idx,
                           const float* __restrict__ zw,
                           const T* __restrict__ W2a, const T* __restrict__ W2b,
                           const T* __restrict__ b2b, const T* __restrict__ Wc,
                           const T* __restrict__ bc, T* __restrict__ out, Conv2Smem& s) {
    const int tid  = threadIdx.x;
    const int tl   = tid >> 6;
    const int lane = tid & 63;
    const int i    = blockIdx.x * 4 + tl;

    for (int e = tid; e < 192; e += 256) s.wbot[e] = ldf(W2a, 4096 + e);
    for (int e = tid; e < 640; e += 256) s.wc[e] = ldf(Wc, e);
    if (tid < 5) s.bcs[tid] = ldf(bc, tid);

    if (lane < 9) s.nb[tl][lane] = clamp_idx(idx[i * 9 + lane]);
    const float pi0 = ldf(pos, 3 * i + 0);
    const float pi1 = ldf(pos, 3 * i + 1);
    const float pi2 = ldf(pos, 3 * i + 2);
    __syncthreads();

    // h1 = relu(zw[j] - vi): 9 coalesced row-gathers + subtract
    {
        const float vi = fmaf(pi0, s.wbot[lane], fmaf(pi1, s.wbot[64 + lane], pi2 * s.wbot[128 + lane]));
#pragma unroll
        for (int n = 0; n < 9; ++n) {
            const int j = s.nb[tl][n];
            s.h1s[tl][n * 64 + lane] = fmaxf(zw[j * 64 + lane] - vi, 0.0f);
        }
    }
    __syncthreads();

    // wB: 18 accumulators (9 n x 2 channels), named weight regs per k-tile
    float acc0[9], acc1[9];
#pragma unroll
    for (int n = 0; n < 9; ++n) { acc0[n] = 0.0f; acc1[n] = 0.0f; }
#pragma unroll
    for (int kt = 0; kt < 64; kt += 4) {
        const float wa0 = ldf(W2b, (kt + 0) * 128 + lane);
        const float wa1 = ldf(W2b, (kt + 1) * 128 + lane);
        const float wa2 = ldf(W2b, (kt + 2) * 128 + lane);
        const float wa3 = ldf(W2b, (kt + 3) * 128 + lane);
        const float wb0 = ldf(W2b, (kt + 0) * 128 + lane + 64);
        const float wb1 = ldf(W2b, (kt + 1) * 128 + lane + 64);
        const float wb2 = ldf(W2b, (kt + 2) * 128 + lane + 64);
        const float wb3 = ldf(W2b, (kt + 3) * 128 + lane + 64);
#pragma unroll
        for (int n = 0; n < 9; ++n) {
            const float4 h = *(const float4*)&s.h1s[tl][n * 64 + kt];
            float a0 = acc0[n], a1 = acc1[n];
            a0 = fmaf(h.x, wa0, a0); a0 = fmaf(h.y, wa1, a0);
            a0 = fmaf(h.z, wa2, a0); a0 = fmaf(h.w, wa3, a0);
            a1 = fmaf(h.x, wb0, a1); a1 = fmaf(h.y, wb1, a1);
            a1 = fmaf(h.z, wb2, a1); a1 = fmaf(h.w, wb3, a1);
            acc0[n] = a0; acc1[n] = a1;
        }
    }
    float m0 = acc0[0], m1 = acc1[0];
#pragma unroll
    for (int n = 1; n < 9; ++n) { m0 = fmaxf(m0, acc0[n]); m1 = fmaxf(m1, acc1[n]); }
    s.row[tl][lane]      = fmaxf(m0 + ldf(b2b, lane), 0.0f);
    s.row[tl][lane + 64] = fmaxf(m1 + ldf(b2b, lane + 64), 0.0f);
    __syncthreads();

    // head + log_softmax
    if (tid < 20) {
        const int tgt = tid / 5, o = tid % 5;
        float v = s.bcs[o];
        for (int k = 0; k < 128; ++k) v = fmaf(s.row[tgt][k], s.wc[k * 5 + o], v);
        s.sv[tgt][o] = v;
    }
    __syncthreads();
    if (tid < 20) {
        const int tgt = tid / 5, o = tid % 5;
        float m = s.sv[tgt][0];
#pragma unroll
        for (int q = 1; q < 5; ++q) m = fmaxf(m, s.sv[tgt][q]);
        float sum = 0.0f;
#pragma unroll
        for (int q = 0; q < 5; ++q) sum += expf(s.sv[tgt][q] - m);
        const float lse = m + logf(sum);
        stf(out, (blockIdx.x * 4 + tgt) * 5 + o, s.sv[tgt][o] - lse);
    }
}

__global__ __launch_bounds__(256) void conv2_head_kernel(const void* __restrict__ pos,
                                                         const int* __restrict__ flag,
                                                         const int* __restrict__ idx,
                                                         const float* __restrict__ zw,
                                                         const void* __restrict__ W2a,
                                                         const void* __restrict__ W2b,
                                                         const void* __restrict__ b2b,
                                                         const void* __restrict__ Wc,
                                                         const void* __restrict__ bc,
                                                         void* __restrict__ out) {
    __shared__ Conv2Smem s;
    if (get_dt(flag) == DT_BF16)
        conv2_body<__hip_bfloat16>((const __hip_bfloat16*)pos, idx, zw,
            (const __hip_bfloat16*)W2a, (const __hip_bfloat16*)W2b, (const __hip_bfloat16*)b2b,
            (const __hip_bfloat16*)Wc, (const __hip_bfloat16*)bc, (__hip_bfloat16*)out, s);
    else
        conv2_body<float>((const float*)pos, idx, zw, (const float*)W2a, (const float*)W2b,
            (const float*)b2b, (const float*)Wc, (const float*)bc, (float*)out, s);
}

// ---------------------------------------------------------------------------
extern "C" void kernel_launch(void* const* d_in, const int* in_sizes, int n_in,
                              void* d_out, int out_size, void* d_ws, size_t ws_size,
                              hipStream_t stream) {
    if (ws_size < (size_t)WS_NEEDED) return;

    char* ws = (char*)d_ws;
    int*    flag     = (int*)(ws + WS_FLAG_OFF);
    int*    idx      = (int*)(ws + WS_IDX_OFF);
    float*  x1       = (float*)(ws + WS_X1_OFF);
    int*    sat      = (int*)(ws + WS_SAT_OFF);
    int*    cstart   = (int*)(ws + WS_START_OFF);
    int*    cursor   = (int*)(ws + WS_CURSOR_OFF);
    int*    pid      = (int*)(ws + WS_PID_OFF);
    float4* pts4     = (float4*)(ws + WS_PTS_OFF);
    int*    rowtot   = (int*)(ws + WS_ROWTOT_OFF);
    int*    rowstart = (int*)(ws + WS_ROWSTART_OFF);
    int*    xpre     = (int*)(ws + WS_XPRE_OFF);

    zero_kernel<<<NCELLS / 256, 256, 0, stream>>>(sat, flag);
    sniff_kernel<<<64, 256, 0, stream>>>((const unsigned short*)d_in[0], flag);
    grid_count_kernel<<<N_PTS / 256, 256, 0, stream>>>(d_in[0], flag, sat);
    rowscan_kernel<<<NROWS2D / 256, 256, 0, stream>>>(sat, xpre, rowtot);
    rowoffset_kernel<<<1, 256, 0, stream>>>(rowtot, rowstart);
    cellsaty_kernel<<<NROWS2D / 256, 256, 0, stream>>>(xpre, rowstart, cstart, cursor, sat);
    satzscatter_kernel<<<9 + N_PTS / 256, 256, 0, stream>>>(d_in[0], flag, sat, cursor, pts4, pid);
    knn_grid_kernel<<<N_PTS / 8, 256, 0, stream>>>(d_in[0], flag, cstart, sat, pts4, pid, idx);
    conv1_kernel<<<N_PTS / 4, 256, 0, stream>>>(d_in[0], flag, idx,
        d_in[1], d_in[2], d_in[3], d_in[4], x1);
    zw_kernel<<<N_PTS / 16, 256, 0, stream>>>(d_in[0], flag, d_in[5], d_in[6], x1);
    conv2_head_kernel<<<N_PTS / 4, 256, 0, stream>>>(d_in[0], flag, idx, x1,
        d_in[5], d_in[7], d_in[8], d_in[9], d_in[10], d_out);
}

// Round 10
// 234.646 us; speedup vs baseline: 1.6717x; 1.0031x over previous
//
#include <hip/hip_runtime.h>
#include <hip/hip_bf16.h>
#include <math.h>

#define N_PTS 16384
#define KNN 8

#define DT_BF16 1
#define DT_FP32 2

// Workspace layout:
//   flag : int          @ 0
//   idx  : int  [N*9]   @ 64        -> 589,824 B
//   x1   : f32  [N*64]  @ 589,888   -> 4,194,304 B
// Grid-KNN scratch lives INSIDE the x1 region (dead before conv1 writes x1):
//   sat      : int [110592]  @ x1+0        (counts -> x-prefix -> full 3D SAT)
//   start    : int [110593]  @ x1+442368   (cell starts + sentinel)
//   cursor   : int [110592]  @ x1+884800
//   pid      : int [16384]   @ x1+1327168
//   pts4     : f4  [16384]   @ x1+1392704
//   rowtot   : int [2304]    @ x1+1654848
//   rowstart : int [2304]    @ x1+1664064
//   xpre     : int [110592]  @ x1+1673280  (x-prefix copy; end 2,115,648 <= 4,194,304)
#define WS_FLAG_OFF 0
#define WS_IDX_OFF  64
#define WS_X1_OFF   589888
#define WS_NEEDED   4784192

#define WS_SAT_OFF      (WS_X1_OFF)
#define WS_START_OFF    (WS_X1_OFF + 442368)
#define WS_CURSOR_OFF   (WS_X1_OFF + 884800)
#define WS_PID_OFF      (WS_X1_OFF + 1327168)
#define WS_PTS_OFF      (WS_X1_OFF + 1392704)
#define WS_ROWTOT_OFF   (WS_X1_OFF + 1654848)
#define WS_ROWSTART_OFF (WS_X1_OFF + 1664064)
#define WS_XPRE_OFF     (WS_X1_OFF + 1673280)

#define GRID_R   48
#define NROWS2D  (GRID_R * GRID_R)          // 2304 (y,z) rows
#define NCELLS   (GRID_R * GRID_R * GRID_R) // 110592
#define GLO      -4.5f
#define CELL_E   0.1875f
#define CELL_INV 5.3333335f
#define NBR_MIN  40
#define NBR_LO   9    // minimum population: 8 neighbors + self -> finite d8
#define M_CAP    1024 // if the NBR_MIN window holds more than this, use the LO window

__device__ __forceinline__ float bf2f(__hip_bfloat16 v) { return __bfloat162float(v); }

__device__ __forceinline__ float ldf(const float* p, int i) { return p[i]; }
__device__ __forceinline__ float ldf(const __hip_bfloat16* p, int i) { return bf2f(p[i]); }
__device__ __forceinline__ void stf(float* p, int i, float v) { p[i] = v; }
__device__ __forceinline__ void stf(__hip_bfloat16* p, int i, float v) { p[i] = __float2bfloat16(v); }

__device__ __forceinline__ int clamp_idx(int j) {
    return ((unsigned)j < (unsigned)N_PTS) ? j : 0;
}

__device__ __forceinline__ int cell_of(float v) {
    int c = (int)((v - GLO) * CELL_INV);
    return min(max(c, 0), GRID_R - 1);
}

// flag[0] holds the sniffer's bad-count; >16 => fp32 input.
__device__ __forceinline__ int get_dt(const int* flag) {
    return (flag[0] > 16) ? DT_FP32 : DT_BF16;
}

// ---------------------------------------------------------------------------
// zero: cnt[] and flag.
// ---------------------------------------------------------------------------
__global__ __launch_bounds__(256) void zero_kernel(int* __restrict__ cnt, int* __restrict__ flag) {
    const int e = blockIdx.x * 256 + threadIdx.x;
    cnt[e] = 0;
    if (e == 0) flag[0] = 0;
}

// ---------------------------------------------------------------------------
// sniff (multi-block).
// ---------------------------------------------------------------------------
__global__ __launch_bounds__(256) void sniff_kernel(const unsigned short* __restrict__ posu,
                                                    int* __restrict__ flag) {
    __shared__ int red[256];
    int local = 0;
    for (int e = blockIdx.x * 256 + threadIdx.x; e < 3 * N_PTS; e += 64 * 256) {
        const float v = __uint_as_float(((unsigned)posu[e]) << 16);
        if (!(fabsf(v) <= 64.0f)) local++;
    }
    red[threadIdx.x] = local;
    __syncthreads();
    for (int s = 128; s > 0; s >>= 1) {
        if (threadIdx.x < s) red[threadIdx.x] += red[threadIdx.x + s];
        __syncthreads();
    }
    if (threadIdx.x == 0 && red[0] > 0) atomicAdd(flag, red[0]);
}

// ---------------------------------------------------------------------------
// Grid build (parallel): count -> rowscan(+xpre) -> rowoffset ->
// {cellstart+saty fused} -> {satz+scatter fused}.
// ---------------------------------------------------------------------------
template <typename T>
__device__ __forceinline__ void count_body(const T* __restrict__ pos, int* __restrict__ cnt) {
    const int i = blockIdx.x * 256 + threadIdx.x;
    const float x = ldf(pos, 3 * i + 0);
    const float y = ldf(pos, 3 * i + 1);
    const float z = ldf(pos, 3 * i + 2);
    const int c = (cell_of(z) * GRID_R + cell_of(y)) * GRID_R + cell_of(x);
    atomicAdd(&cnt[c], 1);
}

__global__ __launch_bounds__(256) void grid_count_kernel(const void* __restrict__ pos,
                                                         const int* __restrict__ flag,
                                                         int* __restrict__ cnt) {
    if (get_dt(flag) == DT_BF16) count_body<__hip_bfloat16>((const __hip_bfloat16*)pos, cnt);
    else                         count_body<float>((const float*)pos, cnt);
}

// x-prefix per row (in place over sat, plus copy to xpre), rowtot = row sum.
__global__ __launch_bounds__(256) void rowscan_kernel(int* __restrict__ sat,
                                                      int* __restrict__ xpre,
                                                      int* __restrict__ rowtot) {
    const int t = blockIdx.x * 256 + threadIdx.x;   // row < 2304
    const int rb = t * GRID_R;
    int acc = 0;
    for (int x = 0; x < GRID_R; ++x) {
        acc += sat[rb + x];
        sat[rb + x]  = acc;
        xpre[rb + x] = acc;
    }
    rowtot[t] = acc;
}

// exclusive scan of 2304 row totals (one block, 256 threads x 9 rows).
__global__ __launch_bounds__(256) void rowoffset_kernel(const int* __restrict__ rowtot,
                                                        int* __restrict__ rowstart) {
    __shared__ int part[256];
    const int t = threadIdx.x;
    int loc[9]; int s = 0;
#pragma unroll
    for (int k = 0; k < 9; ++k) { loc[k] = rowtot[t * 9 + k]; s += loc[k]; }
    part[t] = s;
    __syncthreads();
    for (int off = 1; off < 256; off <<= 1) {
        int v = (t >= off) ? part[t - off] : 0;
        __syncthreads();
        part[t] += v;
        __syncthreads();
    }
    int run = (t == 0) ? 0 : part[t - 1];
#pragma unroll
    for (int k = 0; k < 9; ++k) { rowstart[t * 9 + k] = run; run += loc[k]; }
}

// FUSED: cellstart (from xpre copy -> no dependence on sat) + SAT y-pass.
__global__ __launch_bounds__(256) void cellsaty_kernel(const int* __restrict__ xpre,
                                                       const int* __restrict__ rowstart,
                                                       int* __restrict__ cstart,
                                                       int* __restrict__ cursor,
                                                       int* __restrict__ sat) {
    const int t = blockIdx.x * 256 + threadIdx.x;   // < 2304
    const int rb = t * GRID_R;
    const int base = rowstart[t];
    int prev = 0;
    for (int x = 0; x < GRID_R; ++x) {
        const int v = base + prev;
        cstart[rb + x] = v;
        cursor[rb + x] = v;
        prev = xpre[rb + x];
    }
    if (t == NROWS2D - 1) cstart[NCELLS] = base + prev;
    const int z = t / GRID_R, x = t - z * GRID_R;
    const int b2 = z * NROWS2D + x;
    int run = 0;
#pragma unroll
    for (int y = 0; y < GRID_R; ++y) {
        run += sat[b2 + y * GRID_R];
        sat[b2 + y * GRID_R] = run;
    }
}

// FUSED: SAT z-pass (blocks 0..8) + scatter (blocks 9..72).
template <typename T>
__device__ __forceinline__ void scatter_body(const T* __restrict__ pos, int i,
                                             int* __restrict__ cursor,
                                             float4* __restrict__ pts4, int* __restrict__ pid) {
    const float x = ldf(pos, 3 * i + 0);
    const float y = ldf(pos, 3 * i + 1);
    const float z = ldf(pos, 3 * i + 2);
    const int c = (cell_of(z) * GRID_R + cell_of(y)) * GRID_R + cell_of(x);
    const int slot = atomicAdd(&cursor[c], 1);
    const float sq = fmaf(x, x, fmaf(y, y, z * z));
    pts4[slot] = make_float4(-2.0f * x, -2.0f * y, -2.0f * z, sq);
    pid[slot] = i;
}

__global__ __launch_bounds__(256) void satzscatter_kernel(const void* __restrict__ pos,
                                                          const int* __restrict__ flag,
                                                          int* __restrict__ sat,
                                                          int* __restrict__ cursor,
                                                          float4* __restrict__ pts4,
                                                          int* __restrict__ pid) {
    if (blockIdx.x < 9) {
        const int t = blockIdx.x * 256 + threadIdx.x;   // < 2304
        int run = 0;
#pragma unroll
        for (int z = 0; z < GRID_R; ++z) {
            run += sat[t + z * NROWS2D];
            sat[t + z * NROWS2D] = run;
        }
    } else {
        const int i = (blockIdx.x - 9) * 256 + threadIdx.x;
        if (get_dt(flag) == DT_BF16) scatter_body<__hip_bfloat16>((const __hip_bfloat16*)pos, i, cursor, pts4, pid);
        else                         scatter_body<float>((const float*)pos, i, cursor, pts4, pid);
    }
}

// ---------------------------------------------------------------------------
// KNN v11 = v10 + CHORD-CLIPPED second pass (tail fix).
// r9 post-mortem: NBR_MIN change was a no-op -> typical targets don't set
// knn's time; the tail does (Occ 26% with all waves co-resident). Tail =
// outlier waves whose pass-2 BOX (side ~2*s2) swallows thousands of core
// points while the s2-BALL holds only tens. v11: per (y,z) row, skip the row
// if min-dist(row) >= s2, else restrict the x-run to the chord
// pix +- sqrt(s2^2 - dy^2 - dz^2). Exact: row/chord distances lower-bound
// any contained point's distance (incl. clamped edge-cell points), so only
// cells provably void of d_real <= d8_real points are excluded; conservative
// eps on every boundary. Pass 1 unchanged (clip = INF).
// ---------------------------------------------------------------------------
__device__ __forceinline__ int sat_at(const int* __restrict__ sat, int x, int y, int z) {
    if (x < 0 || y < 0 || z < 0) return 0;
    return sat[(z * GRID_R + y) * GRID_R + x];
}

__device__ __forceinline__ int boxcount(const int* __restrict__ sat,
                                        int x0, int x1, int y0, int y1, int z0, int z1) {
    return sat_at(sat, x1, y1, z1) - sat_at(sat, x0 - 1, y1, z1)
         - sat_at(sat, x1, y0 - 1, z1) - sat_at(sat, x1, y1, z0 - 1)
         + sat_at(sat, x0 - 1, y0 - 1, z1) + sat_at(sat, x0 - 1, y1, z0 - 1)
         + sat_at(sat, x1, y0 - 1, z0 - 1) - sat_at(sat, x0 - 1, y0 - 1, z0 - 1);
}

template <typename T>
__device__ void knn_body(const T* __restrict__ pos,
                         const int* __restrict__ cstart, const int* __restrict__ sat,
                         const float4* __restrict__ pts4, const int* __restrict__ pid,
                         int* __restrict__ idx_out,
                         int* __restrict__ rs, int* __restrict__ epf) {
    const int tid  = threadIdx.x;
    const int lane = tid & 31;                 // lane within 32-lane subgroup
    const int i    = blockIdx.x * 8 + (tid >> 5);

    const float pix = ldf(pos, 3 * i + 0);
    const float piy = ldf(pos, 3 * i + 1);
    const float piz = ldf(pos, 3 * i + 2);
    const float sqi = fmaf(pix, pix, fmaf(piy, piy, piz * piz));
    const int cx = cell_of(pix), cy = cell_of(piy), cz = cell_of(piz);

    float bd[KNN];
    int   bi[KNN];
#pragma unroll
    for (int q = 0; q < KNN; ++q) { bd[q] = INFINITY; bi[q] = 0x7fffffff; }
    float tau = INFINITY;

    auto do_insert = [&](float d, int pj) {
        float cd = d; int ci = pj;
#pragma unroll
        for (int q = 0; q < KNN; ++q) {
            const bool ins = (cd < bd[q]) || (cd == bd[q] && ci < bi[q]);
            const float nd = ins ? cd : bd[q];
            const int   ni = ins ? ci : bi[q];
            const float od = ins ? bd[q] : cd;
            const int   oi = ins ? bi[q] : ci;
            bd[q] = nd; bi[q] = ni; cd = od; ci = oi;
        }
        tau = fminf(tau, bd[KNN - 1]);
    };

    // window scan; clipR < INF restricts each row's x-run to the s2-chord.
    auto scan_win = [&](int rr, float clipR) {
        const int x0 = max(cx - rr, 0), x1 = min(cx + rr, GRID_R - 1);
        const int y0 = max(cy - rr, 0), y1 = min(cy + rr, GRID_R - 1);
        const int z0 = max(cz - rr, 0), z1 = min(cz + rr, GRID_R - 1);
        const int ny = y1 - y0 + 1;
        const int R  = ny * (z1 - z0 + 1);
        const float clip2 = clipR * clipR;
        for (int cb = 0; cb < R; cb += 32) {
            const int lr = cb + lane;
            int cnt_r = 0, st_r = 0;
            if (lr < R) {
                const int iz = lr / ny;
                const int iy = lr - iz * ny;
                const int ycell = y0 + iy, zcell = z0 + iz;
                int cxa = x0, cxb = x1;
                if (clipR < 1e30f) {
                    const float ylo = GLO + (float)ycell * CELL_E;
                    const float zlo = GLO + (float)zcell * CELL_E;
                    const float dy = fmaxf(0.0f, fmaxf(ylo - piy, piy - (ylo + CELL_E)));
                    const float dz = fmaxf(0.0f, fmaxf(zlo - piz, piz - (zlo + CELL_E)));
                    const float rad2 = clip2 - dy * dy - dz * dz;
                    if (rad2 <= 0.0f) { cxa = 1; cxb = 0; }
                    else {
                        const float hr = sqrtf(rad2) + 1e-4f;
                        cxa = max(x0, (int)floorf((pix - hr - GLO) * CELL_INV));
                        cxb = min(x1, (int)floorf((pix + hr - GLO) * CELL_INV));
                    }
                }
                if (cxa <= cxb) {
                    const int c0 = (zcell * GRID_R + ycell) * GRID_R + cxa;
                    st_r  = cstart[c0];
                    cnt_r = cstart[c0 + (cxb - cxa) + 1] - st_r;
                }
            }
            int pv = cnt_r;
#pragma unroll
            for (int s = 1; s < 32; s <<= 1) {
                const int u = __shfl_up(pv, s, 32);
                if (lane >= s) pv += u;
            }
            const int Mtot = __shfl(pv, 31, 32);
            asm volatile("s_waitcnt lgkmcnt(0)" ::: "memory");  // prev chunk reads done
            rs[lane]  = st_r;
            epf[lane] = (lr < R) ? (pv - cnt_r) : 0x7fffffff;   // exclusive prefix / +inf
            asm volatile("s_waitcnt lgkmcnt(0)" ::: "memory");  // staging visible
            for (int tb = 0; tb < Mtot; tb += 128) {
                float dls[4]; int pjs[4];
#pragma unroll
                for (int k = 0; k < 4; ++k) {
                    const int t = tb + (k << 5) + lane;
                    dls[k] = INFINITY; pjs[k] = i;              // sentinel: skipped
                    if (t < Mtot) {
                        int p = 0;
#pragma unroll
                        for (int st = 16; st >= 1; st >>= 1)
                            if (epf[p + st] <= t) p += st;
                        const int si = rs[p] + (t - epf[p]);
                        const float4 cq = pts4[si];
                        pjs[k] = pid[si];
                        dls[k] = fmaf(cq.x, pix, fmaf(cq.y, piy, fmaf(cq.z, piz, cq.w)));
                    }
                }
#pragma unroll
                for (int k = 0; k < 4; ++k)
                    if (pjs[k] != i && dls[k] <= tau) do_insert(dls[k], pjs[k]);
            }
        }
    };

    float od[KNN];
    int   oi[KNN];
    auto merge_out = [&]() {
#pragma unroll
        for (int k = 0; k < KNN; ++k) {
            float dw = bd[0];
            int   iw = bi[0];
#pragma unroll
            for (int s = 1; s < 32; s <<= 1) {
                const float dx = __shfl_xor(dw, s, 32);
                const int   ix = __shfl_xor(iw, s, 32);
                if (dx < dw || (dx == dw && ix < iw)) { dw = dx; iw = ix; }
            }
            if (bd[0] == dw && bi[0] == iw) {
#pragma unroll
                for (int q = 0; q < KNN - 1; ++q) { bd[q] = bd[q + 1]; bi[q] = bi[q + 1]; }
                bd[KNN - 1] = INFINITY; bi[KNN - 1] = 0x7fffffff;
            }
            od[k] = dw; oi[k] = iw;
        }
    };

    // ---- 1) two-level SAT radius probe: lane l tests radius l+1 (<=32) ----
    int r;
    {
        const int rl = lane + 1;
        const int bx0 = max(cx - rl, 0), bx1 = min(cx + rl, GRID_R - 1);
        const int by0 = max(cy - rl, 0), by1 = min(cy + rl, GRID_R - 1);
        const int bz0 = max(cz - rl, 0), bz1 = min(cz + rl, GRID_R - 1);
        const int cntl = boxcount(sat, bx0, bx1, by0, by1, bz0, bz1);
        const unsigned long long m9  = __ballot(cntl >= NBR_LO);
        const unsigned long long m26 = __ballot(cntl >= NBR_MIN);
        const unsigned sh  = (unsigned)(tid & 32);
        const unsigned mh9  = (unsigned)(m9  >> sh);
        const unsigned mh26 = (unsigned)(m26 >> sh);
        const int r9  = mh9  ? (int)__ffs(mh9)  : 32;
        const int r26 = mh26 ? (int)__ffs(mh26) : 32;
        const int cnt26 = __shfl(cntl, r26 - 1, 32);   // population of preferred window
        r = (cnt26 <= M_CAP) ? r26 : r9;
    }

    // ---- 2) window scan at r (no clip: tau unknown) ----
    scan_win(r, INFINITY);

    // ---- 3) fused merge + termination; chord-clipped second pass on failure ----
    {
        float mg = INFINITY;
        bool full = true;
        if (cx - r > 0)          { mg = fminf(mg, pix - (GLO + (float)(cx - r) * CELL_E));     full = false; }
        if (cx + r < GRID_R - 1) { mg = fminf(mg, (GLO + (float)(cx + r + 1) * CELL_E) - pix); full = false; }
        if (cy - r > 0)          { mg = fminf(mg, piy - (GLO + (float)(cy - r) * CELL_E));     full = false; }
        if (cy + r < GRID_R - 1) { mg = fminf(mg, (GLO + (float)(cy + r + 1) * CELL_E) - piy); full = false; }
        if (cz - r > 0)          { mg = fminf(mg, piz - (GLO + (float)(cz - r) * CELL_E));     full = false; }
        if (cz + r < GRID_R - 1) { mg = fminf(mg, (GLO + (float)(cz + r + 1) * CELL_E) - piz); full = false; }

        merge_out();                             // common path: the ONLY merge
        bool done = full;
        const float d8 = od[KNN - 1];
        if (!full) {
            const float mge  = mg - 1e-5f;
            const float need = mge * mge - sqi;  // d_real < mge^2  <=>  d' < need
            done = (d8 < need);                  // strict: boundary ties keep scanning
        }

        if (!done) {
            // s2 = conservative real-distance bound on the true 8th neighbor
            const float s2 = sqrtf(fmaxf(d8 + sqi, 0.0f)) + 1e-4f;
            auto dneed = [&](float frac, int clip) -> int {
                int nd = (int)ceilf((s2 - frac) * CELL_INV);
                nd = max(nd, 0);
                return min(nd, clip);
            };
            const float fxm = pix - (GLO + (float)cx * CELL_E);
            const float fxp = (GLO + (float)(cx + 1) * CELL_E) - pix;
            const float fym = piy - (GLO + (float)cy * CELL_E);
            const float fyp = (GLO + (float)(cy + 1) * CELL_E) - piy;
            const float fzm = piz - (GLO + (float)cz * CELL_E);
            const float fzp = (GLO + (float)(cz + 1) * CELL_E) - piz;
            int r2 = r + 1;
            r2 = max(r2, dneed(fxm, cx));
            r2 = max(r2, dneed(fxp, GRID_R - 1 - cx));
            r2 = max(r2, dneed(fym, cy));
            r2 = max(r2, dneed(fyp, GRID_R - 1 - cy));
            r2 = max(r2, dneed(fzm, cz));
            r2 = max(r2, dneed(fzp, GRID_R - 1 - cz));
            r2 = min(r2, GRID_R);

            // fresh lists; tau seeded with pass-1 d8 (chord window is a
            // superset of all points with d_real <= d8_real => exact)
#pragma unroll
            for (int q = 0; q < KNN; ++q) { bd[q] = INFINITY; bi[q] = 0x7fffffff; }
            tau = d8;
            scan_win(r2, s2);
            merge_out();
        }
    }

    if (lane == 0) {
#pragma unroll
        for (int k = 0; k < KNN; ++k) idx_out[i * 9 + k] = clamp_idx(oi[k]);
        idx_out[i * 9 + 8] = i;
    }
}

__global__ __launch_bounds__(256) void knn_grid_kernel(const void* __restrict__ pos,
                                                       const int* __restrict__ flag,
                                                       const int* __restrict__ cstart,
                                                       const int* __restrict__ sat,
                                                       const float4* __restrict__ pts4,
                                                       const int* __restrict__ pid,
                                                       int* __restrict__ idx_out) {
    __shared__ int rs[8][32];
    __shared__ int epf[8][32];
    const int sg = threadIdx.x >> 5;
    if (get_dt(flag) == DT_BF16)
        knn_body<__hip_bfloat16>((const __hip_bfloat16*)pos, cstart, sat, pts4, pid, idx_out,
                                 rs[sg], epf[sg]);
    else
        knn_body<float>((const float*)pos, cstart, sat, pts4, pid, idx_out, rs[sg], epf[sg]);
}

// ---------------------------------------------------------------------------
// conv1 (unchanged from r9): factored first layer; named-reg k-tiled wB.
// ---------------------------------------------------------------------------
struct Conv1Smem {
    alignas(16) float wB[32 * 64];
    alignas(16) float h1s[4][9 * 32];
    alignas(16) float wsum[3 * 32];
    alignas(16) float wbot[3 * 32];
    alignas(16) float posn[4][9][3];
    float bA[32];
    float bB[64];
};

template <typename T>
__device__ void conv1_body(const T* __restrict__ pos, const int* __restrict__ idx,
                           const T* __restrict__ W1a, const T* __restrict__ b1a,
                           const T* __restrict__ W1b, const T* __restrict__ b1b,
                           float* __restrict__ x1, Conv1Smem& s) {
    const int tid = threadIdx.x;
    for (int e = tid; e < 96; e += 256) {
        const float bot = ldf(W1a, 96 + e);
        s.wsum[e] = ldf(W1a, e) + bot;
        s.wbot[e] = bot;
    }
    if (tid < 32) s.bA[tid] = ldf(b1a, tid);
    for (int e = tid; e < 2048; e += 256) s.wB[e] = ldf(W1b, e);
    if (tid < 64) s.bB[tid] = ldf(b1b, tid);

    const int tl   = tid >> 6;
    const int lane = tid & 63;
    const int i    = blockIdx.x * 4 + tl;

    if (lane < 27) {
        const int n = lane / 3, c = lane % 3;
        const int j = clamp_idx(idx[i * 9 + n]);
        s.posn[tl][n][c] = ldf(pos, 3 * j + c);
    }
    const float pi0 = ldf(pos, 3 * i + 0);
    const float pi1 = ldf(pos, 3 * i + 1);
    const float pi2 = ldf(pos, 3 * i + 2);
    __syncthreads();

    for (int e = lane; e < 288; e += 64) {
        const int n = e >> 5, k = e & 31;
        float b = fmaf(pi0, s.wbot[k], fmaf(pi1, s.wbot[32 + k], pi2 * s.wbot[64 + k]));
        float v = s.bA[k] - b;
        v = fmaf(s.posn[tl][n][0], s.wsum[k], v);
        v = fmaf(s.posn[tl][n][1], s.wsum[32 + k], v);
        v = fmaf(s.posn[tl][n][2], s.wsum[64 + k], v);
        s.h1s[tl][n * 32 + k] = fmaxf(v, 0.0f);
    }
    __syncthreads();

    float acc[9];
#pragma unroll
    for (int n = 0; n < 9; ++n) acc[n] = 0.0f;
#pragma unroll
    for (int kt = 0; kt < 32; kt += 8) {
        float w0 = s.wB[(kt + 0) * 64 + lane];
        float w1 = s.wB[(kt + 1) * 64 + lane];
        float w2 = s.wB[(kt + 2) * 64 + lane];
        float w3 = s.wB[(kt + 3) * 64 + lane];
        float w4 = s.wB[(kt + 4) * 64 + lane];
        float w5 = s.wB[(kt + 5) * 64 + lane];
        float w6 = s.wB[(kt + 6) * 64 + lane];
        float w7 = s.wB[(kt + 7) * 64 + lane];
#pragma unroll
        for (int n = 0; n < 9; ++n) {
            const float4 ha = *(const float4*)&s.h1s[tl][n * 32 + kt];
            const float4 hb = *(const float4*)&s.h1s[tl][n * 32 + kt + 4];
            float a = acc[n];
            a = fmaf(ha.x, w0, a); a = fmaf(ha.y, w1, a);
            a = fmaf(ha.z, w2, a); a = fmaf(ha.w, w3, a);
            a = fmaf(hb.x, w4, a); a = fmaf(hb.y, w5, a);
            a = fmaf(hb.z, w6, a); a = fmaf(hb.w, w7, a);
            acc[n] = a;
        }
    }
    float m = acc[0];
#pragma unroll
    for (int n = 1; n < 9; ++n) m = fmaxf(m, acc[n]);
    x1[i * 64 + lane] = fmaxf(m + s.bB[lane], 0.0f);
}

__global__ __launch_bounds__(256) void conv1_kernel(const void* __restrict__ pos,
                                                    const int* __restrict__ flag,
                                                    const int* __restrict__ idx,
                                                    const void* __restrict__ W1a,
                                                    const void* __restrict__ b1a,
                                                    const void* __restrict__ W1b,
                                                    const void* __restrict__ b1b,
                                                    float* __restrict__ x1) {
    __shared__ Conv1Smem s;
    if (get_dt(flag) == DT_BF16)
        conv1_body<__hip_bfloat16>((const __hip_bfloat16*)pos, idx,
            (const __hip_bfloat16*)W1a, (const __hip_bfloat16*)b1a,
            (const __hip_bfloat16*)W1b, (const __hip_bfloat16*)b1b, x1, s);
    else
        conv1_body<float>((const float*)pos, idx, (const float*)W1a, (const float*)b1a,
            (const float*)W1b, (const float*)b1b, x1, s);
}

// ---------------------------------------------------------------------------
// zw (unchanged): per-point precompute for conv2's first layer.
// ---------------------------------------------------------------------------
struct ZwSmem {
    alignas(16) float wA[67 * 64];
    alignas(16) float xrT[4][68][4];
    float bA[64];
};

template <typename T>
__device__ void zw_body(const T* __restrict__ pos, const T* __restrict__ W2a,
                        const T* __restrict__ b2a, float* __restrict__ x1, ZwSmem& s) {
    const int tid  = threadIdx.x;
    const int wv   = tid >> 6;
    const int lane = tid & 63;
    const int j0   = blockIdx.x * 16 + wv * 4;

    for (int e = tid; e < 4288; e += 256) s.wA[e] = ldf(W2a, e);
    if (tid < 64) s.bA[tid] = ldf(b2a, tid);

#pragma unroll
    for (int p = 0; p < 4; ++p)
        s.xrT[wv][lane][p] = x1[(j0 + p) * 64 + lane];
    if (lane < 12) {
        const int p = lane / 3, c = lane % 3;
        s.xrT[wv][64 + c][p] = ldf(pos, 3 * (j0 + p) + c);
    }
    __syncthreads();

    float a0 = s.bA[lane], a1 = a0, a2 = a0, a3 = a0;
    for (int c = 0; c < 67; ++c) {
        const float w = s.wA[c * 64 + lane];
        const float4 xv = *(const float4*)&s.xrT[wv][c][0];
        a0 = fmaf(xv.x, w, a0);
        a1 = fmaf(xv.y, w, a1);
        a2 = fmaf(xv.z, w, a2);
        a3 = fmaf(xv.w, w, a3);
    }
    x1[(j0 + 0) * 64 + lane] = a0;
    x1[(j0 + 1) * 64 + lane] = a1;
    x1[(j0 + 2) * 64 + lane] = a2;
    x1[(j0 + 3) * 64 + lane] = a3;
}

__global__ __launch_bounds__(256) void zw_kernel(const void* __restrict__ pos,
                                                 const int* __restrict__ flag,
                                                 const void* __restrict__ W2a,
                                                 const void* __restrict__ b2a,
                                                 float* __restrict__ x1) {
    __shared__ ZwSmem s;
    if (get_dt(flag) == DT_BF16)
        zw_body<__hip_bfloat16>((const __hip_bfloat16*)pos, (const __hip_bfloat16*)W2a,
                                (const __hip_bfloat16*)b2a, x1, s);
    else
        zw_body<float>((const float*)pos, (const float*)W2a, (const float*)b2a, x1, s);
}

// ---------------------------------------------------------------------------
// conv2+head (unchanged from r9): named-reg k-tiles, 2 channels/thread.
// ---------------------------------------------------------------------------
struct Conv2Smem {
    alignas(16) float h1s[4][9 * 64];
    alignas(16) float row[4][128];
    alignas(16) float wbot[3 * 64];
    alignas(16) float wc[640];
    float bcs[5];
    float sv[4][5];
    int   nb[4][9];
};

template <typename T>
__device__ void conv2_body(const T* __restrict__ pos, const int* __restrict__ idx,
                           const float* __restrict__ zw,
                           const T* __restrict__ W2a, const T* __restrict__ W2b,
                           const T* __restrict__ b2b, const T* __restrict__ Wc,
                           const T* __restrict__ bc, T* __restrict__ out, Conv2Smem& s) {
    const int tid  = threadIdx.x;
    const int tl   = tid >> 6;
    const int lane = tid & 63;
    const int i    = blockIdx.x * 4 + tl;

    for (int e = tid; e < 192; e += 256) s.wbot[e] = ldf(W2a, 4096 + e);
    for (int e = tid; e < 640; e += 256) s.wc[e] = ldf(Wc, e);
    if (tid < 5) s.bcs[tid] = ldf(bc, tid);

    if (lane < 9) s.nb[tl][lane] = clamp_idx(idx[i * 9 + lane]);
    const float pi0 = ldf(pos, 3 * i + 0);
    const float pi1 = ldf(pos, 3 * i + 1);
    const float pi2 = ldf(pos, 3 * i + 2);
    __syncthreads();

    {
        const float vi = fmaf(pi0, s.wbot[lane], fmaf(pi1, s.wbot[64 + lane], pi2 * s.wbot[128 + lane]));
#pragma unroll
        for (int n = 0; n < 9; ++n) {
            const int j = s.nb[tl][n];
            s.h1s[tl][n * 64 + lane] = fmaxf(zw[j * 64 + lane] - vi, 0.0f);
        }
    }
    __syncthreads();

    float acc0[9], acc1[9];
#pragma unroll
    for (int n = 0; n < 9; ++n) { acc0[n] = 0.0f; acc1[n] = 0.0f; }
#pragma unroll
    for (int kt = 0; kt < 64; kt += 4) {
        const float wa0 = ldf(W2b, (kt + 0) * 128 + lane);
        const float wa1 = ldf(W2b, (kt + 1) * 128 + lane);
        const float wa2 = ldf(W2b, (kt + 2) * 128 + lane);
        const float wa3 = ldf(W2b, (kt + 3) * 128 + lane);
        const float wb0 = ldf(W2b, (kt + 0) * 128 + lane + 64);
        const float wb1 = ldf(W2b, (kt + 1) * 128 + lane + 64);
        const float wb2 = ldf(W2b, (kt + 2) * 128 + lane + 64);
        const float wb3 = ldf(W2b, (kt + 3) * 128 + lane + 64);
#pragma unroll
        for (int n = 0; n < 9; ++n) {
            const float4 h = *(const float4*)&s.h1s[tl][n * 64 + kt];
            float a0 = acc0[n], a1 = acc1[n];
            a0 = fmaf(h.x, wa0, a0); a0 = fmaf(h.y, wa1, a0);
            a0 = fmaf(h.z, wa2, a0); a0 = fmaf(h.w, wa3, a0);
            a1 = fmaf(h.x, wb0, a1); a1 = fmaf(h.y, wb1, a1);
            a1 = fmaf(h.z, wb2, a1); a1 = fmaf(h.w, wb3, a1);
            acc0[n] = a0; acc1[n] = a1;
        }
    }
    float m0 = acc0[0], m1 = acc1[0];
#pragma unroll
    for (int n = 1; n < 9; ++n) { m0 = fmaxf(m0, acc0[n]); m1 = fmaxf(m1, acc1[n]); }
    s.row[tl][lane]      = fmaxf(m0 + ldf(b2b, lane), 0.0f);
    s.row[tl][lane + 64] = fmaxf(m1 + ldf(b2b, lane + 64), 0.0f);
    __syncthreads();

    if (tid < 20) {
        const int tgt = tid / 5, o = tid % 5;
        float v = s.bcs[o];
        for (int k = 0; k < 128; ++k) v = fmaf(s.row[tgt][k], s.wc[k * 5 + o], v);
        s.sv[tgt][o] = v;
    }
    __syncthreads();
    if (tid < 20) {
        const int tgt = tid / 5, o = tid % 5;
        float m = s.sv[tgt][0];
#pragma unroll
        for (int q = 1; q < 5; ++q) m = fmaxf(m, s.sv[tgt][q]);
        float sum = 0.0f;
#pragma unroll
        for (int q = 0; q < 5; ++q) sum += expf(s.sv[tgt][q] - m);
        const float lse = m + logf(sum);
        stf(out, (blockIdx.x * 4 + tgt) * 5 + o, s.sv[tgt][o] - lse);
    }
}

__global__ __launch_bounds__(256) void conv2_head_kernel(const void* __restrict__ pos,
                                                         const int* __restrict__ flag,
                                                         const int* __restrict__ idx,
                                                         const float* __restrict__ zw,
                                                         const void* __restrict__ W2a,
                                                         const void* __restrict__ W2b,
                                                         const void* __restrict__ b2b,
                                                         const void* __restrict__ Wc,
                                                         const void* __restrict__ bc,
                                                         void* __restrict__ out) {
    __shared__ Conv2Smem s;
    if (get_dt(flag) == DT_BF16)
        conv2_body<__hip_bfloat16>((const __hip_bfloat16*)pos, idx, zw,
            (const __hip_bfloat16*)W2a, (const __hip_bfloat16*)W2b, (const __hip_bfloat16*)b2b,
            (const __hip_bfloat16*)Wc, (const __hip_bfloat16*)bc, (__hip_bfloat16*)out, s);
    else
        conv2_body<float>((const float*)pos, idx, zw, (const float*)W2a, (const float*)W2b,
            (const float*)b2b, (const float*)Wc, (const float*)bc, (float*)out, s);
}

// ---------------------------------------------------------------------------
extern "C" void kernel_launch(void* const* d_in, const int* in_sizes, int n_in,
                              void* d_out, int out_size, void* d_ws, size_t ws_size,
                              hipStream_t stream) {
    if (ws_size < (size_t)WS_NEEDED) return;

    char* ws = (char*)d_ws;
    int*    flag     = (int*)(ws + WS_FLAG_OFF);
    int*    idx      = (int*)(ws + WS_IDX_OFF);
    float*  x1       = (float*)(ws + WS_X1_OFF);
    int*    sat      = (int*)(ws + WS_SAT_OFF);
    int*    cstart   = (int*)(ws + WS_START_OFF);
    int*    cursor   = (int*)(ws + WS_CURSOR_OFF);
    int*    pid      = (int*)(ws + WS_PID_OFF);
    float4* pts4     = (float4*)(ws + WS_PTS_OFF);
    int*    rowtot   = (int*)(ws + WS_ROWTOT_OFF);
    int*    rowstart = (int*)(ws + WS_ROWSTART_OFF);
    int*    xpre     = (int*)(ws + WS_XPRE_OFF);

    zero_kernel<<<NCELLS / 256, 256, 0, stream>>>(sat, flag);
    sniff_kernel<<<64, 256, 0, stream>>>((const unsigned short*)d_in[0], flag);
    grid_count_kernel<<<N_PTS / 256, 256, 0, stream>>>(d_in[0], flag, sat);
    rowscan_kernel<<<NROWS2D / 256, 256, 0, stream>>>(sat, xpre, rowtot);
    rowoffset_kernel<<<1, 256, 0, stream>>>(rowtot, rowstart);
    cellsaty_kernel<<<NROWS2D / 256, 256, 0, stream>>>(xpre, rowstart, cstart, cursor, sat);
    satzscatter_kernel<<<9 + N_PTS / 256, 256, 0, stream>>>(d_in[0], flag, sat, cursor, pts4, pid);
    knn_grid_kernel<<<N_PTS / 8, 256, 0, stream>>>(d_in[0], flag, cstart, sat, pts4, pid, idx);
    conv1_kernel<<<N_PTS / 4, 256, 0, stream>>>(d_in[0], flag, idx,
        d_in[1], d_in[2], d_in[3], d_in[4], x1);
    zw_kernel<<<N_PTS / 16, 256, 0, stream>>>(d_in[0], flag, d_in[5], d_in[6], x1);
    conv2_head_kernel<<<N_PTS / 4, 256, 0, stream>>>(d_in[0], flag, idx, x1,
        d_in[5], d_in[7], d_in[8], d_in[9], d_in[10], d_out);
}

// Round 11
// 232.999 us; speedup vs baseline: 1.6835x; 1.0071x over previous
//
#include <hip/hip_runtime.h>
#include <hip/hip_bf16.h>
#include <math.h>

#define N_PTS 16384
#define KNN 8

#define DT_BF16 1
#define DT_FP32 2

// Workspace layout:
//   flag : int          @ 0
//   idx  : int  [N*9]   @ 64        -> 589,824 B
//   x1   : f32  [N*64]  @ 589,888   -> 4,194,304 B
// Grid-KNN scratch lives INSIDE the x1 region (dead before conv1 writes x1):
//   sat      : int [110592]  @ x1+0        (counts -> x-prefix -> full 3D SAT)
//   start    : int [110593]  @ x1+442368   (cell starts + sentinel)
//   cursor   : int [110592]  @ x1+884800
//   pid      : int [16384]   @ x1+1327168
//   pts4     : f4  [16384]   @ x1+1392704
//   rowtot   : int [2304]    @ x1+1654848
//   rowstart : int [2304]    @ x1+1664064
//   xpre     : int [110592]  @ x1+1673280  (x-prefix copy; end 2,115,648 <= 4,194,304)
#define WS_FLAG_OFF 0
#define WS_IDX_OFF  64
#define WS_X1_OFF   589888
#define WS_NEEDED   4784192

#define WS_SAT_OFF      (WS_X1_OFF)
#define WS_START_OFF    (WS_X1_OFF + 442368)
#define WS_CURSOR_OFF   (WS_X1_OFF + 884800)
#define WS_PID_OFF      (WS_X1_OFF + 1327168)
#define WS_PTS_OFF      (WS_X1_OFF + 1392704)
#define WS_ROWTOT_OFF   (WS_X1_OFF + 1654848)
#define WS_ROWSTART_OFF (WS_X1_OFF + 1664064)
#define WS_XPRE_OFF     (WS_X1_OFF + 1673280)

#define GRID_R   48
#define NROWS2D  (GRID_R * GRID_R)          // 2304 (y,z) rows
#define NCELLS   (GRID_R * GRID_R * GRID_R) // 110592
#define GLO      -4.5f
#define CELL_E   0.1875f
#define CELL_INV 5.3333335f
#define NBR_MIN  40
#define NBR_LO   9    // minimum population: 8 neighbors + self -> finite d8
#define M_CAP    1024 // if the NBR_MIN window holds more than this, use the LO window

// sentinel key = (key(+INF) << 32) | 0xFFFFFFFF — sorts after any real candidate
#define SENT_KEY 0xFF800000FFFFFFFFull

__device__ __forceinline__ float bf2f(__hip_bfloat16 v) { return __bfloat162float(v); }

__device__ __forceinline__ float ldf(const float* p, int i) { return p[i]; }
__device__ __forceinline__ float ldf(const __hip_bfloat16* p, int i) { return bf2f(p[i]); }
__device__ __forceinline__ void stf(float* p, int i, float v) { p[i] = v; }
__device__ __forceinline__ void stf(__hip_bfloat16* p, int i, float v) { p[i] = __float2bfloat16(v); }

__device__ __forceinline__ int clamp_idx(int j) {
    return ((unsigned)j < (unsigned)N_PTS) ? j : 0;
}

__device__ __forceinline__ int cell_of(float v) {
    int c = (int)((v - GLO) * CELL_INV);
    return min(max(c, 0), GRID_R - 1);
}

// order-preserving float -> uint (lex on (d, idx) == u64 compare)
__device__ __forceinline__ unsigned fkey(float d) {
    unsigned b = __float_as_uint(d);
    return b ^ ((unsigned)((int)b >> 31) | 0x80000000u);
}
__device__ __forceinline__ float fkey_inv(unsigned k) {
    unsigned b = (k & 0x80000000u) ? (k ^ 0x80000000u) : ~k;
    return __uint_as_float(b);
}

// flag[0] holds the sniffer's bad-count; >16 => fp32 input.
__device__ __forceinline__ int get_dt(const int* flag) {
    return (flag[0] > 16) ? DT_FP32 : DT_BF16;
}

// ---------------------------------------------------------------------------
// zero: cnt[] and flag.
// ---------------------------------------------------------------------------
__global__ __launch_bounds__(256) void zero_kernel(int* __restrict__ cnt, int* __restrict__ flag) {
    const int e = blockIdx.x * 256 + threadIdx.x;
    cnt[e] = 0;
    if (e == 0) flag[0] = 0;
}

// ---------------------------------------------------------------------------
// sniff (multi-block).
// ---------------------------------------------------------------------------
__global__ __launch_bounds__(256) void sniff_kernel(const unsigned short* __restrict__ posu,
                                                    int* __restrict__ flag) {
    __shared__ int red[256];
    int local = 0;
    for (int e = blockIdx.x * 256 + threadIdx.x; e < 3 * N_PTS; e += 64 * 256) {
        const float v = __uint_as_float(((unsigned)posu[e]) << 16);
        if (!(fabsf(v) <= 64.0f)) local++;
    }
    red[threadIdx.x] = local;
    __syncthreads();
    for (int s = 128; s > 0; s >>= 1) {
        if (threadIdx.x < s) red[threadIdx.x] += red[threadIdx.x + s];
        __syncthreads();
    }
    if (threadIdx.x == 0 && red[0] > 0) atomicAdd(flag, red[0]);
}

// ---------------------------------------------------------------------------
// Grid build (parallel): count -> rowscan(+xpre) -> rowoffset ->
// {cellstart+saty fused} -> {satz+scatter fused}.
// ---------------------------------------------------------------------------
template <typename T>
__device__ __forceinline__ void count_body(const T* __restrict__ pos, int* __restrict__ cnt) {
    const int i = blockIdx.x * 256 + threadIdx.x;
    const float x = ldf(pos, 3 * i + 0);
    const float y = ldf(pos, 3 * i + 1);
    const float z = ldf(pos, 3 * i + 2);
    const int c = (cell_of(z) * GRID_R + cell_of(y)) * GRID_R + cell_of(x);
    atomicAdd(&cnt[c], 1);
}

__global__ __launch_bounds__(256) void grid_count_kernel(const void* __restrict__ pos,
                                                         const int* __restrict__ flag,
                                                         int* __restrict__ cnt) {
    if (get_dt(flag) == DT_BF16) count_body<__hip_bfloat16>((const __hip_bfloat16*)pos, cnt);
    else                         count_body<float>((const float*)pos, cnt);
}

// x-prefix per row (in place over sat, plus copy to xpre), rowtot = row sum.
__global__ __launch_bounds__(256) void rowscan_kernel(int* __restrict__ sat,
                                                      int* __restrict__ xpre,
                                                      int* __restrict__ rowtot) {
    const int t = blockIdx.x * 256 + threadIdx.x;   // row < 2304
    const int rb = t * GRID_R;
    int acc = 0;
    for (int x = 0; x < GRID_R; ++x) {
        acc += sat[rb + x];
        sat[rb + x]  = acc;
        xpre[rb + x] = acc;
    }
    rowtot[t] = acc;
}

// exclusive scan of 2304 row totals (one block, 256 threads x 9 rows).
__global__ __launch_bounds__(256) void rowoffset_kernel(const int* __restrict__ rowtot,
                                                        int* __restrict__ rowstart) {
    __shared__ int part[256];
    const int t = threadIdx.x;
    int loc[9]; int s = 0;
#pragma unroll
    for (int k = 0; k < 9; ++k) { loc[k] = rowtot[t * 9 + k]; s += loc[k]; }
    part[t] = s;
    __syncthreads();
    for (int off = 1; off < 256; off <<= 1) {
        int v = (t >= off) ? part[t - off] : 0;
        __syncthreads();
        part[t] += v;
        __syncthreads();
    }
    int run = (t == 0) ? 0 : part[t - 1];
#pragma unroll
    for (int k = 0; k < 9; ++k) { rowstart[t * 9 + k] = run; run += loc[k]; }
}

// FUSED: cellstart (from xpre copy -> no dependence on sat) + SAT y-pass.
__global__ __launch_bounds__(256) void cellsaty_kernel(const int* __restrict__ xpre,
                                                       const int* __restrict__ rowstart,
                                                       int* __restrict__ cstart,
                                                       int* __restrict__ cursor,
                                                       int* __restrict__ sat) {
    const int t = blockIdx.x * 256 + threadIdx.x;   // < 2304
    const int rb = t * GRID_R;
    const int base = rowstart[t];
    int prev = 0;
    for (int x = 0; x < GRID_R; ++x) {
        const int v = base + prev;
        cstart[rb + x] = v;
        cursor[rb + x] = v;
        prev = xpre[rb + x];
    }
    if (t == NROWS2D - 1) cstart[NCELLS] = base + prev;
    const int z = t / GRID_R, x = t - z * GRID_R;
    const int b2 = z * NROWS2D + x;
    int run = 0;
#pragma unroll
    for (int y = 0; y < GRID_R; ++y) {
        run += sat[b2 + y * GRID_R];
        sat[b2 + y * GRID_R] = run;
    }
}

// FUSED: SAT z-pass (blocks 0..8) + scatter (blocks 9..72).
template <typename T>
__device__ __forceinline__ void scatter_body(const T* __restrict__ pos, int i,
                                             int* __restrict__ cursor,
                                             float4* __restrict__ pts4, int* __restrict__ pid) {
    const float x = ldf(pos, 3 * i + 0);
    const float y = ldf(pos, 3 * i + 1);
    const float z = ldf(pos, 3 * i + 2);
    const int c = (cell_of(z) * GRID_R + cell_of(y)) * GRID_R + cell_of(x);
    const int slot = atomicAdd(&cursor[c], 1);
    const float sq = fmaf(x, x, fmaf(y, y, z * z));
    pts4[slot] = make_float4(-2.0f * x, -2.0f * y, -2.0f * z, sq);
    pid[slot] = i;
}

__global__ __launch_bounds__(256) void satzscatter_kernel(const void* __restrict__ pos,
                                                          const int* __restrict__ flag,
                                                          int* __restrict__ sat,
                                                          int* __restrict__ cursor,
                                                          float4* __restrict__ pts4,
                                                          int* __restrict__ pid) {
    if (blockIdx.x < 9) {
        const int t = blockIdx.x * 256 + threadIdx.x;   // < 2304
        int run = 0;
#pragma unroll
        for (int z = 0; z < GRID_R; ++z) {
            run += sat[t + z * NROWS2D];
            sat[t + z * NROWS2D] = run;
        }
    } else {
        const int i = (blockIdx.x - 9) * 256 + threadIdx.x;
        if (get_dt(flag) == DT_BF16) scatter_body<__hip_bfloat16>((const __hip_bfloat16*)pos, i, cursor, pts4, pid);
        else                         scatter_body<float>((const float*)pos, i, cursor, pts4, pid);
    }
}

// ---------------------------------------------------------------------------
// KNN v12 = v11 + u64 keys + BITONIC cross-lane merge (serial-chain fix).
// r10 post-mortem: three candidate-count fixes were null -> knn is bound by
// the per-target serial latency chain (VALUBusy 27% at 8 waves/SIMD = one
// VALU issue per ~30cy per wave). Longest chain: the 8-pick merge, 40
// dependent shfl latencies (~1.6k cy/target, run for EVERY target as the
// termination check). v12: (d,idx) packed into order-preserving u64 keys
// (lex == u64 compare; ties -> smaller idx automatic); merge = 5 bitonic
// butterfly levels, each ONE parallel 8-key exchange (independent bpermutes)
// + register-only clean-sort (m[i]=min(a[i],b[7-i]) keeps lowest 8; 3
// compare-exchange stages). ~0.5k cy. All lanes end with the identical
// sorted global top-8 -> doubles as output and d8. Identical selection
// semantics (same lex order, tau gate incl. ties, INF sentinel).
// ---------------------------------------------------------------------------
__device__ __forceinline__ int sat_at(const int* __restrict__ sat, int x, int y, int z) {
    if (x < 0 || y < 0 || z < 0) return 0;
    return sat[(z * GRID_R + y) * GRID_R + x];
}

__device__ __forceinline__ int boxcount(const int* __restrict__ sat,
                                        int x0, int x1, int y0, int y1, int z0, int z1) {
    return sat_at(sat, x1, y1, z1) - sat_at(sat, x0 - 1, y1, z1)
         - sat_at(sat, x1, y0 - 1, z1) - sat_at(sat, x1, y1, z0 - 1)
         + sat_at(sat, x0 - 1, y0 - 1, z1) + sat_at(sat, x0 - 1, y1, z0 - 1)
         + sat_at(sat, x1, y0 - 1, z0 - 1) - sat_at(sat, x0 - 1, y0 - 1, z0 - 1);
}

template <typename T>
__device__ void knn_body(const T* __restrict__ pos,
                         const int* __restrict__ cstart, const int* __restrict__ sat,
                         const float4* __restrict__ pts4, const int* __restrict__ pid,
                         int* __restrict__ idx_out,
                         int* __restrict__ rs, int* __restrict__ epf) {
    const int tid  = threadIdx.x;
    const int lane = tid & 31;                 // lane within 32-lane subgroup
    const int i    = blockIdx.x * 8 + (tid >> 5);

    const float pix = ldf(pos, 3 * i + 0);
    const float piy = ldf(pos, 3 * i + 1);
    const float piz = ldf(pos, 3 * i + 2);
    const float sqi = fmaf(pix, pix, fmaf(piy, piy, piz * piz));
    const int cx = cell_of(pix), cy = cell_of(piy), cz = cell_of(piz);

    unsigned long long bk[KNN];
#pragma unroll
    for (int q = 0; q < KNN; ++q) bk[q] = SENT_KEY;
    unsigned long long tk = SENT_KEY;          // gate key (>= global 8th-best)

    auto do_insert = [&](unsigned long long ck) {
#pragma unroll
        for (int q = 0; q < KNN; ++q) {
            const unsigned long long old = bk[q];
            const bool ins = ck < old;
            bk[q] = ins ? ck : old;
            ck    = ins ? old : ck;
        }
        tk = bk[KNN - 1];
    };

    // window scan; clipR < INF restricts each row's x-run to the s2-chord.
    auto scan_win = [&](int rr, float clipR) {
        const int x0 = max(cx - rr, 0), x1 = min(cx + rr, GRID_R - 1);
        const int y0 = max(cy - rr, 0), y1 = min(cy + rr, GRID_R - 1);
        const int z0 = max(cz - rr, 0), z1 = min(cz + rr, GRID_R - 1);
        const int ny = y1 - y0 + 1;
        const int R  = ny * (z1 - z0 + 1);
        const float clip2 = clipR * clipR;
        for (int cb = 0; cb < R; cb += 32) {
            const int lr = cb + lane;
            int cnt_r = 0, st_r = 0;
            if (lr < R) {
                const int iz = lr / ny;
                const int iy = lr - iz * ny;
                const int ycell = y0 + iy, zcell = z0 + iz;
                int cxa = x0, cxb = x1;
                if (clipR < 1e30f) {
                    const float ylo = GLO + (float)ycell * CELL_E;
                    const float zlo = GLO + (float)zcell * CELL_E;
                    const float dy = fmaxf(0.0f, fmaxf(ylo - piy, piy - (ylo + CELL_E)));
                    const float dz = fmaxf(0.0f, fmaxf(zlo - piz, piz - (zlo + CELL_E)));
                    const float rad2 = clip2 - dy * dy - dz * dz;
                    if (rad2 <= 0.0f) { cxa = 1; cxb = 0; }
                    else {
                        const float hr = sqrtf(rad2) + 1e-4f;
                        cxa = max(x0, (int)floorf((pix - hr - GLO) * CELL_INV));
                        cxb = min(x1, (int)floorf((pix + hr - GLO) * CELL_INV));
                    }
                }
                if (cxa <= cxb) {
                    const int c0 = (zcell * GRID_R + ycell) * GRID_R + cxa;
                    st_r  = cstart[c0];
                    cnt_r = cstart[c0 + (cxb - cxa) + 1] - st_r;
                }
            }
            int pv = cnt_r;
#pragma unroll
            for (int s = 1; s < 32; s <<= 1) {
                const int u = __shfl_up(pv, s, 32);
                if (lane >= s) pv += u;
            }
            const int Mtot = __shfl(pv, 31, 32);
            asm volatile("s_waitcnt lgkmcnt(0)" ::: "memory");  // prev chunk reads done
            rs[lane]  = st_r;
            epf[lane] = (lr < R) ? (pv - cnt_r) : 0x7fffffff;   // exclusive prefix / +inf
            asm volatile("s_waitcnt lgkmcnt(0)" ::: "memory");  // staging visible
            for (int tb = 0; tb < Mtot; tb += 128) {
                unsigned long long ck[4];
#pragma unroll
                for (int k = 0; k < 4; ++k) {
                    const int t = tb + (k << 5) + lane;
                    ck[k] = SENT_KEY;
                    if (t < Mtot) {
                        int p = 0;
#pragma unroll
                        for (int st = 16; st >= 1; st >>= 1)
                            if (epf[p + st] <= t) p += st;
                        const int si = rs[p] + (t - epf[p]);
                        const float4 cq = pts4[si];
                        const int pj = pid[si];
                        const float d = fmaf(cq.x, pix, fmaf(cq.y, piy, fmaf(cq.z, piz, cq.w)));
                        if (pj != i)
                            ck[k] = ((unsigned long long)fkey(d) << 32) | (unsigned)pj;
                    }
                }
#pragma unroll
                for (int k = 0; k < 4; ++k)
                    if (ck[k] != SENT_KEY && ck[k] <= tk) do_insert(ck[k]);
            }
        }
    };

    // bitonic cross-lane merge: 5 levels; after it, ALL lanes hold the same
    // sorted global top-8 keys in bk[0..7].
    auto merge_all = [&]() {
#pragma unroll
        for (int s = 1; s < 32; s <<= 1) {
            unsigned long long m[KNN];
#pragma unroll
            for (int q = 0; q < KNN; ++q) {
                const unsigned long long o = __shfl_xor(bk[KNN - 1 - q], s, 32);
                m[q] = (bk[q] < o) ? bk[q] : o;    // lowest-8 of the 16 (bitonic)
            }
#pragma unroll
            for (int d = 4; d >= 1; d >>= 1) {
#pragma unroll
                for (int q = 0; q < KNN; ++q) {
                    if (!(q & d)) {
                        const unsigned long long a = m[q], b = m[q + d];
                        const bool sw = b < a;
                        m[q]     = sw ? b : a;
                        m[q + d] = sw ? a : b;
                    }
                }
            }
#pragma unroll
            for (int q = 0; q < KNN; ++q) bk[q] = m[q];
        }
        tk = bk[KNN - 1];
    };

    // ---- 1) two-level SAT radius probe: lane l tests radius l+1 (<=32) ----
    int r;
    {
        const int rl = lane + 1;
        const int bx0 = max(cx - rl, 0), bx1 = min(cx + rl, GRID_R - 1);
        const int by0 = max(cy - rl, 0), by1 = min(cy + rl, GRID_R - 1);
        const int bz0 = max(cz - rl, 0), bz1 = min(cz + rl, GRID_R - 1);
        const int cntl = boxcount(sat, bx0, bx1, by0, by1, bz0, bz1);
        const unsigned long long m9  = __ballot(cntl >= NBR_LO);
        const unsigned long long m26 = __ballot(cntl >= NBR_MIN);
        const unsigned sh  = (unsigned)(tid & 32);
        const unsigned mh9  = (unsigned)(m9  >> sh);
        const unsigned mh26 = (unsigned)(m26 >> sh);
        const int r9  = mh9  ? (int)__ffs(mh9)  : 32;
        const int r26 = mh26 ? (int)__ffs(mh26) : 32;
        const int cnt26 = __shfl(cntl, r26 - 1, 32);   // population of preferred window
        r = (cnt26 <= M_CAP) ? r26 : r9;
    }

    // ---- 2) window scan at r (no clip: tau unknown) ----
    scan_win(r, INFINITY);

    // ---- 3) merge + termination; chord-clipped second pass on failure ----
    {
        float mg = INFINITY;
        bool full = true;
        if (cx - r > 0)          { mg = fminf(mg, pix - (GLO + (float)(cx - r) * CELL_E));     full = false; }
        if (cx + r < GRID_R - 1) { mg = fminf(mg, (GLO + (float)(cx + r + 1) * CELL_E) - pix); full = false; }
        if (cy - r > 0)          { mg = fminf(mg, piy - (GLO + (float)(cy - r) * CELL_E));     full = false; }
        if (cy + r < GRID_R - 1) { mg = fminf(mg, (GLO + (float)(cy + r + 1) * CELL_E) - piy); full = false; }
        if (cz - r > 0)          { mg = fminf(mg, piz - (GLO + (float)(cz - r) * CELL_E));     full = false; }
        if (cz + r < GRID_R - 1) { mg = fminf(mg, (GLO + (float)(cz + r + 1) * CELL_E) - piz); full = false; }

        merge_all();                             // all lanes: sorted global top-8
        bool done = full;
        const unsigned long long d8key = bk[KNN - 1];
        const float d8 = fkey_inv((unsigned)(d8key >> 32));
        if (!full) {
            const float mge  = mg - 1e-5f;
            const float need = mge * mge - sqi;  // d_real < mge^2  <=>  d' < need
            done = (d8 < need);                  // strict; NaN/INF d8 -> false
        }

        if (!done) {
            // s2 = conservative real-distance bound on the true 8th neighbor
            float s2 = sqrtf(fmaxf(d8 + sqi, 0.0f)) + 1e-4f;
            s2 = fminf(s2, 9.0f);                // INF d8 -> full grid
            auto dneed = [&](float frac, int clip) -> int {
                int nd = (int)ceilf((s2 - frac) * CELL_INV);
                nd = max(nd, 0);
                return min(nd, clip);
            };
            const float fxm = pix - (GLO + (float)cx * CELL_E);
            const float fxp = (GLO + (float)(cx + 1) * CELL_E) - pix;
            const float fym = piy - (GLO + (float)cy * CELL_E);
            const float fyp = (GLO + (float)(cy + 1) * CELL_E) - piy;
            const float fzm = piz - (GLO + (float)cz * CELL_E);
            const float fzp = (GLO + (float)(cz + 1) * CELL_E) - piz;
            int r2 = r + 1;
            r2 = max(r2, dneed(fxm, cx));
            r2 = max(r2, dneed(fxp, GRID_R - 1 - cx));
            r2 = max(r2, dneed(fym, cy));
            r2 = max(r2, dneed(fyp, GRID_R - 1 - cy));
            r2 = max(r2, dneed(fzm, cz));
            r2 = max(r2, dneed(fzp, GRID_R - 1 - cz));
            r2 = min(r2, GRID_R);

            // fresh lists; gate seeded with pass-1 8th key (<= admits the 8th
            // itself and its lex-predecessors; chord window is a superset of
            // all points with d_real <= d8_real => exact)
#pragma unroll
            for (int q = 0; q < KNN; ++q) bk[q] = SENT_KEY;
            tk = d8key;
            scan_win(r2, (d8 < INFINITY) ? s2 : INFINITY);
            merge_all();
        }
    }

    if (lane == 0) {
#pragma unroll
        for (int k = 0; k < KNN; ++k) idx_out[i * 9 + k] = clamp_idx((int)(unsigned)bk[k]);
        idx_out[i * 9 + 8] = i;
    }
}

__global__ __launch_bounds__(256) void knn_grid_kernel(const void* __restrict__ pos,
                                                       const int* __restrict__ flag,
                                                       const int* __restrict__ cstart,
                                                       const int* __restrict__ sat,
                                                       const float4* __restrict__ pts4,
                                                       const int* __restrict__ pid,
                                                       int* __restrict__ idx_out) {
    __shared__ int rs[8][32];
    __shared__ int epf[8][32];
    const int sg = threadIdx.x >> 5;
    if (get_dt(flag) == DT_BF16)
        knn_body<__hip_bfloat16>((const __hip_bfloat16*)pos, cstart, sat, pts4, pid, idx_out,
                                 rs[sg], epf[sg]);
    else
        knn_body<float>((const float*)pos, cstart, sat, pts4, pid, idx_out, rs[sg], epf[sg]);
}

// ---------------------------------------------------------------------------
// conv1 (unchanged from r10): factored first layer; named-reg k-tiled wB.
// ---------------------------------------------------------------------------
struct Conv1Smem {
    alignas(16) float wB[32 * 64];
    alignas(16) float h1s[4][9 * 32];
    alignas(16) float wsum[3 * 32];
    alignas(16) float wbot[3 * 32];
    alignas(16) float posn[4][9][3];
    float bA[32];
    float bB[64];
};

template <typename T>
__device__ void conv1_body(const T* __restrict__ pos, const int* __restrict__ idx,
                           const T* __restrict__ W1a, const T* __restrict__ b1a,
                           const T* __restrict__ W1b, const T* __restrict__ b1b,
                           float* __restrict__ x1, Conv1Smem& s) {
    const int tid = threadIdx.x;
    for (int e = tid; e < 96; e += 256) {
        const float bot = ldf(W1a, 96 + e);
        s.wsum[e] = ldf(W1a, e) + bot;
        s.wbot[e] = bot;
    }
    if (tid < 32) s.bA[tid] = ldf(b1a, tid);
    for (int e = tid; e < 2048; e += 256) s.wB[e] = ldf(W1b, e);
    if (tid < 64) s.bB[tid] = ldf(b1b, tid);

    const int tl   = tid >> 6;
    const int lane = tid & 63;
    const int i    = blockIdx.x * 4 + tl;

    if (lane < 27) {
        const int n = lane / 3, c = lane % 3;
        const int j = clamp_idx(idx[i * 9 + n]);
        s.posn[tl][n][c] = ldf(pos, 3 * j + c);
    }
    const float pi0 = ldf(pos, 3 * i + 0);
    const float pi1 = ldf(pos, 3 * i + 1);
    const float pi2 = ldf(pos, 3 * i + 2);
    __syncthreads();

    for (int e = lane; e < 288; e += 64) {
        const int n = e >> 5, k = e & 31;
        float b = fmaf(pi0, s.wbot[k], fmaf(pi1, s.wbot[32 + k], pi2 * s.wbot[64 + k]));
        float v = s.bA[k] - b;
        v = fmaf(s.posn[tl][n][0], s.wsum[k], v);
        v = fmaf(s.posn[tl][n][1], s.wsum[32 + k], v);
        v = fmaf(s.posn[tl][n][2], s.wsum[64 + k], v);
        s.h1s[tl][n * 32 + k] = fmaxf(v, 0.0f);
    }
    __syncthreads();

    float acc[9];
#pragma unroll
    for (int n = 0; n < 9; ++n) acc[n] = 0.0f;
#pragma unroll
    for (int kt = 0; kt < 32; kt += 8) {
        float w0 = s.wB[(kt + 0) * 64 + lane];
        float w1 = s.wB[(kt + 1) * 64 + lane];
        float w2 = s.wB[(kt + 2) * 64 + lane];
        float w3 = s.wB[(kt + 3) * 64 + lane];
        float w4 = s.wB[(kt + 4) * 64 + lane];
        float w5 = s.wB[(kt + 5) * 64 + lane];
        float w6 = s.wB[(kt + 6) * 64 + lane];
        float w7 = s.wB[(kt + 7) * 64 + lane];
#pragma unroll
        for (int n = 0; n < 9; ++n) {
            const float4 ha = *(const float4*)&s.h1s[tl][n * 32 + kt];
            const float4 hb = *(const float4*)&s.h1s[tl][n * 32 + kt + 4];
            float a = acc[n];
            a = fmaf(ha.x, w0, a); a = fmaf(ha.y, w1, a);
            a = fmaf(ha.z, w2, a); a = fmaf(ha.w, w3, a);
            a = fmaf(hb.x, w4, a); a = fmaf(hb.y, w5, a);
            a = fmaf(hb.z, w6, a); a = fmaf(hb.w, w7, a);
            acc[n] = a;
        }
    }
    float m = acc[0];
#pragma unroll
    for (int n = 1; n < 9; ++n) m = fmaxf(m, acc[n]);
    x1[i * 64 + lane] = fmaxf(m + s.bB[lane], 0.0f);
}

__global__ __launch_bounds__(256) void conv1_kernel(const void* __restrict__ pos,
                                                    const int* __restrict__ flag,
                                                    const int* __restrict__ idx,
                                                    const void* __restrict__ W1a,
                                                    const void* __restrict__ b1a,
                                                    const void* __restrict__ W1b,
                                                    const void* __restrict__ b1b,
                                                    float* __restrict__ x1) {
    __shared__ Conv1Smem s;
    if (get_dt(flag) == DT_BF16)
        conv1_body<__hip_bfloat16>((const __hip_bfloat16*)pos, idx,
            (const __hip_bfloat16*)W1a, (const __hip_bfloat16*)b1a,
            (const __hip_bfloat16*)W1b, (const __hip_bfloat16*)b1b, x1, s);
    else
        conv1_body<float>((const float*)pos, idx, (const float*)W1a, (const float*)b1a,
            (const float*)W1b, (const float*)b1b, x1, s);
}

// ---------------------------------------------------------------------------
// zw (unchanged): per-point precompute for conv2's first layer.
// ---------------------------------------------------------------------------
struct ZwSmem {
    alignas(16) float wA[67 * 64];
    alignas(16) float xrT[4][68][4];
    float bA[64];
};

template <typename T>
__device__ void zw_body(const T* __restrict__ pos, const T* __restrict__ W2a,
                        const T* __restrict__ b2a, float* __restrict__ x1, ZwSmem& s) {
    const int tid  = threadIdx.x;
    const int wv   = tid >> 6;
    const int lane = tid & 63;
    const int j0   = blockIdx.x * 16 + wv * 4;

    for (int e = tid; e < 4288; e += 256) s.wA[e] = ldf(W2a, e);
    if (tid < 64) s.bA[tid] = ldf(b2a, tid);

#pragma unroll
    for (int p = 0; p < 4; ++p)
        s.xrT[wv][lane][p] = x1[(j0 + p) * 64 + lane];
    if (lane < 12) {
        const int p = lane / 3, c = lane % 3;
        s.xrT[wv][64 + c][p] = ldf(pos, 3 * (j0 + p) + c);
    }
    __syncthreads();

    float a0 = s.bA[lane], a1 = a0, a2 = a0, a3 = a0;
    for (int c = 0; c < 67; ++c) {
        const float w = s.wA[c * 64 + lane];
        const float4 xv = *(const float4*)&s.xrT[wv][c][0];
        a0 = fmaf(xv.x, w, a0);
        a1 = fmaf(xv.y, w, a1);
        a2 = fmaf(xv.z, w, a2);
        a3 = fmaf(xv.w, w, a3);
    }
    x1[(j0 + 0) * 64 + lane] = a0;
    x1[(j0 + 1) * 64 + lane] = a1;
    x1[(j0 + 2) * 64 + lane] = a2;
    x1[(j0 + 3) * 64 + lane] = a3;
}

__global__ __launch_bounds__(256) void zw_kernel(const void* __restrict__ pos,
                                                 const int* __restrict__ flag,
                                                 const void* __restrict__ W2a,
                                                 const void* __restrict__ b2a,
                                                 float* __restrict__ x1) {
    __shared__ ZwSmem s;
    if (get_dt(flag) == DT_BF16)
        zw_body<__hip_bfloat16>((const __hip_bfloat16*)pos, (const __hip_bfloat16*)W2a,
                                (const __hip_bfloat16*)b2a, x1, s);
    else
        zw_body<float>((const float*)pos, (const float*)W2a, (const float*)b2a, x1, s);
}

// ---------------------------------------------------------------------------
// conv2+head (unchanged from r10): named-reg k-tiles, 2 channels/thread.
// ---------------------------------------------------------------------------
struct Conv2Smem {
    alignas(16) float h1s[4][9 * 64];
    alignas(16) float row[4][128];
    alignas(16) float wbot[3 * 64];
    alignas(16) float wc[640];
    float bcs[5];
    float sv[4][5];
    int   nb[4][9];
};

template <typename T>
__device__ void conv2_body(const T* __restrict__ pos, const int* __restrict__ idx,
                           const float* __restrict__ zw,
                           const T* __restrict__ W2a, const T* __restrict__ W2b,
                           const T* __restrict__ b2b, const T* __restrict__ Wc,
                           const T* __restrict__ bc, T* __restrict__ out, Conv2Smem& s) {
    const int tid  = threadIdx.x;
    const int tl   = tid >> 6;
    const int lane = tid & 63;
    const int i    = blockIdx.x * 4 + tl;

    for (int e = tid; e < 192; e += 256) s.wbot[e] = ldf(W2a, 4096 + e);
    for (int e = tid; e < 640; e += 256) s.wc[e] = ldf(Wc, e);
    if (tid < 5) s.bcs[tid] = ldf(bc, tid);

    if (lane < 9) s.nb[tl][lane] = clamp_idx(idx[i * 9 + lane]);
    const float pi0 = ldf(pos, 3 * i + 0);
    const float pi1 = ldf(pos, 3 * i + 1);
    const float pi2 = ldf(pos, 3 * i + 2);
    __syncthreads();

    {
        const float vi = fmaf(pi0, s.wbot[lane], fmaf(pi1, s.wbot[64 + lane], pi2 * s.wbot[128 + lane]));
#pragma unroll
        for (int n = 0; n < 9; ++n) {
            const int j = s.nb[tl][n];
            s.h1s[tl][n * 64 + lane] = fmaxf(zw[j * 64 + lane] - vi, 0.0f);
        }
    }
    __syncthreads();

    float acc0[9], acc1[9];
#pragma unroll
    for (int n = 0; n < 9; ++n) { acc0[n] = 0.0f; acc1[n] = 0.0f; }
#pragma unroll
    for (int kt = 0; kt < 64; kt += 4) {
        const float wa0 = ldf(W2b, (kt + 0) * 128 + lane);
        const float wa1 = ldf(W2b, (kt + 1) * 128 + lane);
        const float wa2 = ldf(W2b, (kt + 2) * 128 + lane);
        const float wa3 = ldf(W2b, (kt + 3) * 128 + lane);
        const float wb0 = ldf(W2b, (kt + 0) * 128 + lane + 64);
        const float wb1 = ldf(W2b, (kt + 1) * 128 + lane + 64);
        const float wb2 = ldf(W2b, (kt + 2) * 128 + lane + 64);
        const float wb3 = ldf(W2b, (kt + 3) * 128 + lane + 64);
#pragma unroll
        for (int n = 0; n < 9; ++n) {
            const float4 h = *(const float4*)&s.h1s[tl][n * 64 + kt];
            float a0 = acc0[n], a1 = acc1[n];
            a0 = fmaf(h.x, wa0, a0); a0 = fmaf(h.y, wa1, a0);
            a0 = fmaf(h.z, wa2, a0); a0 = fmaf(h.w, wa3, a0);
            a1 = fmaf(h.x, wb0, a1); a1 = fmaf(h.y, wb1, a1);
            a1 = fmaf(h.z, wb2, a1); a1 = fmaf(h.w, wb3, a1);
            acc0[n] = a0; acc1[n] = a1;
        }
    }
    float m0 = acc0[0], m1 = acc1[0];
#pragma unroll
    for (int n = 1; n < 9; ++n) { m0 = fmaxf(m0, acc0[n]); m1 = fmaxf(m1, acc1[n]); }
    s.row[tl][lane]      = fmaxf(m0 + ldf(b2b, lane), 0.0f);
    s.row[tl][lane + 64] = fmaxf(m1 + ldf(b2b, lane + 64), 0.0f);
    __syncthreads();

    if (tid < 20) {
        const int tgt = tid / 5, o = tid % 5;
        float v = s.bcs[o];
        for (int k = 0; k < 128; ++k) v = fmaf(s.row[tgt][k], s.wc[k * 5 + o], v);
        s.sv[tgt][o] = v;
    }
    __syncthreads();
    if (tid < 20) {
        const int tgt = tid / 5, o = tid % 5;
        float m = s.sv[tgt][0];
#pragma unroll
        for (int q = 1; q < 5; ++q) m = fmaxf(m, s.sv[tgt][q]);
        float sum = 0.0f;
#pragma unroll
        for (int q = 0; q < 5; ++q) sum += expf(s.sv[tgt][q] - m);
        const float lse = m + logf(sum);
        stf(out, (blockIdx.x * 4 + tgt) * 5 + o, s.sv[tgt][o] - lse);
    }
}

__global__ __launch_bounds__(256) void conv2_head_kernel(const void* __restrict__ pos,
                                                         const int* __restrict__ flag,
                                                         const int* __restrict__ idx,
                                                         const float* __restrict__ zw,
                                                         const void* __restrict__ W2a,
                                                         const void* __restrict__ W2b,
                                                         const void* __restrict__ b2b,
                                                         const void* __restrict__ Wc,
                                                         const void* __restrict__ bc,
                                                         void* __restrict__ out) {
    __shared__ Conv2Smem s;
    if (get_dt(flag) == DT_BF16)
        conv2_body<__hip_bfloat16>((const __hip_bfloat16*)pos, idx, zw,
            (const __hip_bfloat16*)W2a, (const __hip_bfloat16*)W2b, (const __hip_bfloat16*)b2b,
            (const __hip_bfloat16*)Wc, (const __hip_bfloat16*)bc, (__hip_bfloat16*)out, s);
    else
        conv2_body<float>((const float*)pos, idx, zw, (const float*)W2a, (const float*)W2b,
            (const float*)b2b, (const float*)Wc, (const float*)bc, (float*)out, s);
}

// ---------------------------------------------------------------------------
extern "C" void kernel_launch(void* const* d_in, const int* in_sizes, int n_in,
                              void* d_out, int out_size, void* d_ws, size_t ws_size,
                              hipStream_t stream) {
    if (ws_size < (size_t)WS_NEEDED) return;

    char* ws = (char*)d_ws;
    int*    flag     = (int*)(ws + WS_FLAG_OFF);
    int*    idx      = (int*)(ws + WS_IDX_OFF);
    float*  x1       = (float*)(ws + WS_X1_OFF);
    int*    sat      = (int*)(ws + WS_SAT_OFF);
    int*    cstart   = (int*)(ws + WS_START_OFF);
    int*    cursor   = (int*)(ws + WS_CURSOR_OFF);
    int*    pid      = (int*)(ws + WS_PID_OFF);
    float4* pts4     = (float4*)(ws + WS_PTS_OFF);
    int*    rowtot   = (int*)(ws + WS_ROWTOT_OFF);
    int*    rowstart = (int*)(ws + WS_ROWSTART_OFF);
    int*    xpre     = (int*)(ws + WS_XPRE_OFF);

    zero_kernel<<<NCELLS / 256, 256, 0, stream>>>(sat, flag);
    sniff_kernel<<<64, 256, 0, stream>>>((const unsigned short*)d_in[0], flag);
    grid_count_kernel<<<N_PTS / 256, 256, 0, stream>>>(d_in[0], flag, sat);
    rowscan_kernel<<<NROWS2D / 256, 256, 0, stream>>>(sat, xpre, rowtot);
    rowoffset_kernel<<<1, 256, 0, stream>>>(rowtot, rowstart);
    cellsaty_kernel<<<NROWS2D / 256, 256, 0, stream>>>(xpre, rowstart, cstart, cursor, sat);
    satzscatter_kernel<<<9 + N_PTS / 256, 256, 0, stream>>>(d_in[0], flag, sat, cursor, pts4, pid);
    knn_grid_kernel<<<N_PTS / 8, 256, 0, stream>>>(d_in[0], flag, cstart, sat, pts4, pid, idx);
    conv1_kernel<<<N_PTS / 4, 256, 0, stream>>>(d_in[0], flag, idx,
        d_in[1], d_in[2], d_in[3], d_in[4], x1);
    zw_kernel<<<N_PTS / 16, 256, 0, stream>>>(d_in[0], flag, d_in[5], d_in[6], x1);
    conv2_head_kernel<<<N_PTS / 4, 256, 0, stream>>>(d_in[0], flag, idx, x1,
        d_in[5], d_in[7], d_in[8], d_in[9], d_in[10], d_out);
}

// Round 12
// 225.760 us; speedup vs baseline: 1.7375x; 1.0321x over previous
//
#include <hip/hip_runtime.h>
#include <hip/hip_bf16.h>
#include <math.h>

#define N_PTS 16384
#define KNN 8

#define DT_BF16 1
#define DT_FP32 2

// Workspace layout:
//   flag : int          @ 0
//   idx  : int  [N*9]   @ 64        -> 589,824 B
//   x1   : f32  [N*64]  @ 589,888   -> 4,194,304 B
// Grid-KNN scratch lives INSIDE the x1 region (dead before conv1 writes x1):
//   sat      : int [110592]  @ x1+0        (counts -> x-prefix -> full 3D SAT)
//   start    : int [110593]  @ x1+442368   (cell starts + sentinel)
//   cursor   : int [110592]  @ x1+884800
//   pid      : int [16384]   @ x1+1327168
//   pts4     : f4  [16384]   @ x1+1392704
//   rowtot   : int [2304]    @ x1+1654848
//   rowstart : int [2304]    @ x1+1664064
//   xpre     : int [110592]  @ x1+1673280  (x-prefix copy; end 2,115,648 <= 4,194,304)
#define WS_FLAG_OFF 0
#define WS_IDX_OFF  64
#define WS_X1_OFF   589888
#define WS_NEEDED   4784192

#define WS_SAT_OFF      (WS_X1_OFF)
#define WS_START_OFF    (WS_X1_OFF + 442368)
#define WS_CURSOR_OFF   (WS_X1_OFF + 884800)
#define WS_PID_OFF      (WS_X1_OFF + 1327168)
#define WS_PTS_OFF      (WS_X1_OFF + 1392704)
#define WS_ROWTOT_OFF   (WS_X1_OFF + 1654848)
#define WS_ROWSTART_OFF (WS_X1_OFF + 1664064)
#define WS_XPRE_OFF     (WS_X1_OFF + 1673280)

#define GRID_R   48
#define NROWS2D  (GRID_R * GRID_R)          // 2304 (y,z) rows
#define NCELLS   (GRID_R * GRID_R * GRID_R) // 110592
#define GLO      -4.5f
#define CELL_E   0.1875f
#define CELL_INV 5.3333335f
#define NBR_MIN  40
#define NBR_LO   9    // minimum population: 8 neighbors + self -> finite d8
#define M_CAP    1024 // if the NBR_MIN window holds more than this, use the LO window
#define R_DIRECT 96   // windows with more rows than this walk rows per-lane (no staging)

// sentinel key = (key(+INF) << 32) | 0xFFFFFFFF — sorts after any real candidate
#define SENT_KEY 0xFF800000FFFFFFFFull

__device__ __forceinline__ float bf2f(__hip_bfloat16 v) { return __bfloat162float(v); }

__device__ __forceinline__ float ldf(const float* p, int i) { return p[i]; }
__device__ __forceinline__ float ldf(const __hip_bfloat16* p, int i) { return bf2f(p[i]); }
__device__ __forceinline__ void stf(float* p, int i, float v) { p[i] = v; }
__device__ __forceinline__ void stf(__hip_bfloat16* p, int i, float v) { p[i] = __float2bfloat16(v); }

__device__ __forceinline__ int clamp_idx(int j) {
    return ((unsigned)j < (unsigned)N_PTS) ? j : 0;
}

__device__ __forceinline__ int cell_of(float v) {
    int c = (int)((v - GLO) * CELL_INV);
    return min(max(c, 0), GRID_R - 1);
}

// order-preserving float -> uint (lex on (d, idx) == u64 compare)
__device__ __forceinline__ unsigned fkey(float d) {
    unsigned b = __float_as_uint(d);
    return b ^ ((unsigned)((int)b >> 31) | 0x80000000u);
}
__device__ __forceinline__ float fkey_inv(unsigned k) {
    unsigned b = (k & 0x80000000u) ? (k ^ 0x80000000u) : ~k;
    return __uint_as_float(b);
}

// flag[0] holds the sniffer's bad-count; >16 => fp32 input.
__device__ __forceinline__ int get_dt(const int* flag) {
    return (flag[0] > 16) ? DT_FP32 : DT_BF16;
}

// ---------------------------------------------------------------------------
// zero: cnt[] and flag.
// ---------------------------------------------------------------------------
__global__ __launch_bounds__(256) void zero_kernel(int* __restrict__ cnt, int* __restrict__ flag) {
    const int e = blockIdx.x * 256 + threadIdx.x;
    cnt[e] = 0;
    if (e == 0) flag[0] = 0;
}

// ---------------------------------------------------------------------------
// sniff (multi-block).
// ---------------------------------------------------------------------------
__global__ __launch_bounds__(256) void sniff_kernel(const unsigned short* __restrict__ posu,
                                                    int* __restrict__ flag) {
    __shared__ int red[256];
    int local = 0;
    for (int e = blockIdx.x * 256 + threadIdx.x; e < 3 * N_PTS; e += 64 * 256) {
        const float v = __uint_as_float(((unsigned)posu[e]) << 16);
        if (!(fabsf(v) <= 64.0f)) local++;
    }
    red[threadIdx.x] = local;
    __syncthreads();
    for (int s = 128; s > 0; s >>= 1) {
        if (threadIdx.x < s) red[threadIdx.x] += red[threadIdx.x + s];
        __syncthreads();
    }
    if (threadIdx.x == 0 && red[0] > 0) atomicAdd(flag, red[0]);
}

// ---------------------------------------------------------------------------
// Grid build (parallel): count -> rowscan(+xpre) -> rowoffset ->
// {cellstart+saty fused} -> {satz+scatter fused}.
// ---------------------------------------------------------------------------
template <typename T>
__device__ __forceinline__ void count_body(const T* __restrict__ pos, int* __restrict__ cnt) {
    const int i = blockIdx.x * 256 + threadIdx.x;
    const float x = ldf(pos, 3 * i + 0);
    const float y = ldf(pos, 3 * i + 1);
    const float z = ldf(pos, 3 * i + 2);
    const int c = (cell_of(z) * GRID_R + cell_of(y)) * GRID_R + cell_of(x);
    atomicAdd(&cnt[c], 1);
}

__global__ __launch_bounds__(256) void grid_count_kernel(const void* __restrict__ pos,
                                                         const int* __restrict__ flag,
                                                         int* __restrict__ cnt) {
    if (get_dt(flag) == DT_BF16) count_body<__hip_bfloat16>((const __hip_bfloat16*)pos, cnt);
    else                         count_body<float>((const float*)pos, cnt);
}

// x-prefix per row (in place over sat, plus copy to xpre), rowtot = row sum.
__global__ __launch_bounds__(256) void rowscan_kernel(int* __restrict__ sat,
                                                      int* __restrict__ xpre,
                                                      int* __restrict__ rowtot) {
    const int t = blockIdx.x * 256 + threadIdx.x;   // row < 2304
    const int rb = t * GRID_R;
    int acc = 0;
    for (int x = 0; x < GRID_R; ++x) {
        acc += sat[rb + x];
        sat[rb + x]  = acc;
        xpre[rb + x] = acc;
    }
    rowtot[t] = acc;
}

// exclusive scan of 2304 row totals (one block, 256 threads x 9 rows).
__global__ __launch_bounds__(256) void rowoffset_kernel(const int* __restrict__ rowtot,
                                                        int* __restrict__ rowstart) {
    __shared__ int part[256];
    const int t = threadIdx.x;
    int loc[9]; int s = 0;
#pragma unroll
    for (int k = 0; k < 9; ++k) { loc[k] = rowtot[t * 9 + k]; s += loc[k]; }
    part[t] = s;
    __syncthreads();
    for (int off = 1; off < 256; off <<= 1) {
        int v = (t >= off) ? part[t - off] : 0;
        __syncthreads();
        part[t] += v;
        __syncthreads();
    }
    int run = (t == 0) ? 0 : part[t - 1];
#pragma unroll
    for (int k = 0; k < 9; ++k) { rowstart[t * 9 + k] = run; run += loc[k]; }
}

// FUSED: cellstart (from xpre copy -> no dependence on sat) + SAT y-pass.
__global__ __launch_bounds__(256) void cellsaty_kernel(const int* __restrict__ xpre,
                                                       const int* __restrict__ rowstart,
                                                       int* __restrict__ cstart,
                                                       int* __restrict__ cursor,
                                                       int* __restrict__ sat) {
    const int t = blockIdx.x * 256 + threadIdx.x;   // < 2304
    const int rb = t * GRID_R;
    const int base = rowstart[t];
    int prev = 0;
    for (int x = 0; x < GRID_R; ++x) {
        const int v = base + prev;
        cstart[rb + x] = v;
        cursor[rb + x] = v;
        prev = xpre[rb + x];
    }
    if (t == NROWS2D - 1) cstart[NCELLS] = base + prev;
    const int z = t / GRID_R, x = t - z * GRID_R;
    const int b2 = z * NROWS2D + x;
    int run = 0;
#pragma unroll
    for (int y = 0; y < GRID_R; ++y) {
        run += sat[b2 + y * GRID_R];
        sat[b2 + y * GRID_R] = run;
    }
}

// FUSED: SAT z-pass (blocks 0..8) + scatter (blocks 9..72).
template <typename T>
__device__ __forceinline__ void scatter_body(const T* __restrict__ pos, int i,
                                             int* __restrict__ cursor,
                                             float4* __restrict__ pts4, int* __restrict__ pid) {
    const float x = ldf(pos, 3 * i + 0);
    const float y = ldf(pos, 3 * i + 1);
    const float z = ldf(pos, 3 * i + 2);
    const int c = (cell_of(z) * GRID_R + cell_of(y)) * GRID_R + cell_of(x);
    const int slot = atomicAdd(&cursor[c], 1);
    const float sq = fmaf(x, x, fmaf(y, y, z * z));
    pts4[slot] = make_float4(-2.0f * x, -2.0f * y, -2.0f * z, sq);
    pid[slot] = i;
}

__global__ __launch_bounds__(256) void satzscatter_kernel(const void* __restrict__ pos,
                                                          const int* __restrict__ flag,
                                                          int* __restrict__ sat,
                                                          int* __restrict__ cursor,
                                                          float4* __restrict__ pts4,
                                                          int* __restrict__ pid) {
    if (blockIdx.x < 9) {
        const int t = blockIdx.x * 256 + threadIdx.x;   // < 2304
        int run = 0;
#pragma unroll
        for (int z = 0; z < GRID_R; ++z) {
            run += sat[t + z * NROWS2D];
            sat[t + z * NROWS2D] = run;
        }
    } else {
        const int i = (blockIdx.x - 9) * 256 + threadIdx.x;
        if (get_dt(flag) == DT_BF16) scatter_body<__hip_bfloat16>((const __hip_bfloat16*)pos, i, cursor, pts4, pid);
        else                         scatter_body<float>((const float*)pos, i, cursor, pts4, pid);
    }
}

// ---------------------------------------------------------------------------
// KNN v13 = v12 + HYBRID ROW WALKER (chunk-staging tail fix).
// r11 post-mortem: 4 nulls (candidate count x2, chord clip, merge chain) ->
// the invariant none touched is the PER-CHUNK staging cost: every 32 rows
// cost a serial {waitcnt, cstart loads, 5-shfl prefix, LDS, waitcnt} unit
// (~700cy) REGARDLESS of content. Outlier windows (r~15-25 -> (2r+1)^2 rows
// = 40-80 chunks, twice with pass 2) => 30-60k serial cycles in one wave =
// the 53us floor. v13: if R > R_DIRECT rows (r>=5 <=> probe-certified
// sparse), each lane walks rows lane, lane+32, ... DIRECTLY: chord-clip the
// row, read its [start,end) span, scan its few points inline. No chunks, no
// barriers, no prefix — row probes pipeline across iterations. Dense targets
// (R<=96 => <=3 chunks) keep the candidate-even staged path. Same candidates
// visited; per-lane gate exact (lane's own 8th >= global 8th); merge
// unchanged => identical selection semantics.
// ---------------------------------------------------------------------------
__device__ __forceinline__ int sat_at(const int* __restrict__ sat, int x, int y, int z) {
    if (x < 0 || y < 0 || z < 0) return 0;
    return sat[(z * GRID_R + y) * GRID_R + x];
}

__device__ __forceinline__ int boxcount(const int* __restrict__ sat,
                                        int x0, int x1, int y0, int y1, int z0, int z1) {
    return sat_at(sat, x1, y1, z1) - sat_at(sat, x0 - 1, y1, z1)
         - sat_at(sat, x1, y0 - 1, z1) - sat_at(sat, x1, y1, z0 - 1)
         + sat_at(sat, x0 - 1, y0 - 1, z1) + sat_at(sat, x0 - 1, y1, z0 - 1)
         + sat_at(sat, x1, y0 - 1, z0 - 1) - sat_at(sat, x0 - 1, y0 - 1, z0 - 1);
}

template <typename T>
__device__ void knn_body(const T* __restrict__ pos,
                         const int* __restrict__ cstart, const int* __restrict__ sat,
                         const float4* __restrict__ pts4, const int* __restrict__ pid,
                         int* __restrict__ idx_out,
                         int* __restrict__ rs, int* __restrict__ epf) {
    const int tid  = threadIdx.x;
    const int lane = tid & 31;                 // lane within 32-lane subgroup
    const int i    = blockIdx.x * 8 + (tid >> 5);

    const float pix = ldf(pos, 3 * i + 0);
    const float piy = ldf(pos, 3 * i + 1);
    const float piz = ldf(pos, 3 * i + 2);
    const float sqi = fmaf(pix, pix, fmaf(piy, piy, piz * piz));
    const int cx = cell_of(pix), cy = cell_of(piy), cz = cell_of(piz);

    unsigned long long bk[KNN];
#pragma unroll
    for (int q = 0; q < KNN; ++q) bk[q] = SENT_KEY;
    unsigned long long tk = SENT_KEY;          // gate key (>= global 8th-best)

    auto do_insert = [&](unsigned long long ck) {
#pragma unroll
        for (int q = 0; q < KNN; ++q) {
            const unsigned long long old = bk[q];
            const bool ins = ck < old;
            bk[q] = ins ? ck : old;
            ck    = ins ? old : ck;
        }
        tk = (bk[KNN - 1] < tk) ? bk[KNN - 1] : tk;   // only tightens
    };

    // chord clip for one (y,z) row: returns false if row excluded, else sets
    // [cxa, cxb] to the clipped x-range.
    auto clip_row = [&](int ycell, int zcell, float clip2, bool doclip,
                        int x0, int x1, int& cxa, int& cxb) -> bool {
        cxa = x0; cxb = x1;
        if (doclip) {
            const float ylo = GLO + (float)ycell * CELL_E;
            const float zlo = GLO + (float)zcell * CELL_E;
            const float dy = fmaxf(0.0f, fmaxf(ylo - piy, piy - (ylo + CELL_E)));
            const float dz = fmaxf(0.0f, fmaxf(zlo - piz, piz - (zlo + CELL_E)));
            const float rad2 = clip2 - dy * dy - dz * dz;
            if (rad2 <= 0.0f) return false;
            const float hr = sqrtf(rad2) + 1e-4f;
            cxa = max(x0, (int)floorf((pix - hr - GLO) * CELL_INV));
            cxb = min(x1, (int)floorf((pix + hr - GLO) * CELL_INV));
        }
        return cxa <= cxb;
    };

    auto cand_key = [&](int si) -> unsigned long long {
        const float4 cq = pts4[si];
        const int pj = pid[si];
        const float d = fmaf(cq.x, pix, fmaf(cq.y, piy, fmaf(cq.z, piz, cq.w)));
        if (pj == i) return SENT_KEY;
        return ((unsigned long long)fkey(d) << 32) | (unsigned)pj;
    };

    // window scan; clipR < INF restricts each row's x-run to the s2-chord.
    auto scan_win = [&](int rr, float clipR) {
        const int x0 = max(cx - rr, 0), x1 = min(cx + rr, GRID_R - 1);
        const int y0 = max(cy - rr, 0), y1 = min(cy + rr, GRID_R - 1);
        const int z0 = max(cz - rr, 0), z1 = min(cz + rr, GRID_R - 1);
        const int ny = y1 - y0 + 1;
        const int nz = z1 - z0 + 1;
        const int R  = ny * nz;
        const float clip2 = clipR * clipR;
        const bool doclip = (clipR < 1e30f);

        if (R > R_DIRECT) {
            // ---- direct per-lane row walk (sparse windows only) ----
            int iy = lane, iz = 0;
            while (iy >= ny) { iy -= ny; ++iz; }
            while (iz < nz) {
                const int ycell = y0 + iy, zcell = z0 + iz;
                int cxa, cxb;
                if (clip_row(ycell, zcell, clip2, doclip, x0, x1, cxa, cxb)) {
                    const int c0 = (zcell * GRID_R + ycell) * GRID_R + cxa;
                    const int s0 = cstart[c0];
                    const int s1 = cstart[c0 + (cxb - cxa) + 1];
                    for (int si = s0; si < s1; ++si) {
                        const unsigned long long ck = cand_key(si);
                        if (ck <= tk) do_insert(ck);
                    }
                }
                iy += 32;
                while (iy >= ny && iz < nz) { iy -= ny; ++iz; }
            }
            return;
        }

        // ---- staged candidate-even path (dense windows, R <= 96) ----
        for (int cb = 0; cb < R; cb += 32) {
            const int lr = cb + lane;
            int cnt_r = 0, st_r = 0;
            if (lr < R) {
                const int izq = lr / ny;
                const int iyq = lr - izq * ny;
                int cxa, cxb;
                if (clip_row(y0 + iyq, z0 + izq, clip2, doclip, x0, x1, cxa, cxb)) {
                    const int c0 = ((z0 + izq) * GRID_R + (y0 + iyq)) * GRID_R + cxa;
                    st_r  = cstart[c0];
                    cnt_r = cstart[c0 + (cxb - cxa) + 1] - st_r;
                }
            }
            int pv = cnt_r;
#pragma unroll
            for (int s = 1; s < 32; s <<= 1) {
                const int u = __shfl_up(pv, s, 32);
                if (lane >= s) pv += u;
            }
            const int Mtot = __shfl(pv, 31, 32);
            asm volatile("s_waitcnt lgkmcnt(0)" ::: "memory");  // prev chunk reads done
            rs[lane]  = st_r;
            epf[lane] = (lr < R) ? (pv - cnt_r) : 0x7fffffff;   // exclusive prefix / +inf
            asm volatile("s_waitcnt lgkmcnt(0)" ::: "memory");  // staging visible
            for (int tb = 0; tb < Mtot; tb += 128) {
                unsigned long long ck[4];
#pragma unroll
                for (int k = 0; k < 4; ++k) {
                    const int t = tb + (k << 5) + lane;
                    ck[k] = SENT_KEY;
                    if (t < Mtot) {
                        int p = 0;
#pragma unroll
                        for (int st = 16; st >= 1; st >>= 1)
                            if (epf[p + st] <= t) p += st;
                        ck[k] = cand_key(rs[p] + (t - epf[p]));
                    }
                }
#pragma unroll
                for (int k = 0; k < 4; ++k)
                    if (ck[k] <= tk) do_insert(ck[k]);
            }
        }
    };

    // bitonic cross-lane merge: 5 levels; after it, ALL lanes hold the same
    // sorted global top-8 keys in bk[0..7].
    auto merge_all = [&]() {
#pragma unroll
        for (int s = 1; s < 32; s <<= 1) {
            unsigned long long m[KNN];
#pragma unroll
            for (int q = 0; q < KNN; ++q) {
                const unsigned long long o = __shfl_xor(bk[KNN - 1 - q], s, 32);
                m[q] = (bk[q] < o) ? bk[q] : o;    // lowest-8 of the 16 (bitonic)
            }
#pragma unroll
            for (int d = 4; d >= 1; d >>= 1) {
#pragma unroll
                for (int q = 0; q < KNN; ++q) {
                    if (!(q & d)) {
                        const unsigned long long a = m[q], b = m[q + d];
                        const bool sw = b < a;
                        m[q]     = sw ? b : a;
                        m[q + d] = sw ? a : b;
                    }
                }
            }
#pragma unroll
            for (int q = 0; q < KNN; ++q) bk[q] = m[q];
        }
        tk = bk[KNN - 1];
    };

    // ---- 1) two-level SAT radius probe: lane l tests radius l+1 (<=32) ----
    int r;
    {
        const int rl = lane + 1;
        const int bx0 = max(cx - rl, 0), bx1 = min(cx + rl, GRID_R - 1);
        const int by0 = max(cy - rl, 0), by1 = min(cy + rl, GRID_R - 1);
        const int bz0 = max(cz - rl, 0), bz1 = min(cz + rl, GRID_R - 1);
        const int cntl = boxcount(sat, bx0, bx1, by0, by1, bz0, bz1);
        const unsigned long long m9  = __ballot(cntl >= NBR_LO);
        const unsigned long long m26 = __ballot(cntl >= NBR_MIN);
        const unsigned sh  = (unsigned)(tid & 32);
        const unsigned mh9  = (unsigned)(m9  >> sh);
        const unsigned mh26 = (unsigned)(m26 >> sh);
        const int r9  = mh9  ? (int)__ffs(mh9)  : 32;
        const int r26 = mh26 ? (int)__ffs(mh26) : 32;
        const int cnt26 = __shfl(cntl, r26 - 1, 32);   // population of preferred window
        r = (cnt26 <= M_CAP) ? r26 : r9;
    }

    // ---- 2) window scan at r (no clip: tau unknown) ----
    scan_win(r, INFINITY);

    // ---- 3) merge + termination; chord-clipped second pass on failure ----
    {
        float mg = INFINITY;
        bool full = true;
        if (cx - r > 0)          { mg = fminf(mg, pix - (GLO + (float)(cx - r) * CELL_E));     full = false; }
        if (cx + r < GRID_R - 1) { mg = fminf(mg, (GLO + (float)(cx + r + 1) * CELL_E) - pix); full = false; }
        if (cy - r > 0)          { mg = fminf(mg, piy - (GLO + (float)(cy - r) * CELL_E));     full = false; }
        if (cy + r < GRID_R - 1) { mg = fminf(mg, (GLO + (float)(cy + r + 1) * CELL_E) - piy); full = false; }
        if (cz - r > 0)          { mg = fminf(mg, piz - (GLO + (float)(cz - r) * CELL_E));     full = false; }
        if (cz + r < GRID_R - 1) { mg = fminf(mg, (GLO + (float)(cz + r + 1) * CELL_E) - piz); full = false; }

        merge_all();                             // all lanes: sorted global top-8
        bool done = full;
        const unsigned long long d8key = bk[KNN - 1];
        const float d8 = fkey_inv((unsigned)(d8key >> 32));
        if (!full) {
            const float mge  = mg - 1e-5f;
            const float need = mge * mge - sqi;  // d_real < mge^2  <=>  d' < need
            done = (d8 < need);                  // strict; NaN/INF d8 -> false
        }

        if (!done) {
            // s2 = conservative real-distance bound on the true 8th neighbor
            float s2 = sqrtf(fmaxf(d8 + sqi, 0.0f)) + 1e-4f;
            s2 = fminf(s2, 9.0f);                // INF d8 -> full grid
            auto dneed = [&](float frac, int clip) -> int {
                int nd = (int)ceilf((s2 - frac) * CELL_INV);
                nd = max(nd, 0);
                return min(nd, clip);
            };
            const float fxm = pix - (GLO + (float)cx * CELL_E);
            const float fxp = (GLO + (float)(cx + 1) * CELL_E) - pix;
            const float fym = piy - (GLO + (float)cy * CELL_E);
            const float fyp = (GLO + (float)(cy + 1) * CELL_E) - piy;
            const float fzm = piz - (GLO + (float)cz * CELL_E);
            const float fzp = (GLO + (float)(cz + 1) * CELL_E) - piz;
            int r2 = r + 1;
            r2 = max(r2, dneed(fxm, cx));
            r2 = max(r2, dneed(fxp, GRID_R - 1 - cx));
            r2 = max(r2, dneed(fym, cy));
            r2 = max(r2, dneed(fyp, GRID_R - 1 - cy));
            r2 = max(r2, dneed(fzm, cz));
            r2 = max(r2, dneed(fzp, GRID_R - 1 - cz));
            r2 = min(r2, GRID_R);

            // fresh lists; gate seeded with pass-1 8th key (<= admits the 8th
            // itself and its lex-predecessors; chord window is a superset of
            // all points with d_real <= d8_real => exact)
#pragma unroll
            for (int q = 0; q < KNN; ++q) bk[q] = SENT_KEY;
            tk = d8key;
            scan_win(r2, (d8 < INFINITY) ? s2 : INFINITY);
            merge_all();
        }
    }

    if (lane == 0) {
#pragma unroll
        for (int k = 0; k < KNN; ++k) idx_out[i * 9 + k] = clamp_idx((int)(unsigned)bk[k]);
        idx_out[i * 9 + 8] = i;
    }
}

__global__ __launch_bounds__(256) void knn_grid_kernel(const void* __restrict__ pos,
                                                       const int* __restrict__ flag,
                                                       const int* __restrict__ cstart,
                                                       const int* __restrict__ sat,
                                                       const float4* __restrict__ pts4,
                                                       const int* __restrict__ pid,
                                                       int* __restrict__ idx_out) {
    __shared__ int rs[8][32];
    __shared__ int epf[8][32];
    const int sg = threadIdx.x >> 5;
    if (get_dt(flag) == DT_BF16)
        knn_body<__hip_bfloat16>((const __hip_bfloat16*)pos, cstart, sat, pts4, pid, idx_out,
                                 rs[sg], epf[sg]);
    else
        knn_body<float>((const float*)pos, cstart, sat, pts4, pid, idx_out, rs[sg], epf[sg]);
}

// ---------------------------------------------------------------------------
// conv1 (unchanged from r11): factored first layer; named-reg k-tiled wB.
// ---------------------------------------------------------------------------
struct Conv1Smem {
    alignas(16) float wB[32 * 64];
    alignas(16) float h1s[4][9 * 32];
    alignas(16) float wsum[3 * 32];
    alignas(16) float wbot[3 * 32];
    alignas(16) float posn[4][9][3];
    float bA[32];
    float bB[64];
};

template <typename T>
__device__ void conv1_body(const T* __restrict__ pos, const int* __restrict__ idx,
                           const T* __restrict__ W1a, const T* __restrict__ b1a,
                           const T* __restrict__ W1b, const T* __restrict__ b1b,
                           float* __restrict__ x1, Conv1Smem& s) {
    const int tid = threadIdx.x;
    for (int e = tid; e < 96; e += 256) {
        const float bot = ldf(W1a, 96 + e);
        s.wsum[e] = ldf(W1a, e) + bot;
        s.wbot[e] = bot;
    }
    if (tid < 32) s.bA[tid] = ldf(b1a, tid);
    for (int e = tid; e < 2048; e += 256) s.wB[e] = ldf(W1b, e);
    if (tid < 64) s.bB[tid] = ldf(b1b, tid);

    const int tl   = tid >> 6;
    const int lane = tid & 63;
    const int i    = blockIdx.x * 4 + tl;

    if (lane < 27) {
        const int n = lane / 3, c = lane % 3;
        const int j = clamp_idx(idx[i * 9 + n]);
        s.posn[tl][n][c] = ldf(pos, 3 * j + c);
    }
    const float pi0 = ldf(pos, 3 * i + 0);
    const float pi1 = ldf(pos, 3 * i + 1);
    const float pi2 = ldf(pos, 3 * i + 2);
    __syncthreads();

    for (int e = lane; e < 288; e += 64) {
        const int n = e >> 5, k = e & 31;
        float b = fmaf(pi0, s.wbot[k], fmaf(pi1, s.wbot[32 + k], pi2 * s.wbot[64 + k]));
        float v = s.bA[k] - b;
        v = fmaf(s.posn[tl][n][0], s.wsum[k], v);
        v = fmaf(s.posn[tl][n][1], s.wsum[32 + k], v);
        v = fmaf(s.posn[tl][n][2], s.wsum[64 + k], v);
        s.h1s[tl][n * 32 + k] = fmaxf(v, 0.0f);
    }
    __syncthreads();

    float acc[9];
#pragma unroll
    for (int n = 0; n < 9; ++n) acc[n] = 0.0f;
#pragma unroll
    for (int kt = 0; kt < 32; kt += 8) {
        float w0 = s.wB[(kt + 0) * 64 + lane];
        float w1 = s.wB[(kt + 1) * 64 + lane];
        float w2 = s.wB[(kt + 2) * 64 + lane];
        float w3 = s.wB[(kt + 3) * 64 + lane];
        float w4 = s.wB[(kt + 4) * 64 + lane];
        float w5 = s.wB[(kt + 5) * 64 + lane];
        float w6 = s.wB[(kt + 6) * 64 + lane];
        float w7 = s.wB[(kt + 7) * 64 + lane];
#pragma unroll
        for (int n = 0; n < 9; ++n) {
            const float4 ha = *(const float4*)&s.h1s[tl][n * 32 + kt];
            const float4 hb = *(const float4*)&s.h1s[tl][n * 32 + kt + 4];
            float a = acc[n];
            a = fmaf(ha.x, w0, a); a = fmaf(ha.y, w1, a);
            a = fmaf(ha.z, w2, a); a = fmaf(ha.w, w3, a);
            a = fmaf(hb.x, w4, a); a = fmaf(hb.y, w5, a);
            a = fmaf(hb.z, w6, a); a = fmaf(hb.w, w7, a);
            acc[n] = a;
        }
    }
    float m = acc[0];
#pragma unroll
    for (int n = 1; n < 9; ++n) m = fmaxf(m, acc[n]);
    x1[i * 64 + lane] = fmaxf(m + s.bB[lane], 0.0f);
}

__global__ __launch_bounds__(256) void conv1_kernel(const void* __restrict__ pos,
                                                    const int* __restrict__ flag,
                                                    const int* __restrict__ idx,
                                                    const void* __restrict__ W1a,
                                                    const void* __restrict__ b1a,
                                                    const void* __restrict__ W1b,
                                                    const void* __restrict__ b1b,
                                                    float* __restrict__ x1) {
    __shared__ Conv1Smem s;
    if (get_dt(flag) == DT_BF16)
        conv1_body<__hip_bfloat16>((const __hip_bfloat16*)pos, idx,
            (const __hip_bfloat16*)W1a, (const __hip_bfloat16*)b1a,
            (const __hip_bfloat16*)W1b, (const __hip_bfloat16*)b1b, x1, s);
    else
        conv1_body<float>((const float*)pos, idx, (const float*)W1a, (const float*)b1a,
            (const float*)W1b, (const float*)b1b, x1, s);
}

// ---------------------------------------------------------------------------
// zw (unchanged): per-point precompute for conv2's first layer.
// ---------------------------------------------------------------------------
struct ZwSmem {
    alignas(16) float wA[67 * 64];
    alignas(16) float xrT[4][68][4];
    float bA[64];
};

template <typename T>
__device__ void zw_body(const T* __restrict__ pos, const T* __restrict__ W2a,
                        const T* __restrict__ b2a, float* __restrict__ x1, ZwSmem& s) {
    const int tid  = threadIdx.x;
    const int wv   = tid >> 6;
    const int lane = tid & 63;
    const int j0   = blockIdx.x * 16 + wv * 4;

    for (int e = tid; e < 4288; e += 256) s.wA[e] = ldf(W2a, e);
    if (tid < 64) s.bA[tid] = ldf(b2a, tid);

#pragma unroll
    for (int p = 0; p < 4; ++p)
        s.xrT[wv][lane][p] = x1[(j0 + p) * 64 + lane];
    if (lane < 12) {
        const int p = lane / 3, c = lane % 3;
        s.xrT[wv][64 + c][p] = ldf(pos, 3 * (j0 + p) + c);
    }
    __syncthreads();

    float a0 = s.bA[lane], a1 = a0, a2 = a0, a3 = a0;
    for (int c = 0; c < 67; ++c) {
        const float w = s.wA[c * 64 + lane];
        const float4 xv = *(const float4*)&s.xrT[wv][c][0];
        a0 = fmaf(xv.x, w, a0);
        a1 = fmaf(xv.y, w, a1);
        a2 = fmaf(xv.z, w, a2);
        a3 = fmaf(xv.w, w, a3);
    }
    x1[(j0 + 0) * 64 + lane] = a0;
    x1[(j0 + 1) * 64 + lane] = a1;
    x1[(j0 + 2) * 64 + lane] = a2;
    x1[(j0 + 3) * 64 + lane] = a3;
}

__global__ __launch_bounds__(256) void zw_kernel(const void* __restrict__ pos,
                                                 const int* __restrict__ flag,
                                                 const void* __restrict__ W2a,
                                                 const void* __restrict__ b2a,
                                                 float* __restrict__ x1) {
    __shared__ ZwSmem s;
    if (get_dt(flag) == DT_BF16)
        zw_body<__hip_bfloat16>((const __hip_bfloat16*)pos, (const __hip_bfloat16*)W2a,
                                (const __hip_bfloat16*)b2a, x1, s);
    else
        zw_body<float>((const float*)pos, (const float*)W2a, (const float*)b2a, x1, s);
}

// ---------------------------------------------------------------------------
// conv2+head (unchanged from r11): named-reg k-tiles, 2 channels/thread.
// ---------------------------------------------------------------------------
struct Conv2Smem {
    alignas(16) float h1s[4][9 * 64];
    alignas(16) float row[4][128];
    alignas(16) float wbot[3 * 64];
    alignas(16) float wc[640];
    float bcs[5];
    float sv[4][5];
    int   nb[4][9];
};

template <typename T>
__device__ void conv2_body(const T* __restrict__ pos, const int* __restrict__ idx,
                           const float* __restrict__ zw,
                           const T* __restrict__ W2a, const T* __restrict__ W2b,
                           const T* __restrict__ b2b, const T* __restrict__ Wc,
                           const T* __restrict__ bc, T* __restrict__ out, Conv2Smem& s) {
    const int tid  = threadIdx.x;
    const int tl   = tid >> 6;
    const int lane = tid & 63;
    const int i    = blockIdx.x * 4 + tl;

    for (int e = tid; e < 192; e += 256) s.wbot[e] = ldf(W2a, 4096 + e);
    for (int e = tid; e < 640; e += 256) s.wc[e] = ldf(Wc, e);
    if (tid < 5) s.bcs[tid] = ldf(bc, tid);

    if (lane < 9) s.nb[tl][lane] = clamp_idx(idx[i * 9 + lane]);
    const float pi0 = ldf(pos, 3 * i + 0);
    const float pi1 = ldf(pos, 3 * i + 1);
    const float pi2 = ldf(pos, 3 * i + 2);
    __syncthreads();

    {
        const float vi = fmaf(pi0, s.wbot[lane], fmaf(pi1, s.wbot[64 + lane], pi2 * s.wbot[128 + lane]));
#pragma unroll
        for (int n = 0; n < 9; ++n) {
            const int j = s.nb[tl][n];
            s.h1s[tl][n * 64 + lane] = fmaxf(zw[j * 64 + lane] - vi, 0.0f);
        }
    }
    __syncthreads();

    float acc0[9], acc1[9];
#pragma unroll
    for (int n = 0; n < 9; ++n) { acc0[n] = 0.0f; acc1[n] = 0.0f; }
#pragma unroll
    for (int kt = 0; kt < 64; kt += 4) {
        const float wa0 = ldf(W2b, (kt + 0) * 128 + lane);
        const float wa1 = ldf(W2b, (kt + 1) * 128 + lane);
        const float wa2 = ldf(W2b, (kt + 2) * 128 + lane);
        const float wa3 = ldf(W2b, (kt + 3) * 128 + lane);
        const float wb0 = ldf(W2b, (kt + 0) * 128 + lane + 64);
        const float wb1 = ldf(W2b, (kt + 1) * 128 + lane + 64);
        const float wb2 = ldf(W2b, (kt + 2) * 128 + lane + 64);
        const float wb3 = ldf(W2b, (kt + 3) * 128 + lane + 64);
#pragma unroll
        for (int n = 0; n < 9; ++n) {
            const float4 h = *(const float4*)&s.h1s[tl][n * 64 + kt];
            float a0 = acc0[n], a1 = acc1[n];
            a0 = fmaf(h.x, wa0, a0); a0 = fmaf(h.y, wa1, a0);
            a0 = fmaf(h.z, wa2, a0); a0 = fmaf(h.w, wa3, a0);
            a1 = fmaf(h.x, wb0, a1); a1 = fmaf(h.y, wb1, a1);
            a1 = fmaf(h.z, wb2, a1); a1 = fmaf(h.w, wb3, a1);
            acc0[n] = a0; acc1[n] = a1;
        }
    }
    float m0 = acc0[0], m1 = acc1[0];
#pragma unroll
    for (int n = 1; n < 9; ++n) { m0 = fmaxf(m0, acc0[n]); m1 = fmaxf(m1, acc1[n]); }
    s.row[tl][lane]      = fmaxf(m0 + ldf(b2b, lane), 0.0f);
    s.row[tl][lane + 64] = fmaxf(m1 + ldf(b2b, lane + 64), 0.0f);
    __syncthreads();

    if (tid < 20) {
        const int tgt = tid / 5, o = tid % 5;
        float v = s.bcs[o];
        for (int k = 0; k < 128; ++k) v = fmaf(s.row[tgt][k], s.wc[k * 5 + o], v);
        s.sv[tgt][o] = v;
    }
    __syncthreads();
    if (tid < 20) {
        const int tgt = tid / 5, o = tid % 5;
        float m = s.sv[tgt][0];
#pragma unroll
        for (int q = 1; q < 5; ++q) m = fmaxf(m, s.sv[tgt][q]);
        float sum = 0.0f;
#pragma unroll
        for (int q = 0; q < 5; ++q) sum += expf(s.sv[tgt][q] - m);
        const float lse = m + logf(sum);
        stf(out, (blockIdx.x * 4 + tgt) * 5 + o, s.sv[tgt][o] - lse);
    }
}

__global__ __launch_bounds__(256) void conv2_head_kernel(const void* __restrict__ pos,
                                                         const int* __restrict__ flag,
                                                         const int* __restrict__ idx,
                                                         const float* __restrict__ zw,
                                                         const void* __restrict__ W2a,
                                                         const void* __restrict__ W2b,
                                                         const void* __restrict__ b2b,
                                                         const void* __restrict__ Wc,
                                                         const void* __restrict__ bc,
                                                         void* __restrict__ out) {
    __shared__ Conv2Smem s;
    if (get_dt(flag) == DT_BF16)
        conv2_body<__hip_bfloat16>((const __hip_bfloat16*)pos, idx, zw,
            (const __hip_bfloat16*)W2a, (const __hip_bfloat16*)W2b, (const __hip_bfloat16*)b2b,
            (const __hip_bfloat16*)Wc, (const __hip_bfloat16*)bc, (__hip_bfloat16*)out, s);
    else
        conv2_body<float>((const float*)pos, idx, zw, (const float*)W2a, (const float*)W2b,
            (const float*)b2b, (const float*)Wc, (const float*)bc, (float*)out, s);
}

// ---------------------------------------------------------------------------
extern "C" void kernel_launch(void* const* d_in, const int* in_sizes, int n_in,
                              void* d_out, int out_size, void* d_ws, size_t ws_size,
                              hipStream_t stream) {
    if (ws_size < (size_t)WS_NEEDED) return;

    char* ws = (char*)d_ws;
    int*    flag     = (int*)(ws + WS_FLAG_OFF);
    int*    idx      = (int*)(ws + WS_IDX_OFF);
    float*  x1       = (float*)(ws + WS_X1_OFF);
    int*    sat      = (int*)(ws + WS_SAT_OFF);
    int*    cstart   = (int*)(ws + WS_START_OFF);
    int*    cursor   = (int*)(ws + WS_CURSOR_OFF);
    int*    pid      = (int*)(ws + WS_PID_OFF);
    float4* pts4     = (float4*)(ws + WS_PTS_OFF);
    int*    rowtot   = (int*)(ws + WS_ROWTOT_OFF);
    int*    rowstart = (int*)(ws + WS_ROWSTART_OFF);
    int*    xpre     = (int*)(ws + WS_XPRE_OFF);

    zero_kernel<<<NCELLS / 256, 256, 0, stream>>>(sat, flag);
    sniff_kernel<<<64, 256, 0, stream>>>((const unsigned short*)d_in[0], flag);
    grid_count_kernel<<<N_PTS / 256, 256, 0, stream>>>(d_in[0], flag, sat);
    rowscan_kernel<<<NROWS2D / 256, 256, 0, stream>>>(sat, xpre, rowtot);
    rowoffset_kernel<<<1, 256, 0, stream>>>(rowtot, rowstart);
    cellsaty_kernel<<<NROWS2D / 256, 256, 0, stream>>>(xpre, rowstart, cstart, cursor, sat);
    satzscatter_kernel<<<9 + N_PTS / 256, 256, 0, stream>>>(d_in[0], flag, sat, cursor, pts4, pid);
    knn_grid_kernel<<<N_PTS / 8, 256, 0, stream>>>(d_in[0], flag, cstart, sat, pts4, pid, idx);
    conv1_kernel<<<N_PTS / 4, 256, 0, stream>>>(d_in[0], flag, idx,
        d_in[1], d_in[2], d_in[3], d_in[4], x1);
    zw_kernel<<<N_PTS / 16, 256, 0, stream>>>(d_in[0], flag, d_in[5], d_in[6], x1);
    conv2_head_kernel<<<N_PTS / 4, 256, 0, stream>>>(d_in[0], flag, idx, x1,
        d_in[5], d_in[7], d_in[8], d_in[9], d_in[10], d_out);
}